// Round 4
// baseline (1711.497 us; speedup 1.0000x reference)
//
#include <hip/hip_runtime.h>

#define L_ 6
#define H_ 8
#define C_ 512
#define V_ 32000
#define B_ 2
#define T_ 4096
#define Q_ 256
#define N_ 64
#define NC_ 16
#define M_ 8192   // B*T

typedef unsigned short u16;
typedef __attribute__((ext_vector_type(8))) short bf16x8;
typedef __attribute__((ext_vector_type(4))) float f32x4;

__device__ __forceinline__ float bf2f(u16 u){
  return __uint_as_float(((unsigned int)u) << 16);
}
__device__ __forceinline__ u16 f2bf(float f){
  unsigned int x = __float_as_uint(f);
  return (u16)((x + 0x7fffu + ((x >> 16) & 1u)) >> 16);
}

__device__ __forceinline__ void gl_lds16(const u16* g, u16* l){
  __builtin_amdgcn_global_load_lds((const __attribute__((address_space(1))) void*)g,
                                   (__attribute__((address_space(3))) void*)l, 16, 0, 0);
}

// ---------------- dtype detection: bf16 weights never have |x|>=2 ----------------
__global__ __launch_bounds__(256) void detect_kernel(const void* __restrict__ probe,
                                                     int* __restrict__ flag){
  __shared__ int cnt;
  if (threadIdx.x == 0) cnt = 0;
  __syncthreads();
  const u16* p = (const u16*)probe;
  int c = 0;
  for (int i = threadIdx.x; i < 2048; i += 256){
    int e = (p[i] >> 7) & 0xFF;
    if (e >= 128) c++;
  }
  atomicAdd(&cnt, c);
  __syncthreads();
  if (threadIdx.x == 0) *flag = (cnt > 32) ? 1 : 0;  // 1 = inputs are fp32
}

// ---------------- pointer table: bf16 -> use raw inputs in place; fp32 -> converted pool ----------------
struct PtrTab { const void* raw[23]; long long off[23]; };

__global__ __launch_bounds__(64) void fill_ptab(PtrTab pt, const u16* __restrict__ pool,
    const int* __restrict__ flag, const u16** __restrict__ ptab){
  int i = threadIdx.x;
  if (i < 23)
    ptab[i+1] = (*flag) ? (pool + pt.off[i]) : (const u16*)pt.raw[i];
}

// ---------------- fp32 -> bf16 conversion (only runs when inputs are fp32) ----------------
struct CvtTab { const void* s[23]; int off8[24]; int bstart[24]; };

__global__ __launch_bounds__(256) void convert_all(CvtTab t, u16* __restrict__ pool,
                                                   const int* __restrict__ flag){
  if (!*flag) return;    // bf16 inputs are consumed in place via ptab
  int i = 0;
  #pragma unroll
  for (int k = 1; k < 23; k++) if ((int)blockIdx.x >= t.bstart[k]) i = k;
  const void* sp = t.s[0];
  #pragma unroll
  for (int k = 1; k < 23; k++) if (i == k) sp = t.s[k];
  const int n8 = t.off8[i+1] - t.off8[i];
  const int nb = t.bstart[i+1] - t.bstart[i];
  const int lb = (int)blockIdx.x - t.bstart[i];
  uint4* dp = (uint4*)pool + t.off8[i];
  const int stride = nb * 256;
  const float4* sf = (const float4*)sp;
  for (int j = lb*256 + (int)threadIdx.x; j < n8; j += stride){
    float4 a0 = sf[2*j], a1 = sf[2*j+1];
    uint4 r0;
    r0.x = (unsigned)f2bf(a0.x) | ((unsigned)f2bf(a0.y) << 16);
    r0.y = (unsigned)f2bf(a0.z) | ((unsigned)f2bf(a0.w) << 16);
    r0.z = (unsigned)f2bf(a1.x) | ((unsigned)f2bf(a1.y) << 16);
    r0.w = (unsigned)f2bf(a1.z) | ((unsigned)f2bf(a1.w) << 16);
    dp[j] = r0;
  }
}

// ---------------- embedding: x = wte[idx] + wpe ----------------
__global__ __launch_bounds__(256) void embed_kernel(const int* __restrict__ idx,
    const u16* const* __restrict__ ptab, float* __restrict__ x){
  const u16* wte = ptab[1];
  const u16* wpe = ptab[2];
  int row = blockIdx.x;                 // b*T + t
  int t = row & (T_-1);
  int tok = idx[row];
  const u16* we = wte + (size_t)tok * C_;
  const u16* wp = wpe + (size_t)t * C_;
  float* xo = x + (size_t)row * C_;
  int c = threadIdx.x;
  xo[c]     = bf2f(we[c])     + bf2f(wp[c]);
  xo[c+256] = bf2f(we[c+256]) + bf2f(wp[c+256]);
}

// ---------------- fused LN + time-mix token shift (recomputes LN of row t-1) ----------------
__global__ __launch_bounds__(256) void ln_tmix_kernel(const float* __restrict__ x,
    const u16* const* __restrict__ ptab, int l,
    u16* __restrict__ xk, u16* __restrict__ xv, u16* __restrict__ xr, u16* __restrict__ xg){
  const u16* w  = ptab[3] + l*C_;
  const u16* mk = ptab[6] + l*C_;
  const u16* mv = ptab[7] + l*C_;
  const u16* mr = ptab[8] + l*C_;
  const u16* mg = ptab[9] + l*C_;
  int row = blockIdx.x; int t = row & (T_-1);
  size_t off = (size_t)row*C_;
  const float* cur = x + off;
  int c = threadIdx.x;
  float v0 = cur[c], v1 = cur[c+256];
  float p0 = 0.f, p1 = 0.f;
  if (t){ p0 = cur[c - C_]; p1 = cur[c+256 - C_]; }
  float s = v0+v1, ss = v0*v0+v1*v1;
  float sp = p0+p1, ssp = p0*p0+p1*p1;
  int lane = c & 63, wid = c >> 6;
  #pragma unroll
  for (int o=32;o>0;o>>=1){
    s  += __shfl_down(s,o,64);  ss  += __shfl_down(ss,o,64);
    sp += __shfl_down(sp,o,64); ssp += __shfl_down(ssp,o,64);
  }
  __shared__ float r1[4], r2[4], r3[4], r4[4];
  if (lane==0){ r1[wid]=s; r2[wid]=ss; r3[wid]=sp; r4[wid]=ssp; }
  __syncthreads();
  if (c==0){
    float a =r1[0]+r1[1]+r1[2]+r1[3], bq=r2[0]+r2[1]+r2[2]+r2[3];
    float ap=r3[0]+r3[1]+r3[2]+r3[3], bp=r4[0]+r4[1]+r4[2]+r4[3];
    float mu  = a *(1.f/C_); float var  = bq*(1.f/C_) - mu*mu;
    float mup = ap*(1.f/C_); float varp = bp*(1.f/C_) - mup*mup;
    r1[0]=mu;  r2[0]=rsqrtf(fmaxf(var ,0.f)+1e-5f);
    r3[0]=mup; r4[0]=rsqrtf(fmaxf(varp,0.f)+1e-5f);
  }
  __syncthreads();
  float mu=r1[0], inv=r2[0], mup=r3[0], invp=r4[0];
  #pragma unroll
  for (int p=0;p<2;p++){
    int cc = c + p*256;
    float wc = bf2f(w[cc]);
    float xc = ((p?v1:v0)-mu)*inv*wc;
    float xp = t ? ((p?p1:p0)-mup)*invp*wc : 0.f;
    float xx = xp - xc;
    xk[off+cc] = f2bf(xc + xx*bf2f(mk[cc]));
    xv[off+cc] = f2bf(xc + xx*bf2f(mv[cc]));
    xr[off+cc] = f2bf(xc + xx*bf2f(mr[cc]));
    xg[off+cc] = f2bf(xc + xx*bf2f(mg[cc]));
  }
}

// ---------------- fused LN + channel-mix token shift ----------------
__global__ __launch_bounds__(256) void ln_cmix_kernel(const float* __restrict__ x,
    const u16* const* __restrict__ ptab, int l,
    u16* __restrict__ xk, u16* __restrict__ xr){
  const u16* w  = ptab[4]  + l*C_;
  const u16* mk = ptab[19] + l*C_;
  const u16* mr = ptab[20] + l*C_;
  int row = blockIdx.x; int t = row & (T_-1);
  size_t off = (size_t)row*C_;
  const float* cur = x + off;
  int c = threadIdx.x;
  float v0 = cur[c], v1 = cur[c+256];
  float p0 = 0.f, p1 = 0.f;
  if (t){ p0 = cur[c - C_]; p1 = cur[c+256 - C_]; }
  float s = v0+v1, ss = v0*v0+v1*v1;
  float sp = p0+p1, ssp = p0*p0+p1*p1;
  int lane = c & 63, wid = c >> 6;
  #pragma unroll
  for (int o=32;o>0;o>>=1){
    s  += __shfl_down(s,o,64);  ss  += __shfl_down(ss,o,64);
    sp += __shfl_down(sp,o,64); ssp += __shfl_down(ssp,o,64);
  }
  __shared__ float r1[4], r2[4], r3[4], r4[4];
  if (lane==0){ r1[wid]=s; r2[wid]=ss; r3[wid]=sp; r4[wid]=ssp; }
  __syncthreads();
  if (c==0){
    float a =r1[0]+r1[1]+r1[2]+r1[3], bq=r2[0]+r2[1]+r2[2]+r2[3];
    float ap=r3[0]+r3[1]+r3[2]+r3[3], bp=r4[0]+r4[1]+r4[2]+r4[3];
    float mu  = a *(1.f/C_); float var  = bq*(1.f/C_) - mu*mu;
    float mup = ap*(1.f/C_); float varp = bp*(1.f/C_) - mup*mup;
    r1[0]=mu;  r2[0]=rsqrtf(fmaxf(var ,0.f)+1e-5f);
    r3[0]=mup; r4[0]=rsqrtf(fmaxf(varp,0.f)+1e-5f);
  }
  __syncthreads();
  float mu=r1[0], inv=r2[0], mup=r3[0], invp=r4[0];
  #pragma unroll
  for (int p=0;p<2;p++){
    int cc = c + p*256;
    float wc = bf2f(w[cc]);
    float xc = ((p?v1:v0)-mu)*inv*wc;
    float xp = t ? ((p?p1:p0)-mup)*invp*wc : 0.f;
    float xx = xp - xc;
    xk[off+cc] = f2bf(xc + xx*bf2f(mk[cc]));
    xr[off+cc] = f2bf(xc + xx*bf2f(mr[cc]));
  }
}

// ---------------- final LN for last position only ----------------
__global__ __launch_bounds__(256) void lnf_last(const float* __restrict__ x,
    const u16* const* __restrict__ ptab, float* __restrict__ xf){
  const u16* w = ptab[5];
  int b = blockIdx.x;
  const float* xr = x + ((size_t)b*T_ + (T_-1))*C_;
  int c = threadIdx.x;
  float v0 = xr[c], v1 = xr[c+256];
  float s = v0+v1, ss = v0*v0+v1*v1;
  int lane = c & 63, wid = c >> 6;
  #pragma unroll
  for (int o=32;o>0;o>>=1){ s += __shfl_down(s,o,64); ss += __shfl_down(ss,o,64); }
  __shared__ float r1[4], r2[4];
  if (lane==0){ r1[wid]=s; r2[wid]=ss; }
  __syncthreads();
  if (c==0){
    float a=r1[0]+r1[1]+r1[2]+r1[3], bq=r2[0]+r2[1]+r2[2]+r2[3];
    float mu = a*(1.f/C_);
    float var = bq*(1.f/C_) - mu*mu;
    r1[0]=mu; r2[0]=rsqrtf(fmaxf(var,0.f)+1e-5f);
  }
  __syncthreads();
  float mu=r1[0], inv=r2[0];
  xf[b*C_+c]     = (v0-mu)*inv*bf2f(w[c]);
  xf[b*C_+c+256] = (v1-mu)*inv*bf2f(w[c+256]);
}

// ================= MFMA GEMM bodies =================
#define ACT_RELU2_BF16 1
#define ACT_ADD_F32 2
#define ACT_BF16 3
#define ACT_CMIX 4      // Yf += v * bf2f(AuxB) (AuxB holds sigmoid gate)
#define ACT_SIG_BF16 7  // Yb = bf16(sigmoid(v))

// ---- 128(M) x 64(N), BK=64, 24KB LDS, for grids with >=2 blocks/CU shortage ----
template<int ACT>
__device__ __forceinline__ void gemm_mfma_body(const u16* __restrict__ X, const u16* __restrict__ W,
    float* __restrict__ Yf, u16* __restrict__ Yb, const u16* __restrict__ AuxB,
    int Ndim, int Kdim, int bm, int bn){
  __shared__ __align__(16) u16 Al[128*64];
  __shared__ __align__(16) u16 Bl[64*64];
  const int tid = threadIdx.x;
  const int wv = tid >> 6, ln = tid & 63;
  const int m16 = ln & 15, q = ln >> 4;

  f32x4 acc[2][4];
  #pragma unroll
  for (int i=0;i<2;i++)
    #pragma unroll
    for (int j=0;j<4;j++) acc[i][j] = f32x4{0.f,0.f,0.f,0.f};

  const int r0 = wv*8 + (ln >> 3);
  const int c0 = (ln & 7)*8;
  const u16* ga = X + (size_t)(bm + r0)*Kdim + c0;
  const u16* gb = W + (size_t)(bn + r0)*Kdim + c0;
  u16* la = Al + r0*64 + c0;
  u16* lb = Bl + r0*64 + c0;

  for (int k0=0; k0<Kdim; k0+=64){
    #pragma unroll
    for (int s=0;s<4;s++)
      gl_lds16(ga + (size_t)(s*32)*Kdim + k0, la + s*2048);
    #pragma unroll
    for (int s=0;s<2;s++)
      gl_lds16(gb + (size_t)(s*32)*Kdim + k0, lb + s*2048);
    __syncthreads();
    #pragma unroll
    for (int kh=0; kh<2; kh++){
      bf16x8 af[2], bfr[4];
      #pragma unroll
      for (int i=0;i<2;i++) af[i]  = *(const bf16x8*)(Al + (wv*32 + i*16 + m16)*64 + kh*32 + q*8);
      #pragma unroll
      for (int j=0;j<4;j++) bfr[j] = *(const bf16x8*)(Bl + (j*16 + m16)*64 + kh*32 + q*8);
      #pragma unroll
      for (int i=0;i<2;i++)
        #pragma unroll
        for (int j=0;j<4;j++)
          acc[i][j] = __builtin_amdgcn_mfma_f32_16x16x32_bf16(af[i], bfr[j], acc[i][j], 0, 0, 0);
    }
    __syncthreads();
  }

  #pragma unroll
  for (int i=0;i<2;i++){
    int row = bm + wv*32 + i*16 + q*4;
    #pragma unroll
    for (int j=0;j<4;j++){
      int col = bn + j*16 + m16;
      #pragma unroll
      for (int r=0;r<4;r++){
        size_t off = (size_t)(row + r)*Ndim + col;
        float v = acc[i][j][r];
        if (ACT==ACT_ADD_F32) Yf[off] += v;
        else if (ACT==ACT_CMIX){ Yf[off] += v * bf2f(AuxB[off]); }
        else if (ACT==ACT_BF16) Yb[off] = f2bf(v);
      }
    }
  }
}

// ---- 128(M) x 128(N), BK=64, 32KB LDS: 32 MFMA per K-step per wave ----
template<int ACT>
__device__ __forceinline__ void gemm128_body(const u16* __restrict__ X, const u16* __restrict__ W,
    u16* __restrict__ Yb, int Ndim, int Kdim, int bm, int bn){
  __shared__ __align__(16) u16 Al[128*64];
  __shared__ __align__(16) u16 Bl[128*64];
  const int tid = threadIdx.x;
  const int wv = tid >> 6, ln = tid & 63;
  const int m16 = ln & 15, q = ln >> 4;

  f32x4 acc[2][8];
  #pragma unroll
  for (int i=0;i<2;i++)
    #pragma unroll
    for (int j=0;j<8;j++) acc[i][j] = f32x4{0.f,0.f,0.f,0.f};

  const int r0 = wv*8 + (ln >> 3);
  const int c0 = (ln & 7)*8;
  const u16* ga = X + (size_t)(bm + r0)*Kdim + c0;
  const u16* gb = W + (size_t)(bn + r0)*Kdim + c0;
  u16* la = Al + r0*64 + c0;
  u16* lb = Bl + r0*64 + c0;

  for (int k0=0; k0<Kdim; k0+=64){
    #pragma unroll
    for (int s=0;s<4;s++)
      gl_lds16(ga + (size_t)(s*32)*Kdim + k0, la + s*2048);
    #pragma unroll
    for (int s=0;s<4;s++)
      gl_lds16(gb + (size_t)(s*32)*Kdim + k0, lb + s*2048);
    __syncthreads();
    #pragma unroll
    for (int kh=0; kh<2; kh++){
      bf16x8 af0 = *(const bf16x8*)(Al + (wv*32 + m16)*64      + kh*32 + q*8);
      bf16x8 af1 = *(const bf16x8*)(Al + (wv*32 + 16 + m16)*64 + kh*32 + q*8);
      #pragma unroll
      for (int j=0;j<8;j++){
        bf16x8 bfr = *(const bf16x8*)(Bl + (j*16 + m16)*64 + kh*32 + q*8);
        acc[0][j] = __builtin_amdgcn_mfma_f32_16x16x32_bf16(af0, bfr, acc[0][j], 0, 0, 0);
        acc[1][j] = __builtin_amdgcn_mfma_f32_16x16x32_bf16(af1, bfr, acc[1][j], 0, 0, 0);
      }
    }
    __syncthreads();
  }

  #pragma unroll
  for (int i=0;i<2;i++){
    int row = bm + wv*32 + i*16 + q*4;
    #pragma unroll
    for (int j=0;j<8;j++){
      int col = bn + j*16 + m16;
      #pragma unroll
      for (int r=0;r<4;r++){
        size_t off = (size_t)(row + r)*Ndim + col;
        float v = acc[i][j][r];
        if (ACT==ACT_BF16) Yb[off] = f2bf(v);
        else if (ACT==ACT_RELU2_BF16){ float rr = v>0.f ? v : 0.f; Yb[off] = f2bf(rr*rr); }
        else if (ACT==ACT_SIG_BF16) Yb[off] = f2bf(1.f/(1.f+expf(-v)));
      }
    }
  }
}

// fused r/k/v/g projections, 128x128 tiles, grid (64,4,4)
__global__ __launch_bounds__(256,3) void gemm4_mfma(const u16* const* __restrict__ ptab, int l,
    const u16* __restrict__ Abase,
    u16* __restrict__ Rb, u16* __restrict__ Kb, u16* __restrict__ Vb, u16* __restrict__ Gb){
  const size_t MC = (size_t)M_*C_;
  const size_t ws = (size_t)l*C_*C_;
  const int bm = blockIdx.x*128, bn = blockIdx.y*128;
  switch (blockIdx.z){
    case 0:  gemm128_body<ACT_BF16>(Abase + 2*MC, ptab[12]+ws, Rb, C_, C_, bm, bn); break;
    case 1:  gemm128_body<ACT_BF16>(Abase,        ptab[13]+ws, Kb, C_, C_, bm, bn); break;
    case 2:  gemm128_body<ACT_BF16>(Abase + 1*MC, ptab[14]+ws, Vb, C_, C_, bm, bn); break;
    default: gemm128_body<ACT_BF16>(Abase + 3*MC, ptab[15]+ws, Gb, C_, C_, bm, bn); break;
  }
}

// fused cmix key (relu^2 -> H1) + receptance gate (sigmoid -> RRb), 128x128, grid (64,16)
__global__ __launch_bounds__(256,3) void gemm_ck_cr(const u16* const* __restrict__ ptab, int l,
    const u16* __restrict__ MK, u16* __restrict__ H1,
    const u16* __restrict__ MV, u16* __restrict__ RRb){
  if (blockIdx.y < 12)
    gemm128_body<ACT_RELU2_BF16>(MK, ptab[21]+(size_t)l*3*C_*C_, H1, 3*C_, C_,
                                 blockIdx.x*128, blockIdx.y*128);
  else
    gemm128_body<ACT_SIG_BF16>(MV, ptab[23]+(size_t)l*C_*C_, RRb, C_, C_,
                               blockIdx.x*128, (blockIdx.y-12)*128);
}

// output projection with residual add: X += YGN @ Wo^T   (grid 64x8, 128x64)
__global__ __launch_bounds__(256,4) void gemm_wo(const u16* const* __restrict__ ptab, int l,
    const u16* __restrict__ YGN, float* __restrict__ X){
  gemm_mfma_body<ACT_ADD_F32>(YGN, ptab[16]+(size_t)l*C_*C_, X, nullptr, nullptr,
                              C_, C_, blockIdx.x*128, blockIdx.y*64);
}

// cmix value GEMM with fused tail: X += gate * (H1 @ Wcv^T)   (grid 64x8, 128x64)
__global__ __launch_bounds__(256,4) void gemm_cmix(const u16* const* __restrict__ ptab, int l,
    const u16* __restrict__ H1, float* __restrict__ X, const u16* __restrict__ RRb){
  gemm_mfma_body<ACT_CMIX>(H1, ptab[22]+(size_t)l*3*C_*C_, X, nullptr, RRb,
                           C_, 3*C_, blockIdx.x*128, blockIdx.y*64);
}

// ---------------- K/V per-(b,h) transpose; K gets wdec^(Q-1-tloc) scale ----------------
// grid (T/64, B*H, 2): z=0 V->Vt plain, z=1 K->Kt scaled
__global__ __launch_bounds__(256) void kvtrans(const u16* __restrict__ Kb, const u16* __restrict__ Vb,
    u16* __restrict__ Kt, u16* __restrict__ Vt, const u16* const* __restrict__ ptab, int l){
  __shared__ __align__(16) u16 tile[64*64];
  const int t0 = blockIdx.x*64, bh = blockIdx.y, b = bh>>3, h = bh&7;
  const bool isK = (blockIdx.z == 1);
  const u16* src = isK ? Kb : Vb;
  u16* dst = isK ? Kt : Vt;
  float l2w = 0.f;
  if (isK){
    const u16* td = ptab[10] + l*H_;
    l2w = -expf(bf2f(td[h])) * 1.44269504f;
  }
  const int tid = threadIdx.x;
  #pragma unroll
  for (int it=0; it<2; ++it){
    int tl = it*32 + (tid>>3);
    int n0 = (tid&7)*8;
    union {uint4 q; u16 e[8];} v;
    v.q = *(const uint4*)(src + ((size_t)(b*T_ + t0 + tl))*C_ + h*N_ + n0);
    if (isK){
      int tloc = (t0 + tl) & (Q_-1);
      float sc = exp2f(l2w * (float)(Q_-1 - tloc));
      #pragma unroll
      for (int e=0;e<8;++e) v.e[e] = f2bf(bf2f(v.e[e])*sc);
    }
    int col = n0 ^ (((tl>>3)&7)<<3);
    *(uint4*)&tile[tl*64 + col] = v.q;
  }
  __syncthreads();
  #pragma unroll
  for (int it=0; it<2; ++it){
    int nl = it*32 + (tid>>3);
    int t0l = (tid&7)*8;
    int swz = (tid&7)<<3;
    union {uint4 q; u16 h2[8];} pk;
    #pragma unroll
    for (int e=0;e<8;++e)
      pk.h2[e] = tile[(t0l+e)*64 + (nl ^ swz)];
    *(uint4*)(dst + ((size_t)(bh*N_ + nl))*T_ + t0 + t0l) = pk.q;
  }
}

// ---------------- per-chunk state S_c = (k*wkv)^T @ v via MFMA on Kt(scaled)/Vt ----------------
__global__ __launch_bounds__(256) void wkv_state_mfma(const u16* __restrict__ Kt,
    const u16* __restrict__ Vt, float* __restrict__ S){
  const int c = blockIdx.x, bh = blockIdx.y;
  const int tid = threadIdx.x, wv = tid >> 6, ln = tid & 63;
  const int m16 = ln & 15, q = ln >> 4;
  const u16* ka = Kt + (size_t)(bh*N_ + wv*16 + m16)*T_ + c*Q_;
  const u16* vb = Vt + (size_t)(bh*N_ + m16)*T_ + c*Q_;
  f32x4 acc[4];
  #pragma unroll
  for (int nt=0;nt<4;++nt) acc[nt] = f32x4{0.f,0.f,0.f,0.f};
  #pragma unroll
  for (int ks=0; ks<8; ++ks){
    bf16x8 af = *(const bf16x8*)(ka + ks*32 + q*8);
    #pragma unroll
    for (int nt=0;nt<4;++nt){
      bf16x8 bv = *(const bf16x8*)(vb + (size_t)(nt*16)*T_ + ks*32 + q*8);
      acc[nt] = __builtin_amdgcn_mfma_f32_16x16x32_bf16(af, bv, acc[nt], 0,0,0);
    }
  }
  float* Sp = S + ((size_t)bh*NC_ + c)*(N_*N_);
  #pragma unroll
  for (int nt=0;nt<4;++nt)
    #pragma unroll
    for (int r=0;r<4;++r)
      Sp[(wv*16 + q*4 + r)*N_ + nt*16 + m16] = acc[nt][r];
}

// ---------------- sequential prefix over chunks ----------------
__global__ __launch_bounds__(256) void wkv_prefix(float* __restrict__ S,
    const u16* const* __restrict__ ptab, int l){
  const int bh = blockIdx.x, h = bh&7;
  const u16* td = ptab[10] + l*H_;
  const float l2w = -expf(bf2f(td[h])) * 1.44269504f;
  const float wsd = exp2f(l2w * (float)Q_);
  float* Sp = S + (size_t)bh*NC_*N_*N_;
  for (int e=threadIdx.x; e<N_*N_; e+=256){
    float cur = 0.f;
    for (int cc=0;cc<NC_;++cc){
      float sc = Sp[(size_t)cc*N_*N_ + e];
      Sp[(size_t)cc*N_*N_ + e] = cur;
      cur = wsd*cur + sc;
    }
  }
}

// ---------------- FUSED WKV: intra (MFMA) + inter (VALU r@S) + GroupNorm + silu(g) ----------------
__global__ __launch_bounds__(256) void wkv_fused(const u16* __restrict__ Rb,
    const u16* __restrict__ Kb, const u16* __restrict__ Vt, const float* __restrict__ S,
    const u16* const* __restrict__ ptab, int l,
    const u16* __restrict__ g, u16* __restrict__ out){
  __shared__ float wpow[Q_];
  __shared__ float st[64][68];                 // prefix state (f32)
  __shared__ float rs[64][68];                 // r rows (f32, for inter VALU)
  __shared__ __align__(16) float ylds[64][68]; // intra result; P tile aliases this region
  u16 (*P)[16][72] = reinterpret_cast<u16(*)[16][72]>(&ylds[0][0]);
  const u16* td  = ptab[10] + l*H_;
  const u16* tf  = ptab[11] + l*H_;
  const u16* gnw = ptab[17] + l*C_;
  const u16* gnb = ptab[18] + l*C_;
  const int c = blockIdx.x>>2, ip = blockIdx.x&3;
  const int bh = blockIdx.y, b = bh>>3, h = bh&7;
  const int tid = threadIdx.x, wv = tid >> 6, ln = tid & 63;
  const int m16 = ln & 15, q = ln >> 4;
  const int tx = tid&15, ty = tid>>4;
  const float l2w = -expf(bf2f(td[h])) * 1.44269504f;
  const float uu = bf2f(tf[h]);
  wpow[tid] = exp2f(l2w * (float)tid);
  const float* Sp = S + ((size_t)bh*NC_ + c)*(N_*N_);
  for (int e=tid;e<N_*N_;e+=256) st[e>>6][e&63] = Sp[e];
  const size_t base = ((size_t)b*T_ + (size_t)c*Q_)*C_ + h*N_;
  const int i0 = ip*64;
  {
    const int rrr = tid >> 6, cc2 = tid & 63;
    for (int it=0;it<16;++it){ int i=it*4+rrr; rs[i][cc2]=bf2f(Rb[base+(size_t)(i0+i)*C_+cc2]); }
  }
  __syncthreads();
  // ---- intra-chunk (MFMA) ----
  const int iw0 = ip*64 + wv*16;
  const u16* rrow = Rb + base + (size_t)(iw0 + m16)*C_;
  bf16x8 af0 = *(const bf16x8*)(rrow + q*8);
  bf16x8 af1 = *(const bf16x8*)(rrow + 32 + q*8);
  f32x4 acc[4];
  #pragma unroll
  for (int nt=0;nt<4;++nt) acc[nt] = f32x4{0.f,0.f,0.f,0.f};
  const int irow = iw0 + q*4;
  const u16* vtb = Vt + (size_t)(bh*N_)*T_ + (size_t)c*Q_;
  for (int jt=0; jt<=ip; ++jt){
    f32x4 s[4];
    #pragma unroll
    for (int j2=0;j2<4;++j2) s[j2] = f32x4{0.f,0.f,0.f,0.f};
    #pragma unroll
    for (int j2=0;j2<4;++j2){
      const u16* kr = Kb + base + (size_t)(jt*64 + j2*16 + m16)*C_;
      bf16x8 b0 = *(const bf16x8*)(kr + q*8);
      bf16x8 b1 = *(const bf16x8*)(kr + 32 + q*8);
      s[j2] = __builtin_amdgcn_mfma_f32_16x16x32_bf16(af0, b0, s[j2], 0,0,0);
      s[j2] = __builtin_amdgcn_mfma_f32_16x16x32_bf16(af1, b1, s[j2], 0,0,0);
    }
    #pragma unroll
    for (int j2=0;j2<4;++j2){
      int jc = jt*64 + j2*16 + m16;
      #pragma unroll
      for (int r=0;r<4;++r){
        int ic = irow + r;
        float w = (jc < ic) ? wpow[ic-jc-1] : ((jc==ic) ? uu : 0.f);
        P[wv][q*4+r][j2*16+m16] = f2bf(s[j2][r]*w);
      }
    }
    __asm__ volatile("s_waitcnt lgkmcnt(0)" ::: "memory");
    #pragma unroll
    for (int kp=0;kp<2;++kp){
      bf16x8 ap = *(const bf16x8*)&P[wv][m16][kp*32 + q*8];
      #pragma unroll
      for (int nt=0;nt<4;++nt){
        bf16x8 bv = *(const bf16x8*)(vtb + (size_t)(nt*16 + m16)*T_ + jt*64 + kp*32 + q*8);
        acc[nt] = __builtin_amdgcn_mfma_f32_16x16x32_bf16(ap, bv, acc[nt], 0,0,0);
      }
    }
  }
  __syncthreads();   // all waves done with P region -> safe to write ylds (aliased)
  #pragma unroll
  for (int nt=0;nt<4;++nt)
    #pragma unroll
    for (int r=0;r<4;++r)
      ylds[wv*16 + q*4 + r][nt*16 + m16] = acc[nt][r];
  __syncthreads();
  // ---- inter-chunk (VALU r@S) ----
  float acc2[4][4] = {};
  #pragma unroll
  for (int kk4=0;kk4<16;++kk4){
    f32x4 sv[4], rv[4];
    #pragma unroll
    for (int kkk=0;kkk<4;++kkk) sv[kkk] = *(const f32x4*)&st[kk4*4+kkk][tx*4];
    #pragma unroll
    for (int ii=0;ii<4;++ii)    rv[ii]  = *(const f32x4*)&rs[ty*4+ii][kk4*4];
    #pragma unroll
    for (int ii=0;ii<4;++ii)
      #pragma unroll
      for (int kkk=0;kkk<4;++kkk)
        #pragma unroll
        for (int nn=0;nn<4;++nn)
          acc2[ii][nn] += rv[ii][kkk]*sv[kkk][nn];
  }
  // ---- GroupNorm + silu(g), 16-lane reduce ----
  #pragma unroll
  for (int ii=0;ii<4;ii++){
    int tl = ty*4+ii;
    int il = i0 + tl;
    size_t roff = base + (size_t)il*C_;
    float w = wpow[il];
    f32x4 yv = *(const f32x4*)&ylds[tl][tx*4];
    float val[4];
    float s=0.f, ss=0.f;
    #pragma unroll
    for (int nn=0;nn<4;nn++){
      float v = yv[nn] + w*acc2[ii][nn];
      val[nn]=v; s+=v; ss+=v*v;
    }
    #pragma unroll
    for (int o=8;o>0;o>>=1){ s+=__shfl_xor(s,o,64); ss+=__shfl_xor(ss,o,64); }
    float mu = s*(1.f/N_);
    float var = ss*(1.f/N_) - mu*mu;
    float inv = rsqrtf(fmaxf(var,0.f) + 6.4e-4f);   // GN_EPS = 1e-5*64
    union { ushort4 v; u16 e[4]; } gv, ov;
    gv.v = *(const ushort4*)(g + roff + tx*4);
    #pragma unroll
    for (int nn=0;nn<4;nn++){
      int ci = h*N_ + tx*4 + nn;
      float gg = bf2f(gv.e[nn]);
      float sil = gg/(1.f+expf(-gg));
      ov.e[nn] = f2bf(((val[nn]-mu)*inv*bf2f(gnw[ci]) + bf2f(gnb[ci]))*sil);
    }
    *(ushort4*)(out + roff + tx*4) = ov.v;
  }
}

// ---------------- logits for last position: [B,V] = xf @ wte^T ----------------
__global__ __launch_bounds__(256) void logits_kernel(const float* __restrict__ xf,
    const u16* const* __restrict__ ptab, void* __restrict__ out, const int* __restrict__ flag){
  const u16* wte = ptab[1];
  const int wid = threadIdx.x>>6, lane = threadIdx.x&63;
  const int gw = blockIdx.x*4 + wid;     // 0 .. B*V-1
  const int b = gw / V_, v = gw - b*V_;
  const u16* wrow = wte + (size_t)v*C_;
  const float* xr = xf + b*C_;
  union {uint4 q; u16 h[8];} uu;
  uu.q = *(const uint4*)(wrow + lane*8);
  float s = 0.f;
  #pragma unroll
  for (int j=0;j<8;j++) s += bf2f(uu.h[j])*xr[lane*8+j];
  #pragma unroll
  for (int o=32;o>0;o>>=1) s += __shfl_down(s,o,64);
  if (lane==0){
    size_t o = (size_t)b*V_ + v;
    if (*flag) ((float*)out)[o] = s;          // fp32 harness
    else       ((u16*)out)[o]   = f2bf(s);    // bf16 harness
  }
}

extern "C" void kernel_launch(void* const* d_in, const int* in_sizes, int n_in,
                              void* d_out, int out_size, void* d_ws, size_t ws_size,
                              hipStream_t stream){
  (void)out_size; (void)ws_size; (void)n_in;
  const int* idx  = (const int*)d_in[0];

  char* ws = (char*)d_ws;
  const size_t MC  = (size_t)M_*C_;
  // ---- workspace layout (bytes) ----
  size_t o = 0;
  int* flag = (int*)(ws + o);            o += 1024;
  const u16** ptab = (const u16**)(ws + o); o += 1024;
  float* X   = (float*)(ws + o);         o += MC*4;            // fp32 residual
  u16* MK = (u16*)(ws + o);              o += MC*2;            // also YGN
  u16* MV = (u16*)(ws + o);              o += MC*2;
  u16* MR = (u16*)(ws + o);              o += MC*2;            // also S (tmix) / RRb (cmix)
  u16* MG = (u16*)(ws + o);              o += MC*2;
  u16* Rb = (u16*)(ws + o);              o += MC*2;            // H1 spans Rb..Vb
  u16* Kb = (u16*)(ws + o);              o += MC*2;
  u16* Vb = (u16*)(ws + o);              o += MC*2;
  u16* Gb = (u16*)(ws + o);              o += MC*2;
  u16* Kt = (u16*)(ws + o);              o += MC*2;            // scaled k^T per (b,h): [BH*64, T]
  u16* Vt = (u16*)(ws + o);              o += MC*2;            // v^T per (b,h): [BH*64, T]
  float* XF = (float*)(ws + o);          o += 65536;
  u16* pool = (u16*)(ws + o);            // fp32->bf16 converted inputs (only if needed)
  u16* YGN = MK;
  float* S  = (float*)MR;    // live only during tmix phase (4 MB < 8.4 MB)
  u16* H1 = Rb;              // [M,3C] bf16, spans Rb..Vb
  u16* RRb = MR;             // [M,C] bf16 sigmoid gate (cmix phase)

  // ---- dtype detect + pointer table + (conditional) conversion ----
  detect_kernel<<<1,256,0,stream>>>(d_in[12], flag);   // probe Wr
  CvtTab tab; PtrTab pt;
  int nblocks;
  {
    size_t poff = 0; int acc8 = 0, bacc = 0;
    long long total8 = 0;
    for (int i=1;i<24;i++) total8 += (long long)(in_sizes[i] >> 3);
    for (int i=1;i<24;i++){
      pt.raw[i-1] = d_in[i];
      pt.off[i-1] = (long long)poff;
      poff += (size_t)in_sizes[i];
      tab.s[i-1] = d_in[i];
      tab.off8[i-1] = acc8;
      tab.bstart[i-1] = bacc;
      int n8 = in_sizes[i] >> 3;
      int nb = (int)(((long long)n8 * 2048 + total8 - 1) / total8);
      if (nb < 1) nb = 1;
      acc8 += n8; bacc += nb;
    }
    tab.off8[23] = acc8; tab.bstart[23] = bacc;
    nblocks = bacc;
  }
  fill_ptab<<<1,64,0,stream>>>(pt, pool, flag, ptab);
  convert_all<<<nblocks,256,0,stream>>>(tab, pool, flag);

  embed_kernel<<<M_,256,0,stream>>>(idx, ptab, X);
  dim3 g4 (M_/128, C_/128, 4);     // (64,4,4) fused projections, 128x128
  dim3 gkv(T_/64, B_*H_, 2);       // K/V transpose
  dim3 gck(M_/128, 16);            // 12 ck tiles + 4 cr tiles, 128x128
  dim3 gwo(M_/128, C_/64);         // (64,8) 128x64
  for (int l=0;l<L_;++l){
    // ---- time mix ----
    ln_tmix_kernel<<<M_,256,0,stream>>>(X, ptab, l, MK,MV,MR,MG);
    gemm4_mfma<<<g4,256,0,stream>>>(ptab, l, MK, Rb, Kb, Vb, Gb);
    kvtrans<<<gkv,256,0,stream>>>(Kb, Vb, Kt, Vt, ptab, l);
    wkv_state_mfma<<<dim3(NC_, B_*H_),256,0,stream>>>(Kt, Vt, S);
    wkv_prefix<<<B_*H_,256,0,stream>>>(S, ptab, l);
    wkv_fused<<<dim3(NC_*4, B_*H_),256,0,stream>>>(Rb, Kb, Vt, S, ptab, l, Gb, YGN);
    gemm_wo<<<gwo,256,0,stream>>>(ptab, l, YGN, X);
    // ---- channel mix ----
    ln_cmix_kernel<<<M_,256,0,stream>>>(X, ptab, l, MK, MV);
    gemm_ck_cr<<<gck,256,0,stream>>>(ptab, l, MK, H1, MV, RRb);
    gemm_cmix<<<gwo,256,0,stream>>>(ptab, l, H1, X, RRb);
  }
  lnf_last<<<B_,256,0,stream>>>(X, ptab, XF);
  logits_kernel<<<(B_*V_)/4,256,0,stream>>>(XF, ptab, d_out, flag);
}

// Round 5
// 1583.872 us; speedup vs baseline: 1.0806x; 1.0806x over previous
//
#include <hip/hip_runtime.h>

#define L_ 6
#define H_ 8
#define C_ 512
#define V_ 32000
#define B_ 2
#define T_ 4096
#define Q_ 256
#define N_ 64
#define NC_ 16
#define M_ 8192   // B*T

typedef unsigned short u16;
typedef __attribute__((ext_vector_type(8))) short bf16x8;
typedef __attribute__((ext_vector_type(4))) float f32x4;

__device__ __forceinline__ float bf2f(u16 u){
  return __uint_as_float(((unsigned int)u) << 16);
}
__device__ __forceinline__ u16 f2bf(float f){
  unsigned int x = __float_as_uint(f);
  return (u16)((x + 0x7fffu + ((x >> 16) & 1u)) >> 16);
}

__device__ __forceinline__ void gl_lds16(const u16* g, u16* l){
  __builtin_amdgcn_global_load_lds((const __attribute__((address_space(1))) void*)g,
                                   (__attribute__((address_space(3))) void*)l, 16, 0, 0);
}

// ---------------- dtype detection: bf16 weights never have |x|>=2 ----------------
__global__ __launch_bounds__(256) void detect_kernel(const void* __restrict__ probe,
                                                     int* __restrict__ flag){
  __shared__ int cnt;
  if (threadIdx.x == 0) cnt = 0;
  __syncthreads();
  const u16* p = (const u16*)probe;
  int c = 0;
  for (int i = threadIdx.x; i < 2048; i += 256){
    int e = (p[i] >> 7) & 0xFF;
    if (e >= 128) c++;
  }
  atomicAdd(&cnt, c);
  __syncthreads();
  if (threadIdx.x == 0) *flag = (cnt > 32) ? 1 : 0;  // 1 = inputs are fp32
}

// ---------------- pointer table: bf16 -> use raw inputs in place; fp32 -> converted pool ----------------
struct PtrTab { const void* raw[23]; long long off[23]; };

__global__ __launch_bounds__(64) void fill_ptab(PtrTab pt, const u16* __restrict__ pool,
    const int* __restrict__ flag, const u16** __restrict__ ptab){
  int i = threadIdx.x;
  if (i < 23)
    ptab[i+1] = (*flag) ? (pool + pt.off[i]) : (const u16*)pt.raw[i];
}

// ---------------- fp32 -> bf16 conversion (only runs when inputs are fp32) ----------------
struct CvtTab { const void* s[23]; int off8[24]; int bstart[24]; };

__global__ __launch_bounds__(256) void convert_all(CvtTab t, u16* __restrict__ pool,
                                                   const int* __restrict__ flag){
  if (!*flag) return;    // bf16 inputs are consumed in place via ptab
  int i = 0;
  #pragma unroll
  for (int k = 1; k < 23; k++) if ((int)blockIdx.x >= t.bstart[k]) i = k;
  const void* sp = t.s[0];
  #pragma unroll
  for (int k = 1; k < 23; k++) if (i == k) sp = t.s[k];
  const int n8 = t.off8[i+1] - t.off8[i];
  const int nb = t.bstart[i+1] - t.bstart[i];
  const int lb = (int)blockIdx.x - t.bstart[i];
  uint4* dp = (uint4*)pool + t.off8[i];
  const int stride = nb * 256;
  const float4* sf = (const float4*)sp;
  for (int j = lb*256 + (int)threadIdx.x; j < n8; j += stride){
    float4 a0 = sf[2*j], a1 = sf[2*j+1];
    uint4 r0;
    r0.x = (unsigned)f2bf(a0.x) | ((unsigned)f2bf(a0.y) << 16);
    r0.y = (unsigned)f2bf(a0.z) | ((unsigned)f2bf(a0.w) << 16);
    r0.z = (unsigned)f2bf(a1.x) | ((unsigned)f2bf(a1.y) << 16);
    r0.w = (unsigned)f2bf(a1.z) | ((unsigned)f2bf(a1.w) << 16);
    dp[j] = r0;
  }
}

// ---------------- embedding: x = wte[idx] + wpe ----------------
__global__ __launch_bounds__(256) void embed_kernel(const int* __restrict__ idx,
    const u16* const* __restrict__ ptab, float* __restrict__ x){
  const u16* wte = ptab[1];
  const u16* wpe = ptab[2];
  int row = blockIdx.x;                 // b*T + t
  int t = row & (T_-1);
  int tok = idx[row];
  const u16* we = wte + (size_t)tok * C_;
  const u16* wp = wpe + (size_t)t * C_;
  float* xo = x + (size_t)row * C_;
  int c = threadIdx.x;
  xo[c]     = bf2f(we[c])     + bf2f(wp[c]);
  xo[c+256] = bf2f(we[c+256]) + bf2f(wp[c+256]);
}

// ---------------- fused LN + time-mix token shift (recomputes LN of row t-1) ----------------
__global__ __launch_bounds__(256) void ln_tmix_kernel(const float* __restrict__ x,
    const u16* const* __restrict__ ptab, int l,
    u16* __restrict__ xk, u16* __restrict__ xv, u16* __restrict__ xr, u16* __restrict__ xg){
  const u16* w  = ptab[3] + l*C_;
  const u16* mk = ptab[6] + l*C_;
  const u16* mv = ptab[7] + l*C_;
  const u16* mr = ptab[8] + l*C_;
  const u16* mg = ptab[9] + l*C_;
  int row = blockIdx.x; int t = row & (T_-1);
  size_t off = (size_t)row*C_;
  const float* cur = x + off;
  int c = threadIdx.x;
  float v0 = cur[c], v1 = cur[c+256];
  float p0 = 0.f, p1 = 0.f;
  if (t){ p0 = cur[c - C_]; p1 = cur[c+256 - C_]; }
  float s = v0+v1, ss = v0*v0+v1*v1;
  float sp = p0+p1, ssp = p0*p0+p1*p1;
  int lane = c & 63, wid = c >> 6;
  #pragma unroll
  for (int o=32;o>0;o>>=1){
    s  += __shfl_down(s,o,64);  ss  += __shfl_down(ss,o,64);
    sp += __shfl_down(sp,o,64); ssp += __shfl_down(ssp,o,64);
  }
  __shared__ float r1[4], r2[4], r3[4], r4[4];
  if (lane==0){ r1[wid]=s; r2[wid]=ss; r3[wid]=sp; r4[wid]=ssp; }
  __syncthreads();
  if (c==0){
    float a =r1[0]+r1[1]+r1[2]+r1[3], bq=r2[0]+r2[1]+r2[2]+r2[3];
    float ap=r3[0]+r3[1]+r3[2]+r3[3], bp=r4[0]+r4[1]+r4[2]+r4[3];
    float mu  = a *(1.f/C_); float var  = bq*(1.f/C_) - mu*mu;
    float mup = ap*(1.f/C_); float varp = bp*(1.f/C_) - mup*mup;
    r1[0]=mu;  r2[0]=rsqrtf(fmaxf(var ,0.f)+1e-5f);
    r3[0]=mup; r4[0]=rsqrtf(fmaxf(varp,0.f)+1e-5f);
  }
  __syncthreads();
  float mu=r1[0], inv=r2[0], mup=r3[0], invp=r4[0];
  #pragma unroll
  for (int p=0;p<2;p++){
    int cc = c + p*256;
    float wc = bf2f(w[cc]);
    float xc = ((p?v1:v0)-mu)*inv*wc;
    float xp = t ? ((p?p1:p0)-mup)*invp*wc : 0.f;
    float xx = xp - xc;
    xk[off+cc] = f2bf(xc + xx*bf2f(mk[cc]));
    xv[off+cc] = f2bf(xc + xx*bf2f(mv[cc]));
    xr[off+cc] = f2bf(xc + xx*bf2f(mr[cc]));
    xg[off+cc] = f2bf(xc + xx*bf2f(mg[cc]));
  }
}

// ---------------- fused LN + channel-mix token shift ----------------
__global__ __launch_bounds__(256) void ln_cmix_kernel(const float* __restrict__ x,
    const u16* const* __restrict__ ptab, int l,
    u16* __restrict__ xk, u16* __restrict__ xr){
  const u16* w  = ptab[4]  + l*C_;
  const u16* mk = ptab[19] + l*C_;
  const u16* mr = ptab[20] + l*C_;
  int row = blockIdx.x; int t = row & (T_-1);
  size_t off = (size_t)row*C_;
  const float* cur = x + off;
  int c = threadIdx.x;
  float v0 = cur[c], v1 = cur[c+256];
  float p0 = 0.f, p1 = 0.f;
  if (t){ p0 = cur[c - C_]; p1 = cur[c+256 - C_]; }
  float s = v0+v1, ss = v0*v0+v1*v1;
  float sp = p0+p1, ssp = p0*p0+p1*p1;
  int lane = c & 63, wid = c >> 6;
  #pragma unroll
  for (int o=32;o>0;o>>=1){
    s  += __shfl_down(s,o,64);  ss  += __shfl_down(ss,o,64);
    sp += __shfl_down(sp,o,64); ssp += __shfl_down(ssp,o,64);
  }
  __shared__ float r1[4], r2[4], r3[4], r4[4];
  if (lane==0){ r1[wid]=s; r2[wid]=ss; r3[wid]=sp; r4[wid]=ssp; }
  __syncthreads();
  if (c==0){
    float a =r1[0]+r1[1]+r1[2]+r1[3], bq=r2[0]+r2[1]+r2[2]+r2[3];
    float ap=r3[0]+r3[1]+r3[2]+r3[3], bp=r4[0]+r4[1]+r4[2]+r4[3];
    float mu  = a *(1.f/C_); float var  = bq*(1.f/C_) - mu*mu;
    float mup = ap*(1.f/C_); float varp = bp*(1.f/C_) - mup*mup;
    r1[0]=mu;  r2[0]=rsqrtf(fmaxf(var ,0.f)+1e-5f);
    r3[0]=mup; r4[0]=rsqrtf(fmaxf(varp,0.f)+1e-5f);
  }
  __syncthreads();
  float mu=r1[0], inv=r2[0], mup=r3[0], invp=r4[0];
  #pragma unroll
  for (int p=0;p<2;p++){
    int cc = c + p*256;
    float wc = bf2f(w[cc]);
    float xc = ((p?v1:v0)-mu)*inv*wc;
    float xp = t ? ((p?p1:p0)-mup)*invp*wc : 0.f;
    float xx = xp - xc;
    xk[off+cc] = f2bf(xc + xx*bf2f(mk[cc]));
    xr[off+cc] = f2bf(xc + xx*bf2f(mr[cc]));
  }
}

// ---------------- final LN for last position only ----------------
__global__ __launch_bounds__(256) void lnf_last(const float* __restrict__ x,
    const u16* const* __restrict__ ptab, float* __restrict__ xf){
  const u16* w = ptab[5];
  int b = blockIdx.x;
  const float* xr = x + ((size_t)b*T_ + (T_-1))*C_;
  int c = threadIdx.x;
  float v0 = xr[c], v1 = xr[c+256];
  float s = v0+v1, ss = v0*v0+v1*v1;
  int lane = c & 63, wid = c >> 6;
  #pragma unroll
  for (int o=32;o>0;o>>=1){ s += __shfl_down(s,o,64); ss += __shfl_down(ss,o,64); }
  __shared__ float r1[4], r2[4];
  if (lane==0){ r1[wid]=s; r2[wid]=ss; }
  __syncthreads();
  if (c==0){
    float a=r1[0]+r1[1]+r1[2]+r1[3], bq=r2[0]+r2[1]+r2[2]+r2[3];
    float mu = a*(1.f/C_);
    float var = bq*(1.f/C_) - mu*mu;
    r1[0]=mu; r2[0]=rsqrtf(fmaxf(var,0.f)+1e-5f);
  }
  __syncthreads();
  float mu=r1[0], inv=r2[0];
  xf[b*C_+c]     = (v0-mu)*inv*bf2f(w[c]);
  xf[b*C_+c+256] = (v1-mu)*inv*bf2f(w[c+256]);
}

// ================= MFMA GEMM: 128(M) x 64(N), BK=64, 24KB LDS (R1-proven) =================
#define ACT_RELU2_BF16 1
#define ACT_ADD_F32 2
#define ACT_BF16 3
#define ACT_CMIX 4      // Yf += v * bf2f(AuxB) (AuxB holds sigmoid gate)
#define ACT_SIG_BF16 7  // Yb = bf16(sigmoid(v))

template<int ACT>
__device__ __forceinline__ void gemm_mfma_body(const u16* __restrict__ X, const u16* __restrict__ W,
    float* __restrict__ Yf, u16* __restrict__ Yb, const u16* __restrict__ AuxB,
    int Ndim, int Kdim, int bm, int bn){
  __shared__ __align__(16) u16 Al[128*64];
  __shared__ __align__(16) u16 Bl[64*64];
  const int tid = threadIdx.x;
  const int wv = tid >> 6, ln = tid & 63;
  const int m16 = ln & 15, q = ln >> 4;

  f32x4 acc[2][4];
  #pragma unroll
  for (int i=0;i<2;i++)
    #pragma unroll
    for (int j=0;j<4;j++) acc[i][j] = f32x4{0.f,0.f,0.f,0.f};

  const int r0 = wv*8 + (ln >> 3);
  const int c0 = (ln & 7)*8;
  const u16* ga = X + (size_t)(bm + r0)*Kdim + c0;
  const u16* gb = W + (size_t)(bn + r0)*Kdim + c0;
  u16* la = Al + r0*64 + c0;
  u16* lb = Bl + r0*64 + c0;

  for (int k0=0; k0<Kdim; k0+=64){
    #pragma unroll
    for (int s=0;s<4;s++)
      gl_lds16(ga + (size_t)(s*32)*Kdim + k0, la + s*2048);
    #pragma unroll
    for (int s=0;s<2;s++)
      gl_lds16(gb + (size_t)(s*32)*Kdim + k0, lb + s*2048);
    __syncthreads();
    #pragma unroll
    for (int kh=0; kh<2; kh++){
      bf16x8 af[2], bfr[4];
      #pragma unroll
      for (int i=0;i<2;i++) af[i]  = *(const bf16x8*)(Al + (wv*32 + i*16 + m16)*64 + kh*32 + q*8);
      #pragma unroll
      for (int j=0;j<4;j++) bfr[j] = *(const bf16x8*)(Bl + (j*16 + m16)*64 + kh*32 + q*8);
      #pragma unroll
      for (int i=0;i<2;i++)
        #pragma unroll
        for (int j=0;j<4;j++)
          acc[i][j] = __builtin_amdgcn_mfma_f32_16x16x32_bf16(af[i], bfr[j], acc[i][j], 0, 0, 0);
    }
    __syncthreads();
  }

  // epilogue: C/D layout col=lane&15, row=quad*4+reg
  #pragma unroll
  for (int i=0;i<2;i++){
    int row = bm + wv*32 + i*16 + q*4;
    #pragma unroll
    for (int j=0;j<4;j++){
      int col = bn + j*16 + m16;
      #pragma unroll
      for (int r=0;r<4;r++){
        size_t off = (size_t)(row + r)*Ndim + col;
        float v = acc[i][j][r];
        if (ACT==ACT_ADD_F32) Yf[off] += v;
        else if (ACT==ACT_CMIX){ Yf[off] += v * bf2f(AuxB[off]); }
        else if (ACT==ACT_BF16) Yb[off] = f2bf(v);
        else if (ACT==ACT_RELU2_BF16){ float rr = v>0.f ? v : 0.f; Yb[off] = f2bf(rr*rr); }
        else if (ACT==ACT_SIG_BF16) Yb[off] = f2bf(1.f/(1.f+expf(-v)));
      }
    }
  }
}

// fused r/k/v/g projections, 128x64 tiles, grid (64,8,4)
__global__ __launch_bounds__(256,4) void gemm4_mfma(const u16* const* __restrict__ ptab, int l,
    const u16* __restrict__ Abase,
    u16* __restrict__ Rb, u16* __restrict__ Kb, u16* __restrict__ Vb, u16* __restrict__ Gb){
  const size_t MC = (size_t)M_*C_;
  const size_t ws = (size_t)l*C_*C_;
  const int bm = blockIdx.x*128, bn = blockIdx.y*64;
  switch (blockIdx.z){
    case 0:  gemm_mfma_body<ACT_BF16>(Abase + 2*MC, ptab[12]+ws, nullptr, Rb, nullptr, C_, C_, bm, bn); break;
    case 1:  gemm_mfma_body<ACT_BF16>(Abase,        ptab[13]+ws, nullptr, Kb, nullptr, C_, C_, bm, bn); break;
    case 2:  gemm_mfma_body<ACT_BF16>(Abase + 1*MC, ptab[14]+ws, nullptr, Vb, nullptr, C_, C_, bm, bn); break;
    default: gemm_mfma_body<ACT_BF16>(Abase + 3*MC, ptab[15]+ws, nullptr, Gb, nullptr, C_, C_, bm, bn); break;
  }
}

// fused cmix key (relu^2 -> H1) + receptance gate (sigmoid -> RRb), 128x64, grid (64,32)
__global__ __launch_bounds__(256,4) void gemm_ck_cr(const u16* const* __restrict__ ptab, int l,
    const u16* __restrict__ MK, u16* __restrict__ H1,
    const u16* __restrict__ MV, u16* __restrict__ RRb){
  if (blockIdx.y < 24)
    gemm_mfma_body<ACT_RELU2_BF16>(MK, ptab[21]+(size_t)l*3*C_*C_, nullptr, H1, nullptr,
                                   3*C_, C_, blockIdx.x*128, blockIdx.y*64);
  else
    gemm_mfma_body<ACT_SIG_BF16>(MV, ptab[23]+(size_t)l*C_*C_, nullptr, RRb, nullptr,
                                 C_, C_, blockIdx.x*128, (blockIdx.y-24)*64);
}

// output projection with residual add: X += YGN @ Wo^T   (grid 64x8)
__global__ __launch_bounds__(256,4) void gemm_wo(const u16* const* __restrict__ ptab, int l,
    const u16* __restrict__ YGN, float* __restrict__ X){
  gemm_mfma_body<ACT_ADD_F32>(YGN, ptab[16]+(size_t)l*C_*C_, X, nullptr, nullptr,
                              C_, C_, blockIdx.x*128, blockIdx.y*64);
}

// cmix value GEMM with fused tail: X += gate * (H1 @ Wcv^T)   (grid 64x8)
__global__ __launch_bounds__(256,4) void gemm_cmix(const u16* const* __restrict__ ptab, int l,
    const u16* __restrict__ H1, float* __restrict__ X, const u16* __restrict__ RRb){
  gemm_mfma_body<ACT_CMIX>(H1, ptab[22]+(size_t)l*3*C_*C_, X, nullptr, RRb,
                           C_, 3*C_, blockIdx.x*128, blockIdx.y*64);
}

// ---------------- K/V per-(b,h) transpose; K gets wdec^(Q-1-tloc) scale ----------------
// grid (T/64, B*H, 2): z=0 V->Vt plain, z=1 K->Kt scaled
__global__ __launch_bounds__(256) void kvtrans(const u16* __restrict__ Kb, const u16* __restrict__ Vb,
    u16* __restrict__ Kt, u16* __restrict__ Vt, const u16* const* __restrict__ ptab, int l){
  __shared__ __align__(16) u16 tile[64*64];
  const int t0 = blockIdx.x*64, bh = blockIdx.y, b = bh>>3, h = bh&7;
  const bool isK = (blockIdx.z == 1);
  const u16* src = isK ? Kb : Vb;
  u16* dst = isK ? Kt : Vt;
  float l2w = 0.f;
  if (isK){
    const u16* td = ptab[10] + l*H_;
    l2w = -expf(bf2f(td[h])) * 1.44269504f;
  }
  const int tid = threadIdx.x;
  #pragma unroll
  for (int it=0; it<2; ++it){
    int tl = it*32 + (tid>>3);
    int n0 = (tid&7)*8;
    union {uint4 q; u16 e[8];} v;
    v.q = *(const uint4*)(src + ((size_t)(b*T_ + t0 + tl))*C_ + h*N_ + n0);
    if (isK){
      int tloc = (t0 + tl) & (Q_-1);
      float sc = exp2f(l2w * (float)(Q_-1 - tloc));
      #pragma unroll
      for (int e=0;e<8;++e) v.e[e] = f2bf(bf2f(v.e[e])*sc);
    }
    int col = n0 ^ (((tl>>3)&7)<<3);
    *(uint4*)&tile[tl*64 + col] = v.q;
  }
  __syncthreads();
  #pragma unroll
  for (int it=0; it<2; ++it){
    int nl = it*32 + (tid>>3);
    int t0l = (tid&7)*8;
    int swz = (tid&7)<<3;
    union {uint4 q; u16 h2[8];} pk;
    #pragma unroll
    for (int e=0;e<8;++e)
      pk.h2[e] = tile[(t0l+e)*64 + (nl ^ swz)];
    *(uint4*)(dst + ((size_t)(bh*N_ + nl))*T_ + t0 + t0l) = pk.q;
  }
}

// ---------------- per-chunk state S_c = (k*wkv)^T @ v via MFMA on Kt(scaled)/Vt ----------------
__global__ __launch_bounds__(256) void wkv_state_mfma(const u16* __restrict__ Kt,
    const u16* __restrict__ Vt, float* __restrict__ S){
  const int c = blockIdx.x, bh = blockIdx.y;
  const int tid = threadIdx.x, wv = tid >> 6, ln = tid & 63;
  const int m16 = ln & 15, q = ln >> 4;
  const u16* ka = Kt + (size_t)(bh*N_ + wv*16 + m16)*T_ + c*Q_;
  const u16* vb = Vt + (size_t)(bh*N_ + m16)*T_ + c*Q_;
  f32x4 acc[4];
  #pragma unroll
  for (int nt=0;nt<4;++nt) acc[nt] = f32x4{0.f,0.f,0.f,0.f};
  #pragma unroll
  for (int ks=0; ks<8; ++ks){
    bf16x8 af = *(const bf16x8*)(ka + ks*32 + q*8);
    #pragma unroll
    for (int nt=0;nt<4;++nt){
      bf16x8 bv = *(const bf16x8*)(vb + (size_t)(nt*16)*T_ + ks*32 + q*8);
      acc[nt] = __builtin_amdgcn_mfma_f32_16x16x32_bf16(af, bv, acc[nt], 0,0,0);
    }
  }
  float* Sp = S + ((size_t)bh*NC_ + c)*(N_*N_);
  #pragma unroll
  for (int nt=0;nt<4;++nt)
    #pragma unroll
    for (int r=0;r<4;++r)
      Sp[(wv*16 + q*4 + r)*N_ + nt*16 + m16] = acc[nt][r];
}

// ---------------- sequential prefix over chunks ----------------
__global__ __launch_bounds__(256) void wkv_prefix(float* __restrict__ S,
    const u16* const* __restrict__ ptab, int l){
  const int bh = blockIdx.x, h = bh&7;
  const u16* td = ptab[10] + l*H_;
  const float l2w = -expf(bf2f(td[h])) * 1.44269504f;
  const float wsd = exp2f(l2w * (float)Q_);
  float* Sp = S + (size_t)bh*NC_*N_*N_;
  for (int e=threadIdx.x; e<N_*N_; e+=256){
    float cur = 0.f;
    for (int cc=0;cc<NC_;++cc){
      float sc = Sp[(size_t)cc*N_*N_ + e];
      Sp[(size_t)cc*N_*N_ + e] = cur;
      cur = wsd*cur + sc;
    }
  }
}

// ---------------- FUSED WKV: intra (MFMA) + inter (VALU r@S) + GroupNorm + silu(g) ----------------
__global__ __launch_bounds__(256) void wkv_fused(const u16* __restrict__ Rb,
    const u16* __restrict__ Kb, const u16* __restrict__ Vt, const float* __restrict__ S,
    const u16* const* __restrict__ ptab, int l,
    const u16* __restrict__ g, u16* __restrict__ out){
  __shared__ float wpow[Q_];
  __shared__ float st[64][68];                 // prefix state (f32)
  __shared__ float rs[64][68];                 // r rows (f32, for inter VALU)
  __shared__ __align__(16) float ylds[64][68]; // intra result; P tile aliases this region
  u16 (*P)[16][72] = reinterpret_cast<u16(*)[16][72]>(&ylds[0][0]);
  const u16* td  = ptab[10] + l*H_;
  const u16* tf  = ptab[11] + l*H_;
  const u16* gnw = ptab[17] + l*C_;
  const u16* gnb = ptab[18] + l*C_;
  const int c = blockIdx.x>>2, ip = blockIdx.x&3;
  const int bh = blockIdx.y, b = bh>>3, h = bh&7;
  const int tid = threadIdx.x, wv = tid >> 6, ln = tid & 63;
  const int m16 = ln & 15, q = ln >> 4;
  const int tx = tid&15, ty = tid>>4;
  const float l2w = -expf(bf2f(td[h])) * 1.44269504f;
  const float uu = bf2f(tf[h]);
  wpow[tid] = exp2f(l2w * (float)tid);
  const float* Sp = S + ((size_t)bh*NC_ + c)*(N_*N_);
  for (int e=tid;e<N_*N_;e+=256) st[e>>6][e&63] = Sp[e];
  const size_t base = ((size_t)b*T_ + (size_t)c*Q_)*C_ + h*N_;
  const int i0 = ip*64;
  {
    const int rrr = tid >> 6, cc2 = tid & 63;
    for (int it=0;it<16;++it){ int i=it*4+rrr; rs[i][cc2]=bf2f(Rb[base+(size_t)(i0+i)*C_+cc2]); }
  }
  __syncthreads();
  // ---- intra-chunk (MFMA) ----
  const int iw0 = ip*64 + wv*16;
  const u16* rrow = Rb + base + (size_t)(iw0 + m16)*C_;
  bf16x8 af0 = *(const bf16x8*)(rrow + q*8);
  bf16x8 af1 = *(const bf16x8*)(rrow + 32 + q*8);
  f32x4 acc[4];
  #pragma unroll
  for (int nt=0;nt<4;++nt) acc[nt] = f32x4{0.f,0.f,0.f,0.f};
  const int irow = iw0 + q*4;
  const u16* vtb = Vt + (size_t)(bh*N_)*T_ + (size_t)c*Q_;
  for (int jt=0; jt<=ip; ++jt){
    f32x4 s[4];
    #pragma unroll
    for (int j2=0;j2<4;++j2) s[j2] = f32x4{0.f,0.f,0.f,0.f};
    #pragma unroll
    for (int j2=0;j2<4;++j2){
      const u16* kr = Kb + base + (size_t)(jt*64 + j2*16 + m16)*C_;
      bf16x8 b0 = *(const bf16x8*)(kr + q*8);
      bf16x8 b1 = *(const bf16x8*)(kr + 32 + q*8);
      s[j2] = __builtin_amdgcn_mfma_f32_16x16x32_bf16(af0, b0, s[j2], 0,0,0);
      s[j2] = __builtin_amdgcn_mfma_f32_16x16x32_bf16(af1, b1, s[j2], 0,0,0);
    }
    #pragma unroll
    for (int j2=0;j2<4;++j2){
      int jc = jt*64 + j2*16 + m16;
      #pragma unroll
      for (int r=0;r<4;++r){
        int ic = irow + r;
        float w = (jc < ic) ? wpow[ic-jc-1] : ((jc==ic) ? uu : 0.f);
        P[wv][q*4+r][j2*16+m16] = f2bf(s[j2][r]*w);
      }
    }
    __asm__ volatile("s_waitcnt lgkmcnt(0)" ::: "memory");
    #pragma unroll
    for (int kp=0;kp<2;++kp){
      bf16x8 ap = *(const bf16x8*)&P[wv][m16][kp*32 + q*8];
      #pragma unroll
      for (int nt=0;nt<4;++nt){
        bf16x8 bv = *(const bf16x8*)(vtb + (size_t)(nt*16 + m16)*T_ + jt*64 + kp*32 + q*8);
        acc[nt] = __builtin_amdgcn_mfma_f32_16x16x32_bf16(ap, bv, acc[nt], 0,0,0);
      }
    }
  }
  __syncthreads();   // all waves done with P region -> safe to write ylds (aliased)
  #pragma unroll
  for (int nt=0;nt<4;++nt)
    #pragma unroll
    for (int r=0;r<4;++r)
      ylds[wv*16 + q*4 + r][nt*16 + m16] = acc[nt][r];
  __syncthreads();
  // ---- inter-chunk (VALU r@S) ----
  float acc2[4][4] = {};
  #pragma unroll
  for (int kk4=0;kk4<16;++kk4){
    f32x4 sv[4], rv[4];
    #pragma unroll
    for (int kkk=0;kkk<4;++kkk) sv[kkk] = *(const f32x4*)&st[kk4*4+kkk][tx*4];
    #pragma unroll
    for (int ii=0;ii<4;++ii)    rv[ii]  = *(const f32x4*)&rs[ty*4+ii][kk4*4];
    #pragma unroll
    for (int ii=0;ii<4;++ii)
      #pragma unroll
      for (int kkk=0;kkk<4;++kkk)
        #pragma unroll
        for (int nn=0;nn<4;++nn)
          acc2[ii][nn] += rv[ii][kkk]*sv[kkk][nn];
  }
  // ---- GroupNorm + silu(g), 16-lane reduce ----
  #pragma unroll
  for (int ii=0;ii<4;ii++){
    int tl = ty*4+ii;
    int il = i0 + tl;
    size_t roff = base + (size_t)il*C_;
    float w = wpow[il];
    f32x4 yv = *(const f32x4*)&ylds[tl][tx*4];
    float val[4];
    float s=0.f, ss=0.f;
    #pragma unroll
    for (int nn=0;nn<4;nn++){
      float v = yv[nn] + w*acc2[ii][nn];
      val[nn]=v; s+=v; ss+=v*v;
    }
    #pragma unroll
    for (int o=8;o>0;o>>=1){ s+=__shfl_xor(s,o,64); ss+=__shfl_xor(ss,o,64); }
    float mu = s*(1.f/N_);
    float var = ss*(1.f/N_) - mu*mu;
    float inv = rsqrtf(fmaxf(var,0.f) + 6.4e-4f);   // GN_EPS = 1e-5*64
    union { ushort4 v; u16 e[4]; } gv, ov;
    gv.v = *(const ushort4*)(g + roff + tx*4);
    #pragma unroll
    for (int nn=0;nn<4;nn++){
      int ci = h*N_ + tx*4 + nn;
      float gg = bf2f(gv.e[nn]);
      float sil = gg/(1.f+expf(-gg));
      ov.e[nn] = f2bf(((val[nn]-mu)*inv*bf2f(gnw[ci]) + bf2f(gnb[ci]))*sil);
    }
    *(ushort4*)(out + roff + tx*4) = ov.v;
  }
}

// ---------------- logits for last position: [B,V] = xf @ wte^T ----------------
__global__ __launch_bounds__(256) void logits_kernel(const float* __restrict__ xf,
    const u16* const* __restrict__ ptab, void* __restrict__ out, const int* __restrict__ flag){
  const u16* wte = ptab[1];
  const int wid = threadIdx.x>>6, lane = threadIdx.x&63;
  const int gw = blockIdx.x*4 + wid;     // 0 .. B*V-1
  const int b = gw / V_, v = gw - b*V_;
  const u16* wrow = wte + (size_t)v*C_;
  const float* xr = xf + b*C_;
  union {uint4 q; u16 h[8];} uu;
  uu.q = *(const uint4*)(wrow + lane*8);
  float s = 0.f;
  #pragma unroll
  for (int j=0;j<8;j++) s += bf2f(uu.h[j])*xr[lane*8+j];
  #pragma unroll
  for (int o=32;o>0;o>>=1) s += __shfl_down(s,o,64);
  if (lane==0){
    size_t o = (size_t)b*V_ + v;
    if (*flag) ((float*)out)[o] = s;          // fp32 harness
    else       ((u16*)out)[o]   = f2bf(s);    // bf16 harness
  }
}

extern "C" void kernel_launch(void* const* d_in, const int* in_sizes, int n_in,
                              void* d_out, int out_size, void* d_ws, size_t ws_size,
                              hipStream_t stream){
  (void)out_size; (void)ws_size; (void)n_in;
  const int* idx  = (const int*)d_in[0];

  char* ws = (char*)d_ws;
  const size_t MC  = (size_t)M_*C_;
  // ---- workspace layout (bytes) ----
  size_t o = 0;
  int* flag = (int*)(ws + o);            o += 1024;
  const u16** ptab = (const u16**)(ws + o); o += 1024;
  float* X   = (float*)(ws + o);         o += MC*4;            // fp32 residual
  u16* MK = (u16*)(ws + o);              o += MC*2;            // also YGN
  u16* MV = (u16*)(ws + o);              o += MC*2;
  u16* MR = (u16*)(ws + o);              o += MC*2;            // also S (tmix) / RRb (cmix)
  u16* MG = (u16*)(ws + o);              o += MC*2;
  u16* Rb = (u16*)(ws + o);              o += MC*2;            // H1 spans Rb..Vb
  u16* Kb = (u16*)(ws + o);              o += MC*2;
  u16* Vb = (u16*)(ws + o);              o += MC*2;
  u16* Gb = (u16*)(ws + o);              o += MC*2;
  u16* Kt = (u16*)(ws + o);              o += MC*2;            // scaled k^T per (b,h): [BH*64, T]
  u16* Vt = (u16*)(ws + o);              o += MC*2;            // v^T per (b,h): [BH*64, T]
  float* XF = (float*)(ws + o);          o += 65536;
  u16* pool = (u16*)(ws + o);            // fp32->bf16 converted inputs (only if needed)
  u16* YGN = MK;
  float* S  = (float*)MR;    // live only during tmix phase (4 MB < 8.4 MB)
  u16* H1 = Rb;              // [M,3C] bf16, spans Rb..Vb
  u16* RRb = MR;             // [M,C] bf16 sigmoid gate (cmix phase)

  // ---- dtype detect + pointer table + (conditional) conversion ----
  detect_kernel<<<1,256,0,stream>>>(d_in[12], flag);   // probe Wr
  CvtTab tab; PtrTab pt;
  int nblocks;
  {
    size_t poff = 0; int acc8 = 0, bacc = 0;
    long long total8 = 0;
    for (int i=1;i<24;i++) total8 += (long long)(in_sizes[i] >> 3);
    for (int i=1;i<24;i++){
      pt.raw[i-1] = d_in[i];
      pt.off[i-1] = (long long)poff;
      poff += (size_t)in_sizes[i];
      tab.s[i-1] = d_in[i];
      tab.off8[i-1] = acc8;
      tab.bstart[i-1] = bacc;
      int n8 = in_sizes[i] >> 3;
      int nb = (int)(((long long)n8 * 2048 + total8 - 1) / total8);
      if (nb < 1) nb = 1;
      acc8 += n8; bacc += nb;
    }
    tab.off8[23] = acc8; tab.bstart[23] = bacc;
    nblocks = bacc;
  }
  fill_ptab<<<1,64,0,stream>>>(pt, pool, flag, ptab);
  convert_all<<<nblocks,256,0,stream>>>(tab, pool, flag);

  embed_kernel<<<M_,256,0,stream>>>(idx, ptab, X);
  dim3 g4 (M_/128, C_/64, 4);      // (64,8,4) fused projections, 128x64
  dim3 gkv(T_/64, B_*H_, 2);       // K/V transpose
  dim3 gck(M_/128, 32);            // 24 ck tiles + 8 cr tiles, 128x64
  dim3 gwo(M_/128, C_/64);         // (64,8) 128x64
  for (int l=0;l<L_;++l){
    // ---- time mix ----
    ln_tmix_kernel<<<M_,256,0,stream>>>(X, ptab, l, MK,MV,MR,MG);
    gemm4_mfma<<<g4,256,0,stream>>>(ptab, l, MK, Rb, Kb, Vb, Gb);
    kvtrans<<<gkv,256,0,stream>>>(Kb, Vb, Kt, Vt, ptab, l);
    wkv_state_mfma<<<dim3(NC_, B_*H_),256,0,stream>>>(Kt, Vt, S);
    wkv_prefix<<<B_*H_,256,0,stream>>>(S, ptab, l);
    wkv_fused<<<dim3(NC_*4, B_*H_),256,0,stream>>>(Rb, Kb, Vt, S, ptab, l, Gb, YGN);
    gemm_wo<<<gwo,256,0,stream>>>(ptab, l, YGN, X);
    // ---- channel mix ----
    ln_cmix_kernel<<<M_,256,0,stream>>>(X, ptab, l, MK, MV);
    gemm_ck_cr<<<gck,256,0,stream>>>(ptab, l, MK, H1, MV, RRb);
    gemm_cmix<<<gwo,256,0,stream>>>(ptab, l, H1, X, RRb);
  }
  lnf_last<<<B_,256,0,stream>>>(X, ptab, XF);
  logits_kernel<<<(B_*V_)/4,256,0,stream>>>(XF, ptab, d_out, flag);
}

// Round 8
// 1552.749 us; speedup vs baseline: 1.1022x; 1.0200x over previous
//
#include <hip/hip_runtime.h>

#define L_ 6
#define H_ 8
#define C_ 512
#define V_ 32000
#define B_ 2
#define T_ 4096
#define Q_ 256
#define N_ 64
#define NC_ 16
#define M_ 8192   // B*T

typedef unsigned short u16;
typedef __attribute__((ext_vector_type(8))) short bf16x8;
typedef __attribute__((ext_vector_type(4))) float f32x4;

__device__ __forceinline__ float bf2f(u16 u){
  return __uint_as_float(((unsigned int)u) << 16);
}
__device__ __forceinline__ u16 f2bf(float f){
  unsigned int x = __float_as_uint(f);
  return (u16)((x + 0x7fffu + ((x >> 16) & 1u)) >> 16);
}

__device__ __forceinline__ void gl_lds16(const u16* g, u16* l){
  __builtin_amdgcn_global_load_lds((const __attribute__((address_space(1))) void*)g,
                                   (__attribute__((address_space(3))) void*)l, 16, 0, 0);
}

// ---------------- dtype detection: bf16 weights never have |x|>=2 ----------------
__global__ __launch_bounds__(256) void detect_kernel(const void* __restrict__ probe,
                                                     int* __restrict__ flag){
  __shared__ int cnt;
  if (threadIdx.x == 0) cnt = 0;
  __syncthreads();
  const u16* p = (const u16*)probe;
  int c = 0;
  for (int i = threadIdx.x; i < 2048; i += 256){
    int e = (p[i] >> 7) & 0xFF;
    if (e >= 128) c++;
  }
  atomicAdd(&cnt, c);
  __syncthreads();
  if (threadIdx.x == 0) *flag = (cnt > 32) ? 1 : 0;  // 1 = inputs are fp32
}

// ---------------- pointer table: bf16 -> use raw inputs in place; fp32 -> converted pool ----------------
struct PtrTab { const void* raw[23]; long long off[23]; };

__global__ __launch_bounds__(64) void fill_ptab(PtrTab pt, const u16* __restrict__ pool,
    const int* __restrict__ flag, const u16** __restrict__ ptab){
  int i = threadIdx.x;
  if (i < 23)
    ptab[i+1] = (*flag) ? (pool + pt.off[i]) : (const u16*)pt.raw[i];
}

// ---------------- fp32 -> bf16 conversion, tensors 3..23 only (wte/wpe stay raw) ----------------
struct CvtTab { const void* s[21]; int off8[22]; int bstart[22]; };

__global__ __launch_bounds__(256) void convert_all(CvtTab t, u16* __restrict__ pool,
                                                   const int* __restrict__ flag){
  if (!*flag) return;    // bf16 inputs are consumed in place via ptab
  int i = 0;
  #pragma unroll
  for (int k = 1; k < 21; k++) if ((int)blockIdx.x >= t.bstart[k]) i = k;
  const void* sp = t.s[0];
  #pragma unroll
  for (int k = 1; k < 21; k++) if (i == k) sp = t.s[k];
  const int n8 = t.off8[i+1] - t.off8[i];
  const int nb = t.bstart[i+1] - t.bstart[i];
  const int lb = (int)blockIdx.x - t.bstart[i];
  uint4* dp = (uint4*)pool + t.off8[i];
  const int stride = nb * 256;
  const float4* sf = (const float4*)sp;
  for (int j = lb*256 + (int)threadIdx.x; j < n8; j += stride){
    float4 a0 = sf[2*j], a1 = sf[2*j+1];
    uint4 r0;
    r0.x = (unsigned)f2bf(a0.x) | ((unsigned)f2bf(a0.y) << 16);
    r0.y = (unsigned)f2bf(a0.z) | ((unsigned)f2bf(a0.w) << 16);
    r0.z = (unsigned)f2bf(a1.x) | ((unsigned)f2bf(a1.y) << 16);
    r0.w = (unsigned)f2bf(a1.z) | ((unsigned)f2bf(a1.w) << 16);
    dp[j] = r0;
  }
}

// ---------------- embedding: x = wte[idx] + wpe (reads raw dtype directly) ----------------
__global__ __launch_bounds__(256) void embed_kernel(const int* __restrict__ idx,
    const void* __restrict__ wteR, const void* __restrict__ wpeR,
    const int* __restrict__ flag, float* __restrict__ x){
  int row = blockIdx.x;                 // b*T + t
  int t = row & (T_-1);
  int tok = idx[row];
  float* xo = x + (size_t)row * C_;
  int c = threadIdx.x;
  float a0,a1,b0,b1;
  if (*flag){
    const float* we = (const float*)wteR + (size_t)tok * C_;
    const float* wp = (const float*)wpeR + (size_t)t * C_;
    a0 = we[c]; a1 = we[c+256]; b0 = wp[c]; b1 = wp[c+256];
  } else {
    const u16* we = (const u16*)wteR + (size_t)tok * C_;
    const u16* wp = (const u16*)wpeR + (size_t)t * C_;
    a0 = bf2f(we[c]); a1 = bf2f(we[c+256]); b0 = bf2f(wp[c]); b1 = bf2f(wp[c+256]);
  }
  xo[c]     = a0 + b0;
  xo[c+256] = a1 + b1;
}

// ---------------- fused LN + time-mix token shift (recomputes LN of row t-1) ----------------
__global__ __launch_bounds__(256) void ln_tmix_kernel(const float* __restrict__ x,
    const u16* const* __restrict__ ptab, int l,
    u16* __restrict__ xk, u16* __restrict__ xv, u16* __restrict__ xr, u16* __restrict__ xg){
  const u16* w  = ptab[3] + l*C_;
  const u16* mk = ptab[6] + l*C_;
  const u16* mv = ptab[7] + l*C_;
  const u16* mr = ptab[8] + l*C_;
  const u16* mg = ptab[9] + l*C_;
  int row = blockIdx.x; int t = row & (T_-1);
  size_t off = (size_t)row*C_;
  const float* cur = x + off;
  int c = threadIdx.x;
  float v0 = cur[c], v1 = cur[c+256];
  float p0 = 0.f, p1 = 0.f;
  if (t){ p0 = cur[c - C_]; p1 = cur[c+256 - C_]; }
  float s = v0+v1, ss = v0*v0+v1*v1;
  float sp = p0+p1, ssp = p0*p0+p1*p1;
  int lane = c & 63, wid = c >> 6;
  #pragma unroll
  for (int o=32;o>0;o>>=1){
    s  += __shfl_down(s,o,64);  ss  += __shfl_down(ss,o,64);
    sp += __shfl_down(sp,o,64); ssp += __shfl_down(ssp,o,64);
  }
  __shared__ float r1[4], r2[4], r3[4], r4[4];
  if (lane==0){ r1[wid]=s; r2[wid]=ss; r3[wid]=sp; r4[wid]=ssp; }
  __syncthreads();
  if (c==0){
    float a =r1[0]+r1[1]+r1[2]+r1[3], bq=r2[0]+r2[1]+r2[2]+r2[3];
    float ap=r3[0]+r3[1]+r3[2]+r3[3], bp=r4[0]+r4[1]+r4[2]+r4[3];
    float mu  = a *(1.f/C_); float var  = bq*(1.f/C_) - mu*mu;
    float mup = ap*(1.f/C_); float varp = bp*(1.f/C_) - mup*mup;
    r1[0]=mu;  r2[0]=rsqrtf(fmaxf(var ,0.f)+1e-5f);
    r3[0]=mup; r4[0]=rsqrtf(fmaxf(varp,0.f)+1e-5f);
  }
  __syncthreads();
  float mu=r1[0], inv=r2[0], mup=r3[0], invp=r4[0];
  #pragma unroll
  for (int p=0;p<2;p++){
    int cc = c + p*256;
    float wc = bf2f(w[cc]);
    float xc = ((p?v1:v0)-mu)*inv*wc;
    float xp = t ? ((p?p1:p0)-mup)*invp*wc : 0.f;
    float xx = xp - xc;
    xk[off+cc] = f2bf(xc + xx*bf2f(mk[cc]));
    xv[off+cc] = f2bf(xc + xx*bf2f(mv[cc]));
    xr[off+cc] = f2bf(xc + xx*bf2f(mr[cc]));
    xg[off+cc] = f2bf(xc + xx*bf2f(mg[cc]));
  }
}

// ---------------- fused LN + channel-mix token shift ----------------
__global__ __launch_bounds__(256) void ln_cmix_kernel(const float* __restrict__ x,
    const u16* const* __restrict__ ptab, int l,
    u16* __restrict__ xk, u16* __restrict__ xr){
  const u16* w  = ptab[4]  + l*C_;
  const u16* mk = ptab[19] + l*C_;
  const u16* mr = ptab[20] + l*C_;
  int row = blockIdx.x; int t = row & (T_-1);
  size_t off = (size_t)row*C_;
  const float* cur = x + off;
  int c = threadIdx.x;
  float v0 = cur[c], v1 = cur[c+256];
  float p0 = 0.f, p1 = 0.f;
  if (t){ p0 = cur[c - C_]; p1 = cur[c+256 - C_]; }
  float s = v0+v1, ss = v0*v0+v1*v1;
  float sp = p0+p1, ssp = p0*p0+p1*p1;
  int lane = c & 63, wid = c >> 6;
  #pragma unroll
  for (int o=32;o>0;o>>=1){
    s  += __shfl_down(s,o,64);  ss  += __shfl_down(ss,o,64);
    sp += __shfl_down(sp,o,64); ssp += __shfl_down(ssp,o,64);
  }
  __shared__ float r1[4], r2[4], r3[4], r4[4];
  if (lane==0){ r1[wid]=s; r2[wid]=ss; r3[wid]=sp; r4[wid]=ssp; }
  __syncthreads();
  if (c==0){
    float a =r1[0]+r1[1]+r1[2]+r1[3], bq=r2[0]+r2[1]+r2[2]+r2[3];
    float ap=r3[0]+r3[1]+r3[2]+r3[3], bp=r4[0]+r4[1]+r4[2]+r4[3];
    float mu  = a *(1.f/C_); float var  = bq*(1.f/C_) - mu*mu;
    float mup = ap*(1.f/C_); float varp = bp*(1.f/C_) - mup*mup;
    r1[0]=mu;  r2[0]=rsqrtf(fmaxf(var ,0.f)+1e-5f);
    r3[0]=mup; r4[0]=rsqrtf(fmaxf(varp,0.f)+1e-5f);
  }
  __syncthreads();
  float mu=r1[0], inv=r2[0], mup=r3[0], invp=r4[0];
  #pragma unroll
  for (int p=0;p<2;p++){
    int cc = c + p*256;
    float wc = bf2f(w[cc]);
    float xc = ((p?v1:v0)-mu)*inv*wc;
    float xp = t ? ((p?p1:p0)-mup)*invp*wc : 0.f;
    float xx = xp - xc;
    xk[off+cc] = f2bf(xc + xx*bf2f(mk[cc]));
    xr[off+cc] = f2bf(xc + xx*bf2f(mr[cc]));
  }
}

// ---------------- final LN for last position only ----------------
__global__ __launch_bounds__(256) void lnf_last(const float* __restrict__ x,
    const u16* const* __restrict__ ptab, float* __restrict__ xf){
  const u16* w = ptab[5];
  int b = blockIdx.x;
  const float* xr = x + ((size_t)b*T_ + (T_-1))*C_;
  int c = threadIdx.x;
  float v0 = xr[c], v1 = xr[c+256];
  float s = v0+v1, ss = v0*v0+v1*v1;
  int lane = c & 63, wid = c >> 6;
  #pragma unroll
  for (int o=32;o>0;o>>=1){ s += __shfl_down(s,o,64); ss += __shfl_down(ss,o,64); }
  __shared__ float r1[4], r2[4];
  if (lane==0){ r1[wid]=s; r2[wid]=ss; }
  __syncthreads();
  if (c==0){
    float a=r1[0]+r1[1]+r1[2]+r1[3], bq=r2[0]+r2[1]+r2[2]+r2[3];
    float mu = a*(1.f/C_);
    float var = bq*(1.f/C_) - mu*mu;
    r1[0]=mu; r2[0]=rsqrtf(fmaxf(var,0.f)+1e-5f);
  }
  __syncthreads();
  float mu=r1[0], inv=r2[0];
  xf[b*C_+c]     = (v0-mu)*inv*bf2f(w[c]);
  xf[b*C_+c+256] = (v1-mu)*inv*bf2f(w[c+256]);
}

// ================= MFMA GEMM: 128(M) x 64(N), BK=64, 24KB LDS =================
// Shared memory is declared ONCE per __global__ kernel and passed in, so
// multi-instantiation kernels (ck_cr) don't double-allocate LDS.
#define ACT_RELU2_BF16 1
#define ACT_ADD_F32 2
#define ACT_BF16 3
#define ACT_CMIX 4      // Yf += v * bf2f(AuxB) (AuxB holds sigmoid gate)
#define ACT_SIG_BF16 7  // Yb = bf16(sigmoid(v))

template<int ACT>
__device__ __forceinline__ void gemm_mfma_body(u16* __restrict__ Al, u16* __restrict__ Bl,
    const u16* __restrict__ X, const u16* __restrict__ W,
    float* __restrict__ Yf, u16* __restrict__ Yb, const u16* __restrict__ AuxB,
    int Ndim, int Kdim, int bm, int bn){
  const int tid = threadIdx.x;
  const int wv = tid >> 6, ln = tid & 63;
  const int m16 = ln & 15, q = ln >> 4;

  f32x4 acc[2][4];
  #pragma unroll
  for (int i=0;i<2;i++)
    #pragma unroll
    for (int j=0;j<4;j++) acc[i][j] = f32x4{0.f,0.f,0.f,0.f};

  const int r0 = wv*8 + (ln >> 3);
  const int c0 = (ln & 7)*8;
  const u16* ga = X + (size_t)(bm + r0)*Kdim + c0;
  const u16* gb = W + (size_t)(bn + r0)*Kdim + c0;
  u16* la = Al + r0*64 + c0;
  u16* lb = Bl + r0*64 + c0;

  for (int k0=0; k0<Kdim; k0+=64){
    #pragma unroll
    for (int s=0;s<4;s++)
      gl_lds16(ga + (size_t)(s*32)*Kdim + k0, la + s*2048);
    #pragma unroll
    for (int s=0;s<2;s++)
      gl_lds16(gb + (size_t)(s*32)*Kdim + k0, lb + s*2048);
    __syncthreads();
    #pragma unroll
    for (int kh=0; kh<2; kh++){
      bf16x8 af[2], bfr[4];
      #pragma unroll
      for (int i=0;i<2;i++) af[i]  = *(const bf16x8*)(Al + (wv*32 + i*16 + m16)*64 + kh*32 + q*8);
      #pragma unroll
      for (int j=0;j<4;j++) bfr[j] = *(const bf16x8*)(Bl + (j*16 + m16)*64 + kh*32 + q*8);
      #pragma unroll
      for (int i=0;i<2;i++)
        #pragma unroll
        for (int j=0;j<4;j++)
          acc[i][j] = __builtin_amdgcn_mfma_f32_16x16x32_bf16(af[i], bfr[j], acc[i][j], 0, 0, 0);
    }
    __syncthreads();
  }

  // epilogue: C/D layout col=lane&15, row=quad*4+reg
  #pragma unroll
  for (int i=0;i<2;i++){
    int row = bm + wv*32 + i*16 + q*4;
    #pragma unroll
    for (int j=0;j<4;j++){
      int col = bn + j*16 + m16;
      #pragma unroll
      for (int r=0;r<4;r++){
        size_t off = (size_t)(row + r)*Ndim + col;
        float v = acc[i][j][r];
        if (ACT==ACT_ADD_F32) Yf[off] += v;
        else if (ACT==ACT_CMIX){ Yf[off] += v * bf2f(AuxB[off]); }
        else if (ACT==ACT_BF16) Yb[off] = f2bf(v);
        else if (ACT==ACT_RELU2_BF16){ float rr = v>0.f ? v : 0.f; Yb[off] = f2bf(rr*rr); }
        else if (ACT==ACT_SIG_BF16) Yb[off] = f2bf(1.f/(1.f+expf(-v)));
      }
    }
  }
}

#define GEMM_SH __shared__ __align__(16) u16 SH[128*64 + 64*64]

// fused r/k/v/g projections, 128x64 tiles, grid (64,8,4)
__global__ __launch_bounds__(256,4) void gemm4_mfma(const u16* const* __restrict__ ptab, int l,
    const u16* __restrict__ Abase,
    u16* __restrict__ Rb, u16* __restrict__ Kb, u16* __restrict__ Vb, u16* __restrict__ Gb){
  GEMM_SH;
  const size_t MC = (size_t)M_*C_;
  const size_t ws = (size_t)l*C_*C_;
  const int bm = blockIdx.x*128, bn = blockIdx.y*64;
  switch (blockIdx.z){
    case 0:  gemm_mfma_body<ACT_BF16>(SH, SH+128*64, Abase + 2*MC, ptab[12]+ws, nullptr, Rb, nullptr, C_, C_, bm, bn); break;
    case 1:  gemm_mfma_body<ACT_BF16>(SH, SH+128*64, Abase,        ptab[13]+ws, nullptr, Kb, nullptr, C_, C_, bm, bn); break;
    case 2:  gemm_mfma_body<ACT_BF16>(SH, SH+128*64, Abase + 1*MC, ptab[14]+ws, nullptr, Vb, nullptr, C_, C_, bm, bn); break;
    default: gemm_mfma_body<ACT_BF16>(SH, SH+128*64, Abase + 3*MC, ptab[15]+ws, nullptr, Gb, nullptr, C_, C_, bm, bn); break;
  }
}

// fused cmix key (relu^2 -> H1) + receptance gate (sigmoid -> RRb), 128x64, grid (64,32)
__global__ __launch_bounds__(256,4) void gemm_ck_cr(const u16* const* __restrict__ ptab, int l,
    const u16* __restrict__ MK, u16* __restrict__ H1,
    const u16* __restrict__ MV, u16* __restrict__ RRb){
  GEMM_SH;
  if (blockIdx.y < 24)
    gemm_mfma_body<ACT_RELU2_BF16>(SH, SH+128*64, MK, ptab[21]+(size_t)l*3*C_*C_, nullptr, H1, nullptr,
                                   3*C_, C_, blockIdx.x*128, blockIdx.y*64);
  else
    gemm_mfma_body<ACT_SIG_BF16>(SH, SH+128*64, MV, ptab[23]+(size_t)l*C_*C_, nullptr, RRb, nullptr,
                                 C_, C_, blockIdx.x*128, (blockIdx.y-24)*64);
}

// output projection with residual add: X += YGN @ Wo^T   (grid 64x8)
__global__ __launch_bounds__(256,4) void gemm_wo(const u16* const* __restrict__ ptab, int l,
    const u16* __restrict__ YGN, float* __restrict__ X){
  GEMM_SH;
  gemm_mfma_body<ACT_ADD_F32>(SH, SH+128*64, YGN, ptab[16]+(size_t)l*C_*C_, X, nullptr, nullptr,
                              C_, C_, blockIdx.x*128, blockIdx.y*64);
}

// cmix value GEMM with fused tail: X += gate * (H1 @ Wcv^T)   (grid 64x8)
__global__ __launch_bounds__(256,4) void gemm_cmix(const u16* const* __restrict__ ptab, int l,
    const u16* __restrict__ H1, float* __restrict__ X, const u16* __restrict__ RRb){
  GEMM_SH;
  gemm_mfma_body<ACT_CMIX>(SH, SH+128*64, H1, ptab[22]+(size_t)l*3*C_*C_, X, nullptr, RRb,
                           C_, 3*C_, blockIdx.x*128, blockIdx.y*64);
}

// ---------------- K/V per-(b,h) transpose; K gets wdec^(Q-1-tloc) scale ----------------
// grid (T/64, B*H, 2): z=0 V->Vt plain, z=1 K->Kt scaled
__global__ __launch_bounds__(256) void kvtrans(const u16* __restrict__ Kb, const u16* __restrict__ Vb,
    u16* __restrict__ Kt, u16* __restrict__ Vt, const u16* const* __restrict__ ptab, int l){
  __shared__ __align__(16) u16 tile[64*64];
  const int t0 = blockIdx.x*64, bh = blockIdx.y, b = bh>>3, h = bh&7;
  const bool isK = (blockIdx.z == 1);
  const u16* src = isK ? Kb : Vb;
  u16* dst = isK ? Kt : Vt;
  float l2w = 0.f;
  if (isK){
    const u16* td = ptab[10] + l*H_;
    l2w = -expf(bf2f(td[h])) * 1.44269504f;
  }
  const int tid = threadIdx.x;
  #pragma unroll
  for (int it=0; it<2; ++it){
    int tl = it*32 + (tid>>3);
    int n0 = (tid&7)*8;
    union {uint4 q; u16 e[8];} v;
    v.q = *(const uint4*)(src + ((size_t)(b*T_ + t0 + tl))*C_ + h*N_ + n0);
    if (isK){
      int tloc = (t0 + tl) & (Q_-1);
      float sc = exp2f(l2w * (float)(Q_-1 - tloc));
      #pragma unroll
      for (int e=0;e<8;++e) v.e[e] = f2bf(bf2f(v.e[e])*sc);
    }
    int col = n0 ^ (((tl>>3)&7)<<3);
    *(uint4*)&tile[tl*64 + col] = v.q;
  }
  __syncthreads();
  #pragma unroll
  for (int it=0; it<2; ++it){
    int nl = it*32 + (tid>>3);
    int t0l = (tid&7)*8;
    int swz = (tid&7)<<3;
    union {uint4 q; u16 h2[8];} pk;
    #pragma unroll
    for (int e=0;e<8;++e)
      pk.h2[e] = tile[(t0l+e)*64 + (nl ^ swz)];
    *(uint4*)(dst + ((size_t)(bh*N_ + nl))*T_ + t0 + t0l) = pk.q;
  }
}

// ---------------- per-chunk state S_c = (k*wkv)^T @ v via MFMA on Kt(scaled)/Vt ----------------
__global__ __launch_bounds__(256) void wkv_state_mfma(const u16* __restrict__ Kt,
    const u16* __restrict__ Vt, float* __restrict__ S){
  const int c = blockIdx.x, bh = blockIdx.y;
  const int tid = threadIdx.x, wv = tid >> 6, ln = tid & 63;
  const int m16 = ln & 15, q = ln >> 4;
  const u16* ka = Kt + (size_t)(bh*N_ + wv*16 + m16)*T_ + c*Q_;
  const u16* vb = Vt + (size_t)(bh*N_ + m16)*T_ + c*Q_;
  f32x4 acc[4];
  #pragma unroll
  for (int nt=0;nt<4;++nt) acc[nt] = f32x4{0.f,0.f,0.f,0.f};
  #pragma unroll
  for (int ks=0; ks<8; ++ks){
    bf16x8 af = *(const bf16x8*)(ka + ks*32 + q*8);
    #pragma unroll
    for (int nt=0;nt<4;++nt){
      bf16x8 bv = *(const bf16x8*)(vb + (size_t)(nt*16)*T_ + ks*32 + q*8);
      acc[nt] = __builtin_amdgcn_mfma_f32_16x16x32_bf16(af, bv, acc[nt], 0,0,0);
    }
  }
  float* Sp = S + ((size_t)bh*NC_ + c)*(N_*N_);
  #pragma unroll
  for (int nt=0;nt<4;++nt)
    #pragma unroll
    for (int r=0;r<4;++r)
      Sp[(wv*16 + q*4 + r)*N_ + nt*16 + m16] = acc[nt][r];
}

// ---------------- sequential prefix over chunks ----------------
__global__ __launch_bounds__(256) void wkv_prefix(float* __restrict__ S,
    const u16* const* __restrict__ ptab, int l){
  const int bh = blockIdx.x, h = bh&7;
  const u16* td = ptab[10] + l*H_;
  const float l2w = -expf(bf2f(td[h])) * 1.44269504f;
  const float wsd = exp2f(l2w * (float)Q_);
  float* Sp = S + (size_t)bh*NC_*N_*N_;
  for (int e=threadIdx.x; e<N_*N_; e+=256){
    float cur = 0.f;
    for (int cc=0;cc<NC_;++cc){
      float sc = Sp[(size_t)cc*N_*N_ + e];
      Sp[(size_t)cc*N_*N_ + e] = cur;
      cur = wsd*cur + sc;
    }
  }
}

// ---------------- FUSED WKV: intra (MFMA) + inter (VALU r@S) + GroupNorm + silu(g) ----------------
__global__ __launch_bounds__(256) void wkv_fused(const u16* __restrict__ Rb,
    const u16* __restrict__ Kb, const u16* __restrict__ Vt, const float* __restrict__ S,
    const u16* const* __restrict__ ptab, int l,
    const u16* __restrict__ g, u16* __restrict__ out){
  __shared__ float wpow[Q_];
  __shared__ float st[64][68];                 // prefix state (f32)
  __shared__ float rs[64][68];                 // r rows (f32, for inter VALU)
  __shared__ __align__(16) float ylds[64][68]; // intra result; P tile aliases this region
  u16 (*P)[16][72] = reinterpret_cast<u16(*)[16][72]>(&ylds[0][0]);
  const u16* td  = ptab[10] + l*H_;
  const u16* tf  = ptab[11] + l*H_;
  const u16* gnw = ptab[17] + l*C_;
  const u16* gnb = ptab[18] + l*C_;
  const int c = blockIdx.x>>2, ip = blockIdx.x&3;
  const int bh = blockIdx.y, b = bh>>3, h = bh&7;
  const int tid = threadIdx.x, wv = tid >> 6, ln = tid & 63;
  const int m16 = ln & 15, q = ln >> 4;
  const int tx = tid&15, ty = tid>>4;
  const float l2w = -expf(bf2f(td[h])) * 1.44269504f;
  const float uu = bf2f(tf[h]);
  wpow[tid] = exp2f(l2w * (float)tid);
  const float* Sp = S + ((size_t)bh*NC_ + c)*(N_*N_);
  for (int e=tid;e<N_*N_;e+=256) st[e>>6][e&63] = Sp[e];
  const size_t base = ((size_t)b*T_ + (size_t)c*Q_)*C_ + h*N_;
  const int i0 = ip*64;
  {
    const int rrr = tid >> 6, cc2 = tid & 63;
    for (int it=0;it<16;++it){ int i=it*4+rrr; rs[i][cc2]=bf2f(Rb[base+(size_t)(i0+i)*C_+cc2]); }
  }
  __syncthreads();
  // ---- intra-chunk (MFMA) ----
  const int iw0 = ip*64 + wv*16;
  const u16* rrow = Rb + base + (size_t)(iw0 + m16)*C_;
  bf16x8 af0 = *(const bf16x8*)(rrow + q*8);
  bf16x8 af1 = *(const bf16x8*)(rrow + 32 + q*8);
  f32x4 acc[4];
  #pragma unroll
  for (int nt=0;nt<4;++nt) acc[nt] = f32x4{0.f,0.f,0.f,0.f};
  const int irow = iw0 + q*4;
  const u16* vtb = Vt + (size_t)(bh*N_)*T_ + (size_t)c*Q_;
  for (int jt=0; jt<=ip; ++jt){
    f32x4 s[4];
    #pragma unroll
    for (int j2=0;j2<4;++j2) s[j2] = f32x4{0.f,0.f,0.f,0.f};
    #pragma unroll
    for (int j2=0;j2<4;++j2){
      const u16* kr = Kb + base + (size_t)(jt*64 + j2*16 + m16)*C_;
      bf16x8 b0 = *(const bf16x8*)(kr + q*8);
      bf16x8 b1 = *(const bf16x8*)(kr + 32 + q*8);
      s[j2] = __builtin_amdgcn_mfma_f32_16x16x32_bf16(af0, b0, s[j2], 0,0,0);
      s[j2] = __builtin_amdgcn_mfma_f32_16x16x32_bf16(af1, b1, s[j2], 0,0,0);
    }
    #pragma unroll
    for (int j2=0;j2<4;++j2){
      int jc = jt*64 + j2*16 + m16;
      #pragma unroll
      for (int r=0;r<4;++r){
        int ic = irow + r;
        float w = (jc < ic) ? wpow[ic-jc-1] : ((jc==ic) ? uu : 0.f);
        P[wv][q*4+r][j2*16+m16] = f2bf(s[j2][r]*w);
      }
    }
    __asm__ volatile("s_waitcnt lgkmcnt(0)" ::: "memory");
    #pragma unroll
    for (int kp=0;kp<2;++kp){
      bf16x8 ap = *(const bf16x8*)&P[wv][m16][kp*32 + q*8];
      #pragma unroll
      for (int nt=0;nt<4;++nt){
        bf16x8 bv = *(const bf16x8*)(vtb + (size_t)(nt*16 + m16)*T_ + jt*64 + kp*32 + q*8);
        acc[nt] = __builtin_amdgcn_mfma_f32_16x16x32_bf16(ap, bv, acc[nt], 0,0,0);
      }
    }
  }
  __syncthreads();   // all waves done with P region -> safe to write ylds (aliased)
  #pragma unroll
  for (int nt=0;nt<4;++nt)
    #pragma unroll
    for (int r=0;r<4;++r)
      ylds[wv*16 + q*4 + r][nt*16 + m16] = acc[nt][r];
  __syncthreads();
  // ---- inter-chunk (VALU r@S) ----
  float acc2[4][4] = {};
  #pragma unroll
  for (int kk4=0;kk4<16;++kk4){
    f32x4 sv[4], rv[4];
    #pragma unroll
    for (int kkk=0;kkk<4;++kkk) sv[kkk] = *(const f32x4*)&st[kk4*4+kkk][tx*4];
    #pragma unroll
    for (int ii=0;ii<4;++ii)    rv[ii]  = *(const f32x4*)&rs[ty*4+ii][kk4*4];
    #pragma unroll
    for (int ii=0;ii<4;++ii)
      #pragma unroll
      for (int kkk=0;kkk<4;++kkk)
        #pragma unroll
        for (int nn=0;nn<4;++nn)
          acc2[ii][nn] += rv[ii][kkk]*sv[kkk][nn];
  }
  // ---- GroupNorm + silu(g), 16-lane reduce ----
  #pragma unroll
  for (int ii=0;ii<4;ii++){
    int tl = ty*4+ii;
    int il = i0 + tl;
    size_t roff = base + (size_t)il*C_;
    float w = wpow[il];
    f32x4 yv = *(const f32x4*)&ylds[tl][tx*4];
    float val[4];
    float s=0.f, ss=0.f;
    #pragma unroll
    for (int nn=0;nn<4;nn++){
      float v = yv[nn] + w*acc2[ii][nn];
      val[nn]=v; s+=v; ss+=v*v;
    }
    #pragma unroll
    for (int o=8;o>0;o>>=1){ s+=__shfl_xor(s,o,64); ss+=__shfl_xor(ss,o,64); }
    float mu = s*(1.f/N_);
    float var = ss*(1.f/N_) - mu*mu;
    float inv = rsqrtf(fmaxf(var,0.f) + 6.4e-4f);   // GN_EPS = 1e-5*64
    union { ushort4 v; u16 e[4]; } gv, ov;
    gv.v = *(const ushort4*)(g + roff + tx*4);
    #pragma unroll
    for (int nn=0;nn<4;nn++){
      int ci = h*N_ + tx*4 + nn;
      float gg = bf2f(gv.e[nn]);
      float sil = gg/(1.f+expf(-gg));
      ov.e[nn] = f2bf(((val[nn]-mu)*inv*bf2f(gnw[ci]) + bf2f(gnb[ci]))*sil);
    }
    *(ushort4*)(out + roff + tx*4) = ov.v;
  }
}

// ---------------- logits for last position: [B,V] = xf @ wte^T (raw dtype) ----------------
__global__ __launch_bounds__(256) void logits_kernel(const float* __restrict__ xf,
    const void* __restrict__ wteR, void* __restrict__ out, const int* __restrict__ flag){
  const int wid = threadIdx.x>>6, lane = threadIdx.x&63;
  const int gw = blockIdx.x*4 + wid;     // 0 .. B*V-1
  const int b = gw / V_, v = gw - b*V_;
  const float* xr = xf + b*C_;
  float s = 0.f;
  if (*flag){
    const float* wrow = (const float*)wteR + (size_t)v*C_;
    float4 w0 = ((const float4*)wrow)[lane*2];
    float4 w1 = ((const float4*)wrow)[lane*2+1];
    const float* xp = xr + lane*8;
    s = w0.x*xp[0] + w0.y*xp[1] + w0.z*xp[2] + w0.w*xp[3]
      + w1.x*xp[4] + w1.y*xp[5] + w1.z*xp[6] + w1.w*xp[7];
  } else {
    const u16* wrow = (const u16*)wteR + (size_t)v*C_;
    union {uint4 q; u16 h[8];} uu;
    uu.q = *(const uint4*)(wrow + lane*8);
    #pragma unroll
    for (int j=0;j<8;j++) s += bf2f(uu.h[j])*xr[lane*8+j];
  }
  #pragma unroll
  for (int o=32;o>0;o>>=1) s += __shfl_down(s,o,64);
  if (lane==0){
    size_t o = (size_t)b*V_ + v;
    if (*flag) ((float*)out)[o] = s;          // fp32 harness
    else       ((u16*)out)[o]   = f2bf(s);    // bf16 harness
  }
}

extern "C" void kernel_launch(void* const* d_in, const int* in_sizes, int n_in,
                              void* d_out, int out_size, void* d_ws, size_t ws_size,
                              hipStream_t stream){
  (void)out_size; (void)ws_size; (void)n_in;
  const int* idx  = (const int*)d_in[0];

  char* ws = (char*)d_ws;
  const size_t MC  = (size_t)M_*C_;
  // ---- workspace layout (bytes) ----
  size_t o = 0;
  int* flag = (int*)(ws + o);            o += 1024;
  const u16** ptab = (const u16**)(ws + o); o += 1024;
  float* X   = (float*)(ws + o);         o += MC*4;            // fp32 residual
  u16* MK = (u16*)(ws + o);              o += MC*2;            // also YGN
  u16* MV = (u16*)(ws + o);              o += MC*2;
  u16* MR = (u16*)(ws + o);              o += MC*2;            // also S (tmix) / RRb (cmix)
  u16* MG = (u16*)(ws + o);              o += MC*2;
  u16* Rb = (u16*)(ws + o);              o += MC*2;            // H1 spans Rb..Vb
  u16* Kb = (u16*)(ws + o);              o += MC*2;
  u16* Vb = (u16*)(ws + o);              o += MC*2;
  u16* Gb = (u16*)(ws + o);              o += MC*2;
  u16* Kt = (u16*)(ws + o);              o += MC*2;            // scaled k^T per (b,h): [BH*64, T]
  u16* Vt = (u16*)(ws + o);              o += MC*2;            // v^T per (b,h): [BH*64, T]
  float* XF = (float*)(ws + o);          o += 65536;
  u16* pool = (u16*)(ws + o);            // fp32->bf16 converted inputs 3..23
  u16* YGN = MK;
  float* S  = (float*)MR;    // live only during tmix phase (4 MB < 8.4 MB)
  u16* H1 = Rb;              // [M,3C] bf16, spans Rb..Vb
  u16* RRb = MR;             // [M,C] bf16 sigmoid gate (cmix phase)

  // ---- dtype detect + pointer table + (conditional) conversion of tensors 3..23 ----
  detect_kernel<<<1,256,0,stream>>>(d_in[12], flag);   // probe Wr
  CvtTab tab; PtrTab pt;
  int nblocks;
  {
    size_t poff = 0; int acc8 = 0, bacc = 0;
    long long total8 = 0;
    for (int i=3;i<24;i++) total8 += (long long)(in_sizes[i] >> 3);
    pt.raw[0] = d_in[1]; pt.off[0] = 0;   // wte: raw only (never used via ptab)
    pt.raw[1] = d_in[2]; pt.off[1] = 0;   // wpe: raw only (never used via ptab)
    for (int i=3;i<24;i++){
      int j = i-3;
      pt.raw[i-1] = d_in[i];
      pt.off[i-1] = (long long)poff;
      poff += (size_t)in_sizes[i];
      tab.s[j] = d_in[i];
      tab.off8[j] = acc8;
      tab.bstart[j] = bacc;
      int n8 = in_sizes[i] >> 3;
      int nb = (int)(((long long)n8 * 2048 + total8 - 1) / total8);
      if (nb < 1) nb = 1;
      acc8 += n8; bacc += nb;
    }
    tab.off8[21] = acc8; tab.bstart[21] = bacc;
    nblocks = bacc;
  }
  fill_ptab<<<1,64,0,stream>>>(pt, pool, flag, ptab);
  convert_all<<<nblocks,256,0,stream>>>(tab, pool, flag);

  embed_kernel<<<M_,256,0,stream>>>(idx, d_in[1], d_in[2], flag, X);
  dim3 g4 (M_/128, C_/64, 4);      // (64,8,4) fused projections, 128x64
  dim3 gkv(T_/64, B_*H_, 2);       // K/V transpose
  dim3 gck(M_/128, 32);            // 24 ck tiles + 8 cr tiles, 128x64
  dim3 gwo(M_/128, C_/64);         // (64,8) 128x64
  for (int l=0;l<L_;++l){
    // ---- time mix ----
    ln_tmix_kernel<<<M_,256,0,stream>>>(X, ptab, l, MK,MV,MR,MG);
    gemm4_mfma<<<g4,256,0,stream>>>(ptab, l, MK, Rb, Kb, Vb, Gb);
    kvtrans<<<gkv,256,0,stream>>>(Kb, Vb, Kt, Vt, ptab, l);
    wkv_state_mfma<<<dim3(NC_, B_*H_),256,0,stream>>>(Kt, Vt, S);
    wkv_prefix<<<B_*H_,256,0,stream>>>(S, ptab, l);
    wkv_fused<<<dim3(NC_*4, B_*H_),256,0,stream>>>(Rb, Kb, Vt, S, ptab, l, Gb, YGN);
    gemm_wo<<<gwo,256,0,stream>>>(ptab, l, YGN, X);
    // ---- channel mix ----
    ln_cmix_kernel<<<M_,256,0,stream>>>(X, ptab, l, MK, MV);
    gemm_ck_cr<<<gck,256,0,stream>>>(ptab, l, MK, H1, MV, RRb);
    gemm_cmix<<<gwo,256,0,stream>>>(ptab, l, H1, X, RRb);
  }
  lnf_last<<<B_,256,0,stream>>>(X, ptab, XF);
  logits_kernel<<<(B_*V_)/4,256,0,stream>>>(XF, d_in[1], d_out, flag);
}

// Round 9
// 1498.919 us; speedup vs baseline: 1.1418x; 1.0359x over previous
//
#include <hip/hip_runtime.h>

#define L_ 6
#define H_ 8
#define C_ 512
#define V_ 32000
#define B_ 2
#define T_ 4096
#define Q_ 256
#define N_ 64
#define NC_ 16
#define M_ 8192   // B*T

typedef unsigned short u16;
typedef __attribute__((ext_vector_type(8))) short bf16x8;
typedef __attribute__((ext_vector_type(4))) float f32x4;

__device__ __forceinline__ float bf2f(u16 u){
  return __uint_as_float(((unsigned int)u) << 16);
}
__device__ __forceinline__ u16 f2bf(float f){
  unsigned int x = __float_as_uint(f);
  return (u16)((x + 0x7fffu + ((x >> 16) & 1u)) >> 16);
}

__device__ __forceinline__ void gl_lds16(const u16* g, u16* l){
  __builtin_amdgcn_global_load_lds((const __attribute__((address_space(1))) void*)g,
                                   (__attribute__((address_space(3))) void*)l, 16, 0, 0);
}

// ---------------- dtype detection: bf16 weights never have |x|>=2 ----------------
__global__ __launch_bounds__(256) void detect_kernel(const void* __restrict__ probe,
                                                     int* __restrict__ flag){
  __shared__ int cnt;
  if (threadIdx.x == 0) cnt = 0;
  __syncthreads();
  const u16* p = (const u16*)probe;
  int c = 0;
  for (int i = threadIdx.x; i < 2048; i += 256){
    int e = (p[i] >> 7) & 0xFF;
    if (e >= 128) c++;
  }
  atomicAdd(&cnt, c);
  __syncthreads();
  if (threadIdx.x == 0) *flag = (cnt > 32) ? 1 : 0;  // 1 = inputs are fp32
}

// ---------------- pointer table: bf16 -> use raw inputs in place; fp32 -> converted pool ----------------
struct PtrTab { const void* raw[23]; long long off[23]; };

__global__ __launch_bounds__(64) void fill_ptab(PtrTab pt, const u16* __restrict__ pool,
    const int* __restrict__ flag, const u16** __restrict__ ptab){
  int i = threadIdx.x;
  if (i < 23)
    ptab[i+1] = (*flag) ? (pool + pt.off[i]) : (const u16*)pt.raw[i];
}

// ---------------- fp32 -> bf16 conversion, tensors 3..23 only (wte/wpe stay raw) ----------------
struct CvtTab { const void* s[21]; int off8[22]; int bstart[22]; };

__global__ __launch_bounds__(256) void convert_all(CvtTab t, u16* __restrict__ pool,
                                                   const int* __restrict__ flag){
  if (!*flag) return;    // bf16 inputs are consumed in place via ptab
  int i = 0;
  #pragma unroll
  for (int k = 1; k < 21; k++) if ((int)blockIdx.x >= t.bstart[k]) i = k;
  const void* sp = t.s[0];
  #pragma unroll
  for (int k = 1; k < 21; k++) if (i == k) sp = t.s[k];
  const int n8 = t.off8[i+1] - t.off8[i];
  const int nb = t.bstart[i+1] - t.bstart[i];
  const int lb = (int)blockIdx.x - t.bstart[i];
  uint4* dp = (uint4*)pool + t.off8[i];
  const int stride = nb * 256;
  const float4* sf = (const float4*)sp;
  for (int j = lb*256 + (int)threadIdx.x; j < n8; j += stride){
    float4 a0 = sf[2*j], a1 = sf[2*j+1];
    uint4 r0;
    r0.x = (unsigned)f2bf(a0.x) | ((unsigned)f2bf(a0.y) << 16);
    r0.y = (unsigned)f2bf(a0.z) | ((unsigned)f2bf(a0.w) << 16);
    r0.z = (unsigned)f2bf(a1.x) | ((unsigned)f2bf(a1.y) << 16);
    r0.w = (unsigned)f2bf(a1.z) | ((unsigned)f2bf(a1.w) << 16);
    dp[j] = r0;
  }
}

// ---------------- embedding: x = wte[idx] + wpe (reads raw dtype directly) ----------------
__global__ __launch_bounds__(256) void embed_kernel(const int* __restrict__ idx,
    const void* __restrict__ wteR, const void* __restrict__ wpeR,
    const int* __restrict__ flag, float* __restrict__ x){
  int row = blockIdx.x;                 // b*T + t
  int t = row & (T_-1);
  int tok = idx[row];
  float* xo = x + (size_t)row * C_;
  int c = threadIdx.x;
  float a0,a1,b0,b1;
  if (*flag){
    const float* we = (const float*)wteR + (size_t)tok * C_;
    const float* wp = (const float*)wpeR + (size_t)t * C_;
    a0 = we[c]; a1 = we[c+256]; b0 = wp[c]; b1 = wp[c+256];
  } else {
    const u16* we = (const u16*)wteR + (size_t)tok * C_;
    const u16* wp = (const u16*)wpeR + (size_t)t * C_;
    a0 = bf2f(we[c]); a1 = bf2f(we[c+256]); b0 = bf2f(wp[c]); b1 = bf2f(wp[c+256]);
  }
  xo[c]     = a0 + b0;
  xo[c+256] = a1 + b1;
}

// ---------------- fused LN + time-mix token shift (recomputes LN of row t-1) ----------------
__global__ __launch_bounds__(256) void ln_tmix_kernel(const float* __restrict__ x,
    const u16* const* __restrict__ ptab, int l,
    u16* __restrict__ xk, u16* __restrict__ xv, u16* __restrict__ xr, u16* __restrict__ xg){
  const u16* w  = ptab[3] + l*C_;
  const u16* mk = ptab[6] + l*C_;
  const u16* mv = ptab[7] + l*C_;
  const u16* mr = ptab[8] + l*C_;
  const u16* mg = ptab[9] + l*C_;
  int row = blockIdx.x; int t = row & (T_-1);
  size_t off = (size_t)row*C_;
  const float* cur = x + off;
  int c = threadIdx.x;
  float v0 = cur[c], v1 = cur[c+256];
  float p0 = 0.f, p1 = 0.f;
  if (t){ p0 = cur[c - C_]; p1 = cur[c+256 - C_]; }
  float s = v0+v1, ss = v0*v0+v1*v1;
  float sp = p0+p1, ssp = p0*p0+p1*p1;
  int lane = c & 63, wid = c >> 6;
  #pragma unroll
  for (int o=32;o>0;o>>=1){
    s  += __shfl_down(s,o,64);  ss  += __shfl_down(ss,o,64);
    sp += __shfl_down(sp,o,64); ssp += __shfl_down(ssp,o,64);
  }
  __shared__ float r1[4], r2[4], r3[4], r4[4];
  if (lane==0){ r1[wid]=s; r2[wid]=ss; r3[wid]=sp; r4[wid]=ssp; }
  __syncthreads();
  if (c==0){
    float a =r1[0]+r1[1]+r1[2]+r1[3], bq=r2[0]+r2[1]+r2[2]+r2[3];
    float ap=r3[0]+r3[1]+r3[2]+r3[3], bp=r4[0]+r4[1]+r4[2]+r4[3];
    float mu  = a *(1.f/C_); float var  = bq*(1.f/C_) - mu*mu;
    float mup = ap*(1.f/C_); float varp = bp*(1.f/C_) - mup*mup;
    r1[0]=mu;  r2[0]=rsqrtf(fmaxf(var ,0.f)+1e-5f);
    r3[0]=mup; r4[0]=rsqrtf(fmaxf(varp,0.f)+1e-5f);
  }
  __syncthreads();
  float mu=r1[0], inv=r2[0], mup=r3[0], invp=r4[0];
  #pragma unroll
  for (int p=0;p<2;p++){
    int cc = c + p*256;
    float wc = bf2f(w[cc]);
    float xc = ((p?v1:v0)-mu)*inv*wc;
    float xp = t ? ((p?p1:p0)-mup)*invp*wc : 0.f;
    float xx = xp - xc;
    xk[off+cc] = f2bf(xc + xx*bf2f(mk[cc]));
    xv[off+cc] = f2bf(xc + xx*bf2f(mv[cc]));
    xr[off+cc] = f2bf(xc + xx*bf2f(mr[cc]));
    xg[off+cc] = f2bf(xc + xx*bf2f(mg[cc]));
  }
}

// ---------------- fused LN + channel-mix token shift ----------------
__global__ __launch_bounds__(256) void ln_cmix_kernel(const float* __restrict__ x,
    const u16* const* __restrict__ ptab, int l,
    u16* __restrict__ xk, u16* __restrict__ xr){
  const u16* w  = ptab[4]  + l*C_;
  const u16* mk = ptab[19] + l*C_;
  const u16* mr = ptab[20] + l*C_;
  int row = blockIdx.x; int t = row & (T_-1);
  size_t off = (size_t)row*C_;
  const float* cur = x + off;
  int c = threadIdx.x;
  float v0 = cur[c], v1 = cur[c+256];
  float p0 = 0.f, p1 = 0.f;
  if (t){ p0 = cur[c - C_]; p1 = cur[c+256 - C_]; }
  float s = v0+v1, ss = v0*v0+v1*v1;
  float sp = p0+p1, ssp = p0*p0+p1*p1;
  int lane = c & 63, wid = c >> 6;
  #pragma unroll
  for (int o=32;o>0;o>>=1){
    s  += __shfl_down(s,o,64);  ss  += __shfl_down(ss,o,64);
    sp += __shfl_down(sp,o,64); ssp += __shfl_down(ssp,o,64);
  }
  __shared__ float r1[4], r2[4], r3[4], r4[4];
  if (lane==0){ r1[wid]=s; r2[wid]=ss; r3[wid]=sp; r4[wid]=ssp; }
  __syncthreads();
  if (c==0){
    float a =r1[0]+r1[1]+r1[2]+r1[3], bq=r2[0]+r2[1]+r2[2]+r2[3];
    float ap=r3[0]+r3[1]+r3[2]+r3[3], bp=r4[0]+r4[1]+r4[2]+r4[3];
    float mu  = a *(1.f/C_); float var  = bq*(1.f/C_) - mu*mu;
    float mup = ap*(1.f/C_); float varp = bp*(1.f/C_) - mup*mup;
    r1[0]=mu;  r2[0]=rsqrtf(fmaxf(var ,0.f)+1e-5f);
    r3[0]=mup; r4[0]=rsqrtf(fmaxf(varp,0.f)+1e-5f);
  }
  __syncthreads();
  float mu=r1[0], inv=r2[0], mup=r3[0], invp=r4[0];
  #pragma unroll
  for (int p=0;p<2;p++){
    int cc = c + p*256;
    float wc = bf2f(w[cc]);
    float xc = ((p?v1:v0)-mu)*inv*wc;
    float xp = t ? ((p?p1:p0)-mup)*invp*wc : 0.f;
    float xx = xp - xc;
    xk[off+cc] = f2bf(xc + xx*bf2f(mk[cc]));
    xr[off+cc] = f2bf(xc + xx*bf2f(mr[cc]));
  }
}

// ---------------- final LN for last position only ----------------
__global__ __launch_bounds__(256) void lnf_last(const float* __restrict__ x,
    const u16* const* __restrict__ ptab, float* __restrict__ xf){
  const u16* w = ptab[5];
  int b = blockIdx.x;
  const float* xr = x + ((size_t)b*T_ + (T_-1))*C_;
  int c = threadIdx.x;
  float v0 = xr[c], v1 = xr[c+256];
  float s = v0+v1, ss = v0*v0+v1*v1;
  int lane = c & 63, wid = c >> 6;
  #pragma unroll
  for (int o=32;o>0;o>>=1){ s += __shfl_down(s,o,64); ss += __shfl_down(ss,o,64); }
  __shared__ float r1[4], r2[4];
  if (lane==0){ r1[wid]=s; r2[wid]=ss; }
  __syncthreads();
  if (c==0){
    float a=r1[0]+r1[1]+r1[2]+r1[3], bq=r2[0]+r2[1]+r2[2]+r2[3];
    float mu = a*(1.f/C_);
    float var = bq*(1.f/C_) - mu*mu;
    r1[0]=mu; r2[0]=rsqrtf(fmaxf(var,0.f)+1e-5f);
  }
  __syncthreads();
  float mu=r1[0], inv=r2[0];
  xf[b*C_+c]     = (v0-mu)*inv*bf2f(w[c]);
  xf[b*C_+c+256] = (v1-mu)*inv*bf2f(w[c+256]);
}

// ================= MFMA GEMM: 128(M) x 64(N), BK=64, 24KB LDS =================
#define ACT_RELU2_BF16 1
#define ACT_ADD_F32 2
#define ACT_BF16 3
#define ACT_CMIX 4      // Yf += v * bf2f(AuxB) (AuxB holds sigmoid gate)
#define ACT_SIG_BF16 7  // Yb = bf16(sigmoid(v))

template<int ACT>
__device__ __forceinline__ void gemm_mfma_body(u16* __restrict__ Al, u16* __restrict__ Bl,
    const u16* __restrict__ X, const u16* __restrict__ W,
    float* __restrict__ Yf, u16* __restrict__ Yb, const u16* __restrict__ AuxB,
    int Ndim, int Kdim, int bm, int bn){
  const int tid = threadIdx.x;
  const int wv = tid >> 6, ln = tid & 63;
  const int m16 = ln & 15, q = ln >> 4;

  f32x4 acc[2][4];
  #pragma unroll
  for (int i=0;i<2;i++)
    #pragma unroll
    for (int j=0;j<4;j++) acc[i][j] = f32x4{0.f,0.f,0.f,0.f};

  const int r0 = wv*8 + (ln >> 3);
  const int c0 = (ln & 7)*8;
  const u16* ga = X + (size_t)(bm + r0)*Kdim + c0;
  const u16* gb = W + (size_t)(bn + r0)*Kdim + c0;
  u16* la = Al + r0*64 + c0;
  u16* lb = Bl + r0*64 + c0;

  for (int k0=0; k0<Kdim; k0+=64){
    #pragma unroll
    for (int s=0;s<4;s++)
      gl_lds16(ga + (size_t)(s*32)*Kdim + k0, la + s*2048);
    #pragma unroll
    for (int s=0;s<2;s++)
      gl_lds16(gb + (size_t)(s*32)*Kdim + k0, lb + s*2048);
    __syncthreads();
    #pragma unroll
    for (int kh=0; kh<2; kh++){
      bf16x8 af[2], bfr[4];
      #pragma unroll
      for (int i=0;i<2;i++) af[i]  = *(const bf16x8*)(Al + (wv*32 + i*16 + m16)*64 + kh*32 + q*8);
      #pragma unroll
      for (int j=0;j<4;j++) bfr[j] = *(const bf16x8*)(Bl + (j*16 + m16)*64 + kh*32 + q*8);
      #pragma unroll
      for (int i=0;i<2;i++)
        #pragma unroll
        for (int j=0;j<4;j++)
          acc[i][j] = __builtin_amdgcn_mfma_f32_16x16x32_bf16(af[i], bfr[j], acc[i][j], 0, 0, 0);
    }
    __syncthreads();
  }

  // epilogue: C/D layout col=lane&15, row=quad*4+reg
  #pragma unroll
  for (int i=0;i<2;i++){
    int row = bm + wv*32 + i*16 + q*4;
    #pragma unroll
    for (int j=0;j<4;j++){
      int col = bn + j*16 + m16;
      #pragma unroll
      for (int r=0;r<4;r++){
        size_t off = (size_t)(row + r)*Ndim + col;
        float v = acc[i][j][r];
        if (ACT==ACT_ADD_F32) Yf[off] += v;
        else if (ACT==ACT_CMIX){ Yf[off] += v * bf2f(AuxB[off]); }
        else if (ACT==ACT_BF16) Yb[off] = f2bf(v);
        else if (ACT==ACT_RELU2_BF16){ float rr = v>0.f ? v : 0.f; Yb[off] = f2bf(rr*rr); }
        else if (ACT==ACT_SIG_BF16) Yb[off] = f2bf(1.f/(1.f+expf(-v)));
      }
    }
  }
}

#define GEMM_SH __shared__ __align__(16) u16 SH[128*64 + 64*64]

// fused r/k/v/g projections, 128x64 tiles, grid (64,8,4)
__global__ __launch_bounds__(256,4) void gemm4_mfma(const u16* const* __restrict__ ptab, int l,
    const u16* __restrict__ Abase,
    u16* __restrict__ Rb, u16* __restrict__ Kb, u16* __restrict__ Vb, u16* __restrict__ Gb){
  GEMM_SH;
  const size_t MC = (size_t)M_*C_;
  const size_t ws = (size_t)l*C_*C_;
  const int bm = blockIdx.x*128, bn = blockIdx.y*64;
  switch (blockIdx.z){
    case 0:  gemm_mfma_body<ACT_BF16>(SH, SH+128*64, Abase + 2*MC, ptab[12]+ws, nullptr, Rb, nullptr, C_, C_, bm, bn); break;
    case 1:  gemm_mfma_body<ACT_BF16>(SH, SH+128*64, Abase,        ptab[13]+ws, nullptr, Kb, nullptr, C_, C_, bm, bn); break;
    case 2:  gemm_mfma_body<ACT_BF16>(SH, SH+128*64, Abase + 1*MC, ptab[14]+ws, nullptr, Vb, nullptr, C_, C_, bm, bn); break;
    default: gemm_mfma_body<ACT_BF16>(SH, SH+128*64, Abase + 3*MC, ptab[15]+ws, nullptr, Gb, nullptr, C_, C_, bm, bn); break;
  }
}

// fused cmix key (relu^2 -> H1) + receptance gate (sigmoid -> RRb), 128x64, grid (64,32)
__global__ __launch_bounds__(256,4) void gemm_ck_cr(const u16* const* __restrict__ ptab, int l,
    const u16* __restrict__ MK, u16* __restrict__ H1,
    const u16* __restrict__ MV, u16* __restrict__ RRb){
  GEMM_SH;
  if (blockIdx.y < 24)
    gemm_mfma_body<ACT_RELU2_BF16>(SH, SH+128*64, MK, ptab[21]+(size_t)l*3*C_*C_, nullptr, H1, nullptr,
                                   3*C_, C_, blockIdx.x*128, blockIdx.y*64);
  else
    gemm_mfma_body<ACT_SIG_BF16>(SH, SH+128*64, MV, ptab[23]+(size_t)l*C_*C_, nullptr, RRb, nullptr,
                                 C_, C_, blockIdx.x*128, (blockIdx.y-24)*64);
}

// output projection with residual add: X += YGN @ Wo^T   (grid 64x8)
__global__ __launch_bounds__(256,4) void gemm_wo(const u16* const* __restrict__ ptab, int l,
    const u16* __restrict__ YGN, float* __restrict__ X){
  GEMM_SH;
  gemm_mfma_body<ACT_ADD_F32>(SH, SH+128*64, YGN, ptab[16]+(size_t)l*C_*C_, X, nullptr, nullptr,
                              C_, C_, blockIdx.x*128, blockIdx.y*64);
}

// cmix value GEMM with fused tail: X += gate * (H1 @ Wcv^T)   (grid 64x8)
__global__ __launch_bounds__(256,4) void gemm_cmix(const u16* const* __restrict__ ptab, int l,
    const u16* __restrict__ H1, float* __restrict__ X, const u16* __restrict__ RRb){
  GEMM_SH;
  gemm_mfma_body<ACT_CMIX>(SH, SH+128*64, H1, ptab[22]+(size_t)l*3*C_*C_, X, nullptr, RRb,
                           C_, 3*C_, blockIdx.x*128, blockIdx.y*64);
}

// ---------------- K/V per-(b,h) transpose; K gets wdec^(Q-1-tloc) scale ----------------
// grid (T/64, B*H, 2): z=0 V->Vt plain, z=1 K->Kt scaled
__global__ __launch_bounds__(256) void kvtrans(const u16* __restrict__ Kb, const u16* __restrict__ Vb,
    u16* __restrict__ Kt, u16* __restrict__ Vt, const u16* const* __restrict__ ptab, int l){
  __shared__ __align__(16) u16 tile[64*64];
  const int t0 = blockIdx.x*64, bh = blockIdx.y, b = bh>>3, h = bh&7;
  const bool isK = (blockIdx.z == 1);
  const u16* src = isK ? Kb : Vb;
  u16* dst = isK ? Kt : Vt;
  float l2w = 0.f;
  if (isK){
    const u16* td = ptab[10] + l*H_;
    l2w = -expf(bf2f(td[h])) * 1.44269504f;
  }
  const int tid = threadIdx.x;
  #pragma unroll
  for (int it=0; it<2; ++it){
    int tl = it*32 + (tid>>3);
    int n0 = (tid&7)*8;
    union {uint4 q; u16 e[8];} v;
    v.q = *(const uint4*)(src + ((size_t)(b*T_ + t0 + tl))*C_ + h*N_ + n0);
    if (isK){
      int tloc = (t0 + tl) & (Q_-1);
      float sc = exp2f(l2w * (float)(Q_-1 - tloc));
      #pragma unroll
      for (int e=0;e<8;++e) v.e[e] = f2bf(bf2f(v.e[e])*sc);
    }
    int col = n0 ^ (((tl>>3)&7)<<3);
    *(uint4*)&tile[tl*64 + col] = v.q;
  }
  __syncthreads();
  #pragma unroll
  for (int it=0; it<2; ++it){
    int nl = it*32 + (tid>>3);
    int t0l = (tid&7)*8;
    int swz = (tid&7)<<3;
    union {uint4 q; u16 h2[8];} pk;
    #pragma unroll
    for (int e=0;e<8;++e)
      pk.h2[e] = tile[(t0l+e)*64 + (nl ^ swz)];
    *(uint4*)(dst + ((size_t)(bh*N_ + nl))*T_ + t0 + t0l) = pk.q;
  }
}

// ---------------- per-chunk state, stored TRANSPOSED: St[v_feat][k_feat] ----------------
__global__ __launch_bounds__(256) void wkv_state_mfma(const u16* __restrict__ Kt,
    const u16* __restrict__ Vt, float* __restrict__ S){
  const int c = blockIdx.x, bh = blockIdx.y;
  const int tid = threadIdx.x, wv = tid >> 6, ln = tid & 63;
  const int m16 = ln & 15, q = ln >> 4;
  const u16* ka = Kt + (size_t)(bh*N_ + wv*16 + m16)*T_ + c*Q_;
  const u16* vb = Vt + (size_t)(bh*N_ + m16)*T_ + c*Q_;
  f32x4 acc[4];
  #pragma unroll
  for (int nt=0;nt<4;++nt) acc[nt] = f32x4{0.f,0.f,0.f,0.f};
  #pragma unroll
  for (int ks=0; ks<8; ++ks){
    bf16x8 af = *(const bf16x8*)(ka + ks*32 + q*8);
    #pragma unroll
    for (int nt=0;nt<4;++nt){
      bf16x8 bv = *(const bf16x8*)(vb + (size_t)(nt*16)*T_ + ks*32 + q*8);
      acc[nt] = __builtin_amdgcn_mfma_f32_16x16x32_bf16(af, bv, acc[nt], 0,0,0);
    }
  }
  float* Sp = S + ((size_t)bh*NC_ + c)*(N_*N_);
  // MFMA out: k_feat row = wv*16+q*4+r, v_feat col = nt*16+m16. Store transposed.
  #pragma unroll
  for (int nt=0;nt<4;++nt)
    #pragma unroll
    for (int r=0;r<4;++r)
      Sp[(nt*16 + m16)*N_ + (wv*16 + q*4 + r)] = acc[nt][r];
}

// ---------------- sequential prefix over chunks (elementwise, layout-agnostic) ----------------
__global__ __launch_bounds__(256) void wkv_prefix(float* __restrict__ S,
    const u16* const* __restrict__ ptab, int l){
  const int bh = blockIdx.x, h = bh&7;
  const u16* td = ptab[10] + l*H_;
  const float l2w = -expf(bf2f(td[h])) * 1.44269504f;
  const float wsd = exp2f(l2w * (float)Q_);
  float* Sp = S + (size_t)bh*NC_*N_*N_;
  for (int e=threadIdx.x; e<N_*N_; e+=256){
    float cur = 0.f;
    for (int cc=0;cc<NC_;++cc){
      float sc = Sp[(size_t)cc*N_*N_ + e];
      Sp[(size_t)cc*N_*N_ + e] = cur;
      cur = wsd*cur + sc;
    }
  }
}

// ---------------- FUSED WKV: intra (MFMA) + inter (MFMA on bf16 St) + GN + silu(g) ----------------
// Both accumulators live in the MFMA C/D layout; no layout round-trip, ~19.5 KB LDS.
__global__ __launch_bounds__(256) void wkv_fused(const u16* __restrict__ Rb,
    const u16* __restrict__ Kb, const u16* __restrict__ Vt, const float* __restrict__ S,
    const u16* const* __restrict__ ptab, int l,
    const u16* __restrict__ g, u16* __restrict__ out){
  __shared__ float wpow[Q_];
  __shared__ __align__(16) u16 P[4][16][72];    // 9216 B, wave-private quarters
  __shared__ __align__(16) u16 stl[64][72];     // St in bf16: [v_feat n][k_feat k], 9216 B
  const u16* td  = ptab[10] + l*H_;
  const u16* tf  = ptab[11] + l*H_;
  const u16* gnw = ptab[17] + l*C_;
  const u16* gnb = ptab[18] + l*C_;
  const int c = blockIdx.x>>2, ip = blockIdx.x&3;
  const int bh = blockIdx.y, b = bh>>3, h = bh&7;
  const int tid = threadIdx.x, wv = tid >> 6, ln = tid & 63;
  const int m16 = ln & 15, q = ln >> 4;
  const float l2w = -expf(bf2f(td[h])) * 1.44269504f;
  const float uu = bf2f(tf[h]);
  wpow[tid] = exp2f(l2w * (float)tid);
  // stage prefix state (f32, transposed layout) -> bf16 LDS
  {
    const float* Sp = S + ((size_t)bh*NC_ + c)*(N_*N_);
    #pragma unroll
    for (int k2=0;k2<16;++k2){
      int e = tid + k2*256;           // e = n*64 + k
      stl[e>>6][e&63] = f2bf(Sp[e]);
    }
  }
  __syncthreads();
  const size_t base = ((size_t)b*T_ + (size_t)c*Q_)*C_ + h*N_;
  // ---- intra-chunk (MFMA) ----
  const int iw0 = ip*64 + wv*16;
  const u16* rrow = Rb + base + (size_t)(iw0 + m16)*C_;
  bf16x8 af0 = *(const bf16x8*)(rrow + q*8);
  bf16x8 af1 = *(const bf16x8*)(rrow + 32 + q*8);
  f32x4 acc[4];
  #pragma unroll
  for (int nt=0;nt<4;++nt) acc[nt] = f32x4{0.f,0.f,0.f,0.f};
  const int irow = iw0 + q*4;
  const u16* vtb = Vt + (size_t)(bh*N_)*T_ + (size_t)c*Q_;
  for (int jt=0; jt<=ip; ++jt){
    f32x4 s[4];
    #pragma unroll
    for (int j2=0;j2<4;++j2) s[j2] = f32x4{0.f,0.f,0.f,0.f};
    #pragma unroll
    for (int j2=0;j2<4;++j2){
      const u16* kr = Kb + base + (size_t)(jt*64 + j2*16 + m16)*C_;
      bf16x8 b0 = *(const bf16x8*)(kr + q*8);
      bf16x8 b1 = *(const bf16x8*)(kr + 32 + q*8);
      s[j2] = __builtin_amdgcn_mfma_f32_16x16x32_bf16(af0, b0, s[j2], 0,0,0);
      s[j2] = __builtin_amdgcn_mfma_f32_16x16x32_bf16(af1, b1, s[j2], 0,0,0);
    }
    #pragma unroll
    for (int j2=0;j2<4;++j2){
      int jc = jt*64 + j2*16 + m16;
      #pragma unroll
      for (int r=0;r<4;++r){
        int ic = irow + r;
        float w = (jc < ic) ? wpow[ic-jc-1] : ((jc==ic) ? uu : 0.f);
        P[wv][q*4+r][j2*16+m16] = f2bf(s[j2][r]*w);
      }
    }
    __asm__ volatile("s_waitcnt lgkmcnt(0)" ::: "memory");
    #pragma unroll
    for (int kp=0;kp<2;++kp){
      bf16x8 ap = *(const bf16x8*)&P[wv][m16][kp*32 + q*8];
      #pragma unroll
      for (int nt=0;nt<4;++nt){
        bf16x8 bv = *(const bf16x8*)(vtb + (size_t)(nt*16 + m16)*T_ + jt*64 + kp*32 + q*8);
        acc[nt] = __builtin_amdgcn_mfma_f32_16x16x32_bf16(ap, bv, acc[nt], 0,0,0);
      }
    }
  }
  // ---- inter-chunk via MFMA: y2 = r @ St^T (St rows are output cols) ----
  f32x4 acc2[4];
  #pragma unroll
  for (int nt=0;nt<4;++nt) acc2[nt] = f32x4{0.f,0.f,0.f,0.f};
  #pragma unroll
  for (int nt=0;nt<4;++nt){
    bf16x8 sb0 = *(const bf16x8*)&stl[nt*16 + m16][q*8];
    bf16x8 sb1 = *(const bf16x8*)&stl[nt*16 + m16][32 + q*8];
    acc2[nt] = __builtin_amdgcn_mfma_f32_16x16x32_bf16(af0, sb0, acc2[nt], 0,0,0);
    acc2[nt] = __builtin_amdgcn_mfma_f32_16x16x32_bf16(af1, sb1, acc2[nt], 0,0,0);
  }
  // ---- GroupNorm + silu(g) directly in MFMA C/D layout ----
  #pragma unroll
  for (int r=0;r<4;++r){
    int il = irow + r;                    // row within chunk [0,256)
    size_t roff = base + (size_t)il*C_;
    float w = wpow[il];
    float val[4];
    float s=0.f, ss=0.f;
    #pragma unroll
    for (int nt=0;nt<4;++nt){
      float v = acc[nt][r] + w*acc2[nt][r];
      val[nt]=v; s+=v; ss+=v*v;
    }
    #pragma unroll
    for (int o=8;o>0;o>>=1){ s+=__shfl_xor(s,o,64); ss+=__shfl_xor(ss,o,64); }
    float mu = s*(1.f/N_);
    float var = ss*(1.f/N_) - mu*mu;
    float inv = rsqrtf(fmaxf(var,0.f) + 6.4e-4f);   // GN_EPS = 1e-5*64
    #pragma unroll
    for (int nt=0;nt<4;++nt){
      int n = nt*16 + m16, ci = h*N_ + n;
      float gg = bf2f(g[roff + n]);
      float sil = gg/(1.f+expf(-gg));
      out[roff + n] = f2bf(((val[nt]-mu)*inv*bf2f(gnw[ci]) + bf2f(gnb[ci]))*sil);
    }
  }
}

// ---------------- logits for last position: [B,V] = xf @ wte^T (raw dtype) ----------------
__global__ __launch_bounds__(256) void logits_kernel(const float* __restrict__ xf,
    const void* __restrict__ wteR, void* __restrict__ out, const int* __restrict__ flag){
  const int wid = threadIdx.x>>6, lane = threadIdx.x&63;
  const int gw = blockIdx.x*4 + wid;     // 0 .. B*V-1
  const int b = gw / V_, v = gw - b*V_;
  const float* xr = xf + b*C_;
  float s = 0.f;
  if (*flag){
    const float* wrow = (const float*)wteR + (size_t)v*C_;
    float4 w0 = ((const float4*)wrow)[lane*2];
    float4 w1 = ((const float4*)wrow)[lane*2+1];
    const float* xp = xr + lane*8;
    s = w0.x*xp[0] + w0.y*xp[1] + w0.z*xp[2] + w0.w*xp[3]
      + w1.x*xp[4] + w1.y*xp[5] + w1.z*xp[6] + w1.w*xp[7];
  } else {
    const u16* wrow = (const u16*)wteR + (size_t)v*C_;
    union {uint4 q; u16 h[8];} uu;
    uu.q = *(const uint4*)(wrow + lane*8);
    #pragma unroll
    for (int j=0;j<8;j++) s += bf2f(uu.h[j])*xr[lane*8+j];
  }
  #pragma unroll
  for (int o=32;o>0;o>>=1) s += __shfl_down(s,o,64);
  if (lane==0){
    size_t o = (size_t)b*V_ + v;
    if (*flag) ((float*)out)[o] = s;          // fp32 harness
    else       ((u16*)out)[o]   = f2bf(s);    // bf16 harness
  }
}

extern "C" void kernel_launch(void* const* d_in, const int* in_sizes, int n_in,
                              void* d_out, int out_size, void* d_ws, size_t ws_size,
                              hipStream_t stream){
  (void)out_size; (void)ws_size; (void)n_in;
  const int* idx  = (const int*)d_in[0];

  char* ws = (char*)d_ws;
  const size_t MC  = (size_t)M_*C_;
  // ---- workspace layout (bytes) ----
  size_t o = 0;
  int* flag = (int*)(ws + o);            o += 1024;
  const u16** ptab = (const u16**)(ws + o); o += 1024;
  float* X   = (float*)(ws + o);         o += MC*4;            // fp32 residual
  u16* MK = (u16*)(ws + o);              o += MC*2;            // also YGN
  u16* MV = (u16*)(ws + o);              o += MC*2;
  u16* MR = (u16*)(ws + o);              o += MC*2;            // also S (tmix) / RRb (cmix)
  u16* MG = (u16*)(ws + o);              o += MC*2;
  u16* Rb = (u16*)(ws + o);              o += MC*2;            // H1 spans Rb..Vb
  u16* Kb = (u16*)(ws + o);              o += MC*2;
  u16* Vb = (u16*)(ws + o);              o += MC*2;
  u16* Gb = (u16*)(ws + o);              o += MC*2;
  u16* Kt = (u16*)(ws + o);              o += MC*2;            // scaled k^T per (b,h): [BH*64, T]
  u16* Vt = (u16*)(ws + o);              o += MC*2;            // v^T per (b,h): [BH*64, T]
  float* XF = (float*)(ws + o);          o += 65536;
  u16* pool = (u16*)(ws + o);            // fp32->bf16 converted inputs 3..23
  u16* YGN = MK;
  float* S  = (float*)MR;    // live only during tmix phase (4 MB < 8.4 MB)
  u16* H1 = Rb;              // [M,3C] bf16, spans Rb..Vb
  u16* RRb = MR;             // [M,C] bf16 sigmoid gate (cmix phase)

  // ---- dtype detect + pointer table + (conditional) conversion of tensors 3..23 ----
  detect_kernel<<<1,256,0,stream>>>(d_in[12], flag);   // probe Wr
  CvtTab tab; PtrTab pt;
  int nblocks;
  {
    size_t poff = 0; int acc8 = 0, bacc = 0;
    long long total8 = 0;
    for (int i=3;i<24;i++) total8 += (long long)(in_sizes[i] >> 3);
    pt.raw[0] = d_in[1]; pt.off[0] = 0;   // wte: raw only (never used via ptab)
    pt.raw[1] = d_in[2]; pt.off[1] = 0;   // wpe: raw only (never used via ptab)
    for (int i=3;i<24;i++){
      int j = i-3;
      pt.raw[i-1] = d_in[i];
      pt.off[i-1] = (long long)poff;
      poff += (size_t)in_sizes[i];
      tab.s[j] = d_in[i];
      tab.off8[j] = acc8;
      tab.bstart[j] = bacc;
      int n8 = in_sizes[i] >> 3;
      int nb = (int)(((long long)n8 * 2048 + total8 - 1) / total8);
      if (nb < 1) nb = 1;
      acc8 += n8; bacc += nb;
    }
    tab.off8[21] = acc8; tab.bstart[21] = bacc;
    nblocks = bacc;
  }
  fill_ptab<<<1,64,0,stream>>>(pt, pool, flag, ptab);
  convert_all<<<nblocks,256,0,stream>>>(tab, pool, flag);

  embed_kernel<<<M_,256,0,stream>>>(idx, d_in[1], d_in[2], flag, X);
  dim3 g4 (M_/128, C_/64, 4);      // (64,8,4) fused projections, 128x64
  dim3 gkv(T_/64, B_*H_, 2);       // K/V transpose
  dim3 gck(M_/128, 32);            // 24 ck tiles + 8 cr tiles, 128x64
  dim3 gwo(M_/128, C_/64);         // (64,8) 128x64
  for (int l=0;l<L_;++l){
    // ---- time mix ----
    ln_tmix_kernel<<<M_,256,0,stream>>>(X, ptab, l, MK,MV,MR,MG);
    gemm4_mfma<<<g4,256,0,stream>>>(ptab, l, MK, Rb, Kb, Vb, Gb);
    kvtrans<<<gkv,256,0,stream>>>(Kb, Vb, Kt, Vt, ptab, l);
    wkv_state_mfma<<<dim3(NC_, B_*H_),256,0,stream>>>(Kt, Vt, S);
    wkv_prefix<<<B_*H_,256,0,stream>>>(S, ptab, l);
    wkv_fused<<<dim3(NC_*4, B_*H_),256,0,stream>>>(Rb, Kb, Vt, S, ptab, l, Gb, YGN);
    gemm_wo<<<gwo,256,0,stream>>>(ptab, l, YGN, X);
    // ---- channel mix ----
    ln_cmix_kernel<<<M_,256,0,stream>>>(X, ptab, l, MK, MV);
    gemm_ck_cr<<<gck,256,0,stream>>>(ptab, l, MK, H1, MV, RRb);
    gemm_cmix<<<gwo,256,0,stream>>>(ptab, l, H1, X, RRb);
  }
  lnf_last<<<B_,256,0,stream>>>(X, ptab, XF);
  logits_kernel<<<(B_*V_)/4,256,0,stream>>>(XF, d_in[1], d_out, flag);
}

// Round 10
// 1442.199 us; speedup vs baseline: 1.1867x; 1.0393x over previous
//
#include <hip/hip_runtime.h>

#define L_ 6
#define H_ 8
#define C_ 512
#define V_ 32000
#define B_ 2
#define T_ 4096
#define Q_ 256
#define N_ 64
#define NC_ 16
#define M_ 8192   // B*T

typedef unsigned short u16;
typedef __attribute__((ext_vector_type(8))) short bf16x8;
typedef __attribute__((ext_vector_type(4))) float f32x4;

__device__ __forceinline__ float bf2f(u16 u){
  return __uint_as_float(((unsigned int)u) << 16);
}
__device__ __forceinline__ u16 f2bf(float f){
  unsigned int x = __float_as_uint(f);
  return (u16)((x + 0x7fffu + ((x >> 16) & 1u)) >> 16);
}

__device__ __forceinline__ void gl_lds16(const u16* g, u16* l){
  __builtin_amdgcn_global_load_lds((const __attribute__((address_space(1))) void*)g,
                                   (__attribute__((address_space(3))) void*)l, 16, 0, 0);
}

// ---------------- dtype detection: bf16 weights never have |x|>=2 ----------------
__global__ __launch_bounds__(256) void detect_kernel(const void* __restrict__ probe,
                                                     int* __restrict__ flag){
  __shared__ int cnt;
  if (threadIdx.x == 0) cnt = 0;
  __syncthreads();
  const u16* p = (const u16*)probe;
  int c = 0;
  for (int i = threadIdx.x; i < 2048; i += 256){
    int e = (p[i] >> 7) & 0xFF;
    if (e >= 128) c++;
  }
  atomicAdd(&cnt, c);
  __syncthreads();
  if (threadIdx.x == 0) *flag = (cnt > 32) ? 1 : 0;  // 1 = inputs are fp32
}

// ---------------- pointer table: bf16 -> use raw inputs in place; fp32 -> converted pool ----------------
struct PtrTab { const void* raw[23]; long long off[23]; };

__global__ __launch_bounds__(64) void fill_ptab(PtrTab pt, const u16* __restrict__ pool,
    const int* __restrict__ flag, const u16** __restrict__ ptab){
  int i = threadIdx.x;
  if (i < 23)
    ptab[i+1] = (*flag) ? (pool + pt.off[i]) : (const u16*)pt.raw[i];
}

// ---------------- fp32 -> bf16 conversion, tensors 3..23 only (wte/wpe stay raw) ----------------
struct CvtTab { const void* s[21]; int off8[22]; int bstart[22]; };

__global__ __launch_bounds__(256) void convert_all(CvtTab t, u16* __restrict__ pool,
                                                   const int* __restrict__ flag){
  if (!*flag) return;    // bf16 inputs are consumed in place via ptab
  int i = 0;
  #pragma unroll
  for (int k = 1; k < 21; k++) if ((int)blockIdx.x >= t.bstart[k]) i = k;
  const void* sp = t.s[0];
  #pragma unroll
  for (int k = 1; k < 21; k++) if (i == k) sp = t.s[k];
  const int n8 = t.off8[i+1] - t.off8[i];
  const int nb = t.bstart[i+1] - t.bstart[i];
  const int lb = (int)blockIdx.x - t.bstart[i];
  uint4* dp = (uint4*)pool + t.off8[i];
  const int stride = nb * 256;
  const float4* sf = (const float4*)sp;
  for (int j = lb*256 + (int)threadIdx.x; j < n8; j += stride){
    float4 a0 = sf[2*j], a1 = sf[2*j+1];
    uint4 r0;
    r0.x = (unsigned)f2bf(a0.x) | ((unsigned)f2bf(a0.y) << 16);
    r0.y = (unsigned)f2bf(a0.z) | ((unsigned)f2bf(a0.w) << 16);
    r0.z = (unsigned)f2bf(a1.x) | ((unsigned)f2bf(a1.y) << 16);
    r0.w = (unsigned)f2bf(a1.z) | ((unsigned)f2bf(a1.w) << 16);
    dp[j] = r0;
  }
}

// ---------------- embedding: x = wte[idx] + wpe (reads raw dtype directly) ----------------
__global__ __launch_bounds__(256) void embed_kernel(const int* __restrict__ idx,
    const void* __restrict__ wteR, const void* __restrict__ wpeR,
    const int* __restrict__ flag, float* __restrict__ x){
  int row = blockIdx.x;                 // b*T + t
  int t = row & (T_-1);
  int tok = idx[row];
  float* xo = x + (size_t)row * C_;
  int c = threadIdx.x;
  float a0,a1,b0,b1;
  if (*flag){
    const float* we = (const float*)wteR + (size_t)tok * C_;
    const float* wp = (const float*)wpeR + (size_t)t * C_;
    a0 = we[c]; a1 = we[c+256]; b0 = wp[c]; b1 = wp[c+256];
  } else {
    const u16* we = (const u16*)wteR + (size_t)tok * C_;
    const u16* wp = (const u16*)wpeR + (size_t)t * C_;
    a0 = bf2f(we[c]); a1 = bf2f(we[c+256]); b0 = bf2f(wp[c]); b1 = bf2f(wp[c+256]);
  }
  xo[c]     = a0 + b0;
  xo[c+256] = a1 + b1;
}

// ---------------- fused LN + time-mix token shift (recomputes LN of row t-1) ----------------
__global__ __launch_bounds__(256) void ln_tmix_kernel(const float* __restrict__ x,
    const u16* const* __restrict__ ptab, int l,
    u16* __restrict__ xk, u16* __restrict__ xv, u16* __restrict__ xr, u16* __restrict__ xg){
  const u16* w  = ptab[3] + l*C_;
  const u16* mk = ptab[6] + l*C_;
  const u16* mv = ptab[7] + l*C_;
  const u16* mr = ptab[8] + l*C_;
  const u16* mg = ptab[9] + l*C_;
  int row = blockIdx.x; int t = row & (T_-1);
  size_t off = (size_t)row*C_;
  const float* cur = x + off;
  int c = threadIdx.x;
  float v0 = cur[c], v1 = cur[c+256];
  float p0 = 0.f, p1 = 0.f;
  if (t){ p0 = cur[c - C_]; p1 = cur[c+256 - C_]; }
  float s = v0+v1, ss = v0*v0+v1*v1;
  float sp = p0+p1, ssp = p0*p0+p1*p1;
  int lane = c & 63, wid = c >> 6;
  #pragma unroll
  for (int o=32;o>0;o>>=1){
    s  += __shfl_down(s,o,64);  ss  += __shfl_down(ss,o,64);
    sp += __shfl_down(sp,o,64); ssp += __shfl_down(ssp,o,64);
  }
  __shared__ float r1[4], r2[4], r3[4], r4[4];
  if (lane==0){ r1[wid]=s; r2[wid]=ss; r3[wid]=sp; r4[wid]=ssp; }
  __syncthreads();
  if (c==0){
    float a =r1[0]+r1[1]+r1[2]+r1[3], bq=r2[0]+r2[1]+r2[2]+r2[3];
    float ap=r3[0]+r3[1]+r3[2]+r3[3], bp=r4[0]+r4[1]+r4[2]+r4[3];
    float mu  = a *(1.f/C_); float var  = bq*(1.f/C_) - mu*mu;
    float mup = ap*(1.f/C_); float varp = bp*(1.f/C_) - mup*mup;
    r1[0]=mu;  r2[0]=rsqrtf(fmaxf(var ,0.f)+1e-5f);
    r3[0]=mup; r4[0]=rsqrtf(fmaxf(varp,0.f)+1e-5f);
  }
  __syncthreads();
  float mu=r1[0], inv=r2[0], mup=r3[0], invp=r4[0];
  #pragma unroll
  for (int p=0;p<2;p++){
    int cc = c + p*256;
    float wc = bf2f(w[cc]);
    float xc = ((p?v1:v0)-mu)*inv*wc;
    float xp = t ? ((p?p1:p0)-mup)*invp*wc : 0.f;
    float xx = xp - xc;
    xk[off+cc] = f2bf(xc + xx*bf2f(mk[cc]));
    xv[off+cc] = f2bf(xc + xx*bf2f(mv[cc]));
    xr[off+cc] = f2bf(xc + xx*bf2f(mr[cc]));
    xg[off+cc] = f2bf(xc + xx*bf2f(mg[cc]));
  }
}

// ---------------- fused LN + channel-mix token shift ----------------
__global__ __launch_bounds__(256) void ln_cmix_kernel(const float* __restrict__ x,
    const u16* const* __restrict__ ptab, int l,
    u16* __restrict__ xk, u16* __restrict__ xr){
  const u16* w  = ptab[4]  + l*C_;
  const u16* mk = ptab[19] + l*C_;
  const u16* mr = ptab[20] + l*C_;
  int row = blockIdx.x; int t = row & (T_-1);
  size_t off = (size_t)row*C_;
  const float* cur = x + off;
  int c = threadIdx.x;
  float v0 = cur[c], v1 = cur[c+256];
  float p0 = 0.f, p1 = 0.f;
  if (t){ p0 = cur[c - C_]; p1 = cur[c+256 - C_]; }
  float s = v0+v1, ss = v0*v0+v1*v1;
  float sp = p0+p1, ssp = p0*p0+p1*p1;
  int lane = c & 63, wid = c >> 6;
  #pragma unroll
  for (int o=32;o>0;o>>=1){
    s  += __shfl_down(s,o,64);  ss  += __shfl_down(ss,o,64);
    sp += __shfl_down(sp,o,64); ssp += __shfl_down(ssp,o,64);
  }
  __shared__ float r1[4], r2[4], r3[4], r4[4];
  if (lane==0){ r1[wid]=s; r2[wid]=ss; r3[wid]=sp; r4[wid]=ssp; }
  __syncthreads();
  if (c==0){
    float a =r1[0]+r1[1]+r1[2]+r1[3], bq=r2[0]+r2[1]+r2[2]+r2[3];
    float ap=r3[0]+r3[1]+r3[2]+r3[3], bp=r4[0]+r4[1]+r4[2]+r4[3];
    float mu  = a *(1.f/C_); float var  = bq*(1.f/C_) - mu*mu;
    float mup = ap*(1.f/C_); float varp = bp*(1.f/C_) - mup*mup;
    r1[0]=mu;  r2[0]=rsqrtf(fmaxf(var ,0.f)+1e-5f);
    r3[0]=mup; r4[0]=rsqrtf(fmaxf(varp,0.f)+1e-5f);
  }
  __syncthreads();
  float mu=r1[0], inv=r2[0], mup=r3[0], invp=r4[0];
  #pragma unroll
  for (int p=0;p<2;p++){
    int cc = c + p*256;
    float wc = bf2f(w[cc]);
    float xc = ((p?v1:v0)-mu)*inv*wc;
    float xp = t ? ((p?p1:p0)-mup)*invp*wc : 0.f;
    float xx = xp - xc;
    xk[off+cc] = f2bf(xc + xx*bf2f(mk[cc]));
    xr[off+cc] = f2bf(xc + xx*bf2f(mr[cc]));
  }
}

// ---------------- final LN for last position only ----------------
__global__ __launch_bounds__(256) void lnf_last(const float* __restrict__ x,
    const u16* const* __restrict__ ptab, float* __restrict__ xf){
  const u16* w = ptab[5];
  int b = blockIdx.x;
  const float* xr = x + ((size_t)b*T_ + (T_-1))*C_;
  int c = threadIdx.x;
  float v0 = xr[c], v1 = xr[c+256];
  float s = v0+v1, ss = v0*v0+v1*v1;
  int lane = c & 63, wid = c >> 6;
  #pragma unroll
  for (int o=32;o>0;o>>=1){ s += __shfl_down(s,o,64); ss += __shfl_down(ss,o,64); }
  __shared__ float r1[4], r2[4];
  if (lane==0){ r1[wid]=s; r2[wid]=ss; }
  __syncthreads();
  if (c==0){
    float a=r1[0]+r1[1]+r1[2]+r1[3], bq=r2[0]+r2[1]+r2[2]+r2[3];
    float mu = a*(1.f/C_);
    float var = bq*(1.f/C_) - mu*mu;
    r1[0]=mu; r2[0]=rsqrtf(fmaxf(var,0.f)+1e-5f);
  }
  __syncthreads();
  float mu=r1[0], inv=r2[0];
  xf[b*C_+c]     = (v0-mu)*inv*bf2f(w[c]);
  xf[b*C_+c+256] = (v1-mu)*inv*bf2f(w[c+256]);
}

// ================= MFMA GEMM: 128(M) x 64(N), BK=64, 24KB LDS =================
#define ACT_RELU2_BF16 1
#define ACT_ADD_F32 2
#define ACT_BF16 3
#define ACT_CMIX 4      // Yf += v * bf2f(AuxB) (AuxB holds sigmoid gate)
#define ACT_SIG_BF16 7  // Yb = bf16(sigmoid(v))

template<int ACT>
__device__ __forceinline__ void gemm_mfma_body(u16* __restrict__ Al, u16* __restrict__ Bl,
    const u16* __restrict__ X, const u16* __restrict__ W,
    float* __restrict__ Yf, u16* __restrict__ Yb, const u16* __restrict__ AuxB,
    int Ndim, int Kdim, int bm, int bn){
  const int tid = threadIdx.x;
  const int wv = tid >> 6, ln = tid & 63;
  const int m16 = ln & 15, q = ln >> 4;

  f32x4 acc[2][4];
  #pragma unroll
  for (int i=0;i<2;i++)
    #pragma unroll
    for (int j=0;j<4;j++) acc[i][j] = f32x4{0.f,0.f,0.f,0.f};

  const int r0 = wv*8 + (ln >> 3);
  const int c0 = (ln & 7)*8;
  const u16* ga = X + (size_t)(bm + r0)*Kdim + c0;
  const u16* gb = W + (size_t)(bn + r0)*Kdim + c0;
  u16* la = Al + r0*64 + c0;
  u16* lb = Bl + r0*64 + c0;

  for (int k0=0; k0<Kdim; k0+=64){
    #pragma unroll
    for (int s=0;s<4;s++)
      gl_lds16(ga + (size_t)(s*32)*Kdim + k0, la + s*2048);
    #pragma unroll
    for (int s=0;s<2;s++)
      gl_lds16(gb + (size_t)(s*32)*Kdim + k0, lb + s*2048);
    __syncthreads();
    #pragma unroll
    for (int kh=0; kh<2; kh++){
      bf16x8 af[2], bfr[4];
      #pragma unroll
      for (int i=0;i<2;i++) af[i]  = *(const bf16x8*)(Al + (wv*32 + i*16 + m16)*64 + kh*32 + q*8);
      #pragma unroll
      for (int j=0;j<4;j++) bfr[j] = *(const bf16x8*)(Bl + (j*16 + m16)*64 + kh*32 + q*8);
      #pragma unroll
      for (int i=0;i<2;i++)
        #pragma unroll
        for (int j=0;j<4;j++)
          acc[i][j] = __builtin_amdgcn_mfma_f32_16x16x32_bf16(af[i], bfr[j], acc[i][j], 0, 0, 0);
    }
    __syncthreads();
  }

  // epilogue: C/D layout col=lane&15, row=quad*4+reg
  #pragma unroll
  for (int i=0;i<2;i++){
    int row = bm + wv*32 + i*16 + q*4;
    #pragma unroll
    for (int j=0;j<4;j++){
      int col = bn + j*16 + m16;
      #pragma unroll
      for (int r=0;r<4;r++){
        size_t off = (size_t)(row + r)*Ndim + col;
        float v = acc[i][j][r];
        if (ACT==ACT_ADD_F32) Yf[off] += v;
        else if (ACT==ACT_CMIX){ Yf[off] += v * bf2f(AuxB[off]); }
        else if (ACT==ACT_BF16) Yb[off] = f2bf(v);
        else if (ACT==ACT_RELU2_BF16){ float rr = v>0.f ? v : 0.f; Yb[off] = f2bf(rr*rr); }
        else if (ACT==ACT_SIG_BF16) Yb[off] = f2bf(1.f/(1.f+expf(-v)));
      }
    }
  }
}

#define GEMM_SH __shared__ __align__(16) u16 SH[128*64 + 64*64]

// fused r/k/v/g projections, 128x64 tiles, grid (64,8,4)
__global__ __launch_bounds__(256,4) void gemm4_mfma(const u16* const* __restrict__ ptab, int l,
    const u16* __restrict__ Abase,
    u16* __restrict__ Rb, u16* __restrict__ Kb, u16* __restrict__ Vb, u16* __restrict__ Gb){
  GEMM_SH;
  const size_t MC = (size_t)M_*C_;
  const size_t ws = (size_t)l*C_*C_;
  const int bm = blockIdx.x*128, bn = blockIdx.y*64;
  switch (blockIdx.z){
    case 0:  gemm_mfma_body<ACT_BF16>(SH, SH+128*64, Abase + 2*MC, ptab[12]+ws, nullptr, Rb, nullptr, C_, C_, bm, bn); break;
    case 1:  gemm_mfma_body<ACT_BF16>(SH, SH+128*64, Abase,        ptab[13]+ws, nullptr, Kb, nullptr, C_, C_, bm, bn); break;
    case 2:  gemm_mfma_body<ACT_BF16>(SH, SH+128*64, Abase + 1*MC, ptab[14]+ws, nullptr, Vb, nullptr, C_, C_, bm, bn); break;
    default: gemm_mfma_body<ACT_BF16>(SH, SH+128*64, Abase + 3*MC, ptab[15]+ws, nullptr, Gb, nullptr, C_, C_, bm, bn); break;
  }
}

// fused cmix key (relu^2 -> H1) + receptance gate (sigmoid -> RRb), 128x64, grid (64,32)
__global__ __launch_bounds__(256,4) void gemm_ck_cr(const u16* const* __restrict__ ptab, int l,
    const u16* __restrict__ MK, u16* __restrict__ H1,
    const u16* __restrict__ MV, u16* __restrict__ RRb){
  GEMM_SH;
  if (blockIdx.y < 24)
    gemm_mfma_body<ACT_RELU2_BF16>(SH, SH+128*64, MK, ptab[21]+(size_t)l*3*C_*C_, nullptr, H1, nullptr,
                                   3*C_, C_, blockIdx.x*128, blockIdx.y*64);
  else
    gemm_mfma_body<ACT_SIG_BF16>(SH, SH+128*64, MV, ptab[23]+(size_t)l*C_*C_, nullptr, RRb, nullptr,
                                 C_, C_, blockIdx.x*128, (blockIdx.y-24)*64);
}

// output projection with residual add: X += YGN @ Wo^T   (grid 64x8)
__global__ __launch_bounds__(256,4) void gemm_wo(const u16* const* __restrict__ ptab, int l,
    const u16* __restrict__ YGN, float* __restrict__ X){
  GEMM_SH;
  gemm_mfma_body<ACT_ADD_F32>(SH, SH+128*64, YGN, ptab[16]+(size_t)l*C_*C_, X, nullptr, nullptr,
                              C_, C_, blockIdx.x*128, blockIdx.y*64);
}

// cmix value GEMM with fused tail: X += gate * (H1 @ Wcv^T)   (grid 64x8)
__global__ __launch_bounds__(256,4) void gemm_cmix(const u16* const* __restrict__ ptab, int l,
    const u16* __restrict__ H1, float* __restrict__ X, const u16* __restrict__ RRb){
  GEMM_SH;
  gemm_mfma_body<ACT_CMIX>(SH, SH+128*64, H1, ptab[22]+(size_t)l*3*C_*C_, X, nullptr, RRb,
                           C_, 3*C_, blockIdx.x*128, blockIdx.y*64);
}

// ---------------- K/V per-(b,h) transpose; K gets wdec^(Q-1-tloc) scale ----------------
// grid (T/64, B*H, 2): z=0 V->Vt plain, z=1 K->Kt scaled
__global__ __launch_bounds__(256) void kvtrans(const u16* __restrict__ Kb, const u16* __restrict__ Vb,
    u16* __restrict__ Kt, u16* __restrict__ Vt, const u16* const* __restrict__ ptab, int l){
  __shared__ __align__(16) u16 tile[64*64];
  const int t0 = blockIdx.x*64, bh = blockIdx.y, b = bh>>3, h = bh&7;
  const bool isK = (blockIdx.z == 1);
  const u16* src = isK ? Kb : Vb;
  u16* dst = isK ? Kt : Vt;
  float l2w = 0.f;
  if (isK){
    const u16* td = ptab[10] + l*H_;
    l2w = -expf(bf2f(td[h])) * 1.44269504f;
  }
  const int tid = threadIdx.x;
  #pragma unroll
  for (int it=0; it<2; ++it){
    int tl = it*32 + (tid>>3);
    int n0 = (tid&7)*8;
    union {uint4 q; u16 e[8];} v;
    v.q = *(const uint4*)(src + ((size_t)(b*T_ + t0 + tl))*C_ + h*N_ + n0);
    if (isK){
      int tloc = (t0 + tl) & (Q_-1);
      float sc = exp2f(l2w * (float)(Q_-1 - tloc));
      #pragma unroll
      for (int e=0;e<8;++e) v.e[e] = f2bf(bf2f(v.e[e])*sc);
    }
    int col = n0 ^ (((tl>>3)&7)<<3);
    *(uint4*)&tile[tl*64 + col] = v.q;
  }
  __syncthreads();
  #pragma unroll
  for (int it=0; it<2; ++it){
    int nl = it*32 + (tid>>3);
    int t0l = (tid&7)*8;
    int swz = (tid&7)<<3;
    union {uint4 q; u16 h2[8];} pk;
    #pragma unroll
    for (int e=0;e<8;++e)
      pk.h2[e] = tile[(t0l+e)*64 + (nl ^ swz)];
    *(uint4*)(dst + ((size_t)(bh*N_ + nl))*T_ + t0 + t0l) = pk.q;
  }
}

// ---------------- per-chunk state, stored TRANSPOSED: St[v_feat][k_feat] ----------------
__global__ __launch_bounds__(256) void wkv_state_mfma(const u16* __restrict__ Kt,
    const u16* __restrict__ Vt, float* __restrict__ S){
  const int c = blockIdx.x, bh = blockIdx.y;
  const int tid = threadIdx.x, wv = tid >> 6, ln = tid & 63;
  const int m16 = ln & 15, q = ln >> 4;
  const u16* ka = Kt + (size_t)(bh*N_ + wv*16 + m16)*T_ + c*Q_;
  const u16* vb = Vt + (size_t)(bh*N_ + m16)*T_ + c*Q_;
  f32x4 acc[4];
  #pragma unroll
  for (int nt=0;nt<4;++nt) acc[nt] = f32x4{0.f,0.f,0.f,0.f};
  #pragma unroll
  for (int ks=0; ks<8; ++ks){
    bf16x8 af = *(const bf16x8*)(ka + ks*32 + q*8);
    #pragma unroll
    for (int nt=0;nt<4;++nt){
      bf16x8 bv = *(const bf16x8*)(vb + (size_t)(nt*16)*T_ + ks*32 + q*8);
      acc[nt] = __builtin_amdgcn_mfma_f32_16x16x32_bf16(af, bv, acc[nt], 0,0,0);
    }
  }
  float* Sp = S + ((size_t)bh*NC_ + c)*(N_*N_);
  // MFMA out: k_feat row = wv*16+q*4+r, v_feat col = nt*16+m16. Store transposed.
  #pragma unroll
  for (int nt=0;nt<4;++nt)
    #pragma unroll
    for (int r=0;r<4;++r)
      Sp[(nt*16 + m16)*N_ + (wv*16 + q*4 + r)] = acc[nt][r];
}

// ---------------- sequential prefix over chunks -> bf16 St output ----------------
// Sb16[cc] = bf16( sum_{j<cc} wsd^(cc-1-j) * S_j )  (exclusive prefix, f32 Horner)
__global__ __launch_bounds__(256) void wkv_prefix(const float* __restrict__ S,
    u16* __restrict__ Sb16, const u16* const* __restrict__ ptab, int l){
  const int bh = blockIdx.x, h = bh&7;
  const u16* td = ptab[10] + l*H_;
  const float l2w = -expf(bf2f(td[h])) * 1.44269504f;
  const float wsd = exp2f(l2w * (float)Q_);
  const float* Sp = S + (size_t)bh*NC_*N_*N_;
  u16* Sb = Sb16 + (size_t)bh*NC_*N_*N_;
  for (int e=threadIdx.x; e<N_*N_; e+=256){
    float cur = 0.f;
    for (int cc=0;cc<NC_;++cc){
      Sb[(size_t)cc*N_*N_ + e] = f2bf(cur);
      cur = wsd*cur + Sp[(size_t)cc*N_*N_ + e];
    }
  }
}

// ---------------- FUSED WKV: intra (MFMA) + inter (MFMA on bf16 St) + GN + silu(g) ----------------
// acc's in MFMA C/D layout; V prefetched to regs per jt (breaks the lgkmcnt serialization);
// St staged coalesced from bf16; g staged via LDS.
__global__ __launch_bounds__(256) void wkv_fused(const u16* __restrict__ Rb,
    const u16* __restrict__ Kb, const u16* __restrict__ Vt, const u16* __restrict__ Sb16,
    const u16* const* __restrict__ ptab, int l,
    const u16* __restrict__ g, u16* __restrict__ out){
  __shared__ float wpow[Q_];
  __shared__ __align__(16) u16 P[4][16][72];    // 9216 B, wave-private quarters
  __shared__ __align__(16) u16 stl[64][72];     // St bf16: [v_feat n][k_feat k]
  __shared__ __align__(16) u16 gl[64][72];      // g tile: [row-in-strip][n]
  const u16* td  = ptab[10] + l*H_;
  const u16* tf  = ptab[11] + l*H_;
  const u16* gnw = ptab[17] + l*C_;
  const u16* gnb = ptab[18] + l*C_;
  const int c = blockIdx.x>>2, ip = blockIdx.x&3;
  const int bh = blockIdx.y, b = bh>>3, h = bh&7;
  const int tid = threadIdx.x, wv = tid >> 6, ln = tid & 63;
  const int m16 = ln & 15, q = ln >> 4;
  const float l2w = -expf(bf2f(td[h])) * 1.44269504f;
  const float uu = bf2f(tf[h]);
  wpow[tid] = exp2f(l2w * (float)tid);
  const size_t base = ((size_t)b*T_ + (size_t)c*Q_)*C_ + h*N_;
  const int i0 = ip*64;
  // stage bf16 St (coalesced uint4) and g tile
  {
    const u16* Sp = Sb16 + ((size_t)bh*NC_ + c)*(N_*N_);
    #pragma unroll
    for (int k2=0;k2<2;++k2){
      int e = (tid + k2*256)*8;       // e = n*64 + k
      *(uint4*)&stl[e>>6][e&63] = *(const uint4*)(Sp + e);
    }
    #pragma unroll
    for (int it=0; it<2; ++it){
      int rr2 = it*32 + (tid>>3);
      int n0 = (tid&7)*8;
      *(uint4*)&gl[rr2][n0] = *(const uint4*)(g + base + (size_t)(i0+rr2)*C_ + n0);
    }
  }
  __syncthreads();
  // ---- intra-chunk (MFMA) ----
  const int iw0 = ip*64 + wv*16;
  const u16* rrow = Rb + base + (size_t)(iw0 + m16)*C_;
  bf16x8 af0 = *(const bf16x8*)(rrow + q*8);
  bf16x8 af1 = *(const bf16x8*)(rrow + 32 + q*8);
  f32x4 acc[4];
  #pragma unroll
  for (int nt=0;nt<4;++nt) acc[nt] = f32x4{0.f,0.f,0.f,0.f};
  const int irow = iw0 + q*4;
  const u16* vtb = Vt + (size_t)(bh*N_)*T_ + (size_t)c*Q_;
  for (int jt=0; jt<=ip; ++jt){
    // prefetch V fragments for this jt BEFORE the P-store barrier (independent loads)
    bf16x8 vfr[2][4];
    #pragma unroll
    for (int kp=0;kp<2;++kp)
      #pragma unroll
      for (int nt=0;nt<4;++nt)
        vfr[kp][nt] = *(const bf16x8*)(vtb + (size_t)(nt*16 + m16)*T_ + jt*64 + kp*32 + q*8);
    f32x4 s[4];
    #pragma unroll
    for (int j2=0;j2<4;++j2) s[j2] = f32x4{0.f,0.f,0.f,0.f};
    #pragma unroll
    for (int j2=0;j2<4;++j2){
      const u16* kr = Kb + base + (size_t)(jt*64 + j2*16 + m16)*C_;
      bf16x8 b0 = *(const bf16x8*)(kr + q*8);
      bf16x8 b1 = *(const bf16x8*)(kr + 32 + q*8);
      s[j2] = __builtin_amdgcn_mfma_f32_16x16x32_bf16(af0, b0, s[j2], 0,0,0);
      s[j2] = __builtin_amdgcn_mfma_f32_16x16x32_bf16(af1, b1, s[j2], 0,0,0);
    }
    #pragma unroll
    for (int j2=0;j2<4;++j2){
      int jc = jt*64 + j2*16 + m16;
      #pragma unroll
      for (int r=0;r<4;++r){
        int ic = irow + r;
        float w = (jc < ic) ? wpow[ic-jc-1] : ((jc==ic) ? uu : 0.f);
        P[wv][q*4+r][j2*16+m16] = f2bf(s[j2][r]*w);
      }
    }
    __asm__ volatile("s_waitcnt lgkmcnt(0)" ::: "memory");
    #pragma unroll
    for (int kp=0;kp<2;++kp){
      bf16x8 ap = *(const bf16x8*)&P[wv][m16][kp*32 + q*8];
      #pragma unroll
      for (int nt=0;nt<4;++nt)
        acc[nt] = __builtin_amdgcn_mfma_f32_16x16x32_bf16(ap, vfr[kp][nt], acc[nt], 0,0,0);
    }
  }
  // ---- inter-chunk via MFMA: y2 = r @ St^T (St rows are output cols) ----
  f32x4 acc2[4];
  #pragma unroll
  for (int nt=0;nt<4;++nt) acc2[nt] = f32x4{0.f,0.f,0.f,0.f};
  #pragma unroll
  for (int nt=0;nt<4;++nt){
    bf16x8 sb0 = *(const bf16x8*)&stl[nt*16 + m16][q*8];
    bf16x8 sb1 = *(const bf16x8*)&stl[nt*16 + m16][32 + q*8];
    acc2[nt] = __builtin_amdgcn_mfma_f32_16x16x32_bf16(af0, sb0, acc2[nt], 0,0,0);
    acc2[nt] = __builtin_amdgcn_mfma_f32_16x16x32_bf16(af1, sb1, acc2[nt], 0,0,0);
  }
  // ---- GroupNorm + silu(g) directly in MFMA C/D layout ----
  #pragma unroll
  for (int r=0;r<4;++r){
    int il = irow + r;                    // row within chunk [0,256)
    int rs = il - i0;                     // row within 64-row strip
    size_t roff = base + (size_t)il*C_;
    float w = wpow[il];
    float val[4];
    float s=0.f, ss=0.f;
    #pragma unroll
    for (int nt=0;nt<4;++nt){
      float v = acc[nt][r] + w*acc2[nt][r];
      val[nt]=v; s+=v; ss+=v*v;
    }
    #pragma unroll
    for (int o=8;o>0;o>>=1){ s+=__shfl_xor(s,o,64); ss+=__shfl_xor(ss,o,64); }
    float mu = s*(1.f/N_);
    float var = ss*(1.f/N_) - mu*mu;
    float inv = rsqrtf(fmaxf(var,0.f) + 6.4e-4f);   // GN_EPS = 1e-5*64
    #pragma unroll
    for (int nt=0;nt<4;++nt){
      int n = nt*16 + m16, ci = h*N_ + n;
      float gg = bf2f(gl[rs][n]);
      float sil = gg/(1.f+expf(-gg));
      out[roff + n] = f2bf(((val[nt]-mu)*inv*bf2f(gnw[ci]) + bf2f(gnb[ci]))*sil);
    }
  }
}

// ---------------- logits for last position: [B,V] = xf @ wte^T (raw dtype) ----------------
__global__ __launch_bounds__(256) void logits_kernel(const float* __restrict__ xf,
    const void* __restrict__ wteR, void* __restrict__ out, const int* __restrict__ flag){
  const int wid = threadIdx.x>>6, lane = threadIdx.x&63;
  const int gw = blockIdx.x*4 + wid;     // 0 .. B*V-1
  const int b = gw / V_, v = gw - b*V_;
  const float* xr = xf + b*C_;
  float s = 0.f;
  if (*flag){
    const float* wrow = (const float*)wteR + (size_t)v*C_;
    float4 w0 = ((const float4*)wrow)[lane*2];
    float4 w1 = ((const float4*)wrow)[lane*2+1];
    const float* xp = xr + lane*8;
    s = w0.x*xp[0] + w0.y*xp[1] + w0.z*xp[2] + w0.w*xp[3]
      + w1.x*xp[4] + w1.y*xp[5] + w1.z*xp[6] + w1.w*xp[7];
  } else {
    const u16* wrow = (const u16*)wteR + (size_t)v*C_;
    union {uint4 q; u16 h[8];} uu;
    uu.q = *(const uint4*)(wrow + lane*8);
    #pragma unroll
    for (int j=0;j<8;j++) s += bf2f(uu.h[j])*xr[lane*8+j];
  }
  #pragma unroll
  for (int o=32;o>0;o>>=1) s += __shfl_down(s,o,64);
  if (lane==0){
    size_t o = (size_t)b*V_ + v;
    if (*flag) ((float*)out)[o] = s;          // fp32 harness
    else       ((u16*)out)[o]   = f2bf(s);    // bf16 harness
  }
}

extern "C" void kernel_launch(void* const* d_in, const int* in_sizes, int n_in,
                              void* d_out, int out_size, void* d_ws, size_t ws_size,
                              hipStream_t stream){
  (void)out_size; (void)ws_size; (void)n_in;
  const int* idx  = (const int*)d_in[0];

  char* ws = (char*)d_ws;
  const size_t MC  = (size_t)M_*C_;
  // ---- workspace layout (bytes) ----
  size_t o = 0;
  int* flag = (int*)(ws + o);            o += 1024;
  const u16** ptab = (const u16**)(ws + o); o += 1024;
  float* X   = (float*)(ws + o);         o += MC*4;            // fp32 residual
  u16* MK = (u16*)(ws + o);              o += MC*2;            // also YGN
  u16* MV = (u16*)(ws + o);              o += MC*2;
  u16* MR = (u16*)(ws + o);              o += MC*2;            // also S (tmix) / RRb (cmix)
  u16* MG = (u16*)(ws + o);              o += MC*2;            // also Sb16 (after gemm4)
  u16* Rb = (u16*)(ws + o);              o += MC*2;            // H1 spans Rb..Vb
  u16* Kb = (u16*)(ws + o);              o += MC*2;
  u16* Vb = (u16*)(ws + o);              o += MC*2;
  u16* Gb = (u16*)(ws + o);              o += MC*2;
  u16* Kt = (u16*)(ws + o);              o += MC*2;            // scaled k^T per (b,h): [BH*64, T]
  u16* Vt = (u16*)(ws + o);              o += MC*2;            // v^T per (b,h): [BH*64, T]
  float* XF = (float*)(ws + o);          o += 65536;
  u16* pool = (u16*)(ws + o);            // fp32->bf16 converted inputs 3..23
  u16* YGN = MK;
  float* S  = (float*)MR;    // f32 per-chunk states (live only during tmix phase)
  u16* Sb16 = MG;            // bf16 exclusive-prefix states (2 MB; MG free after gemm4)
  u16* H1 = Rb;              // [M,3C] bf16, spans Rb..Vb
  u16* RRb = MR;             // [M,C] bf16 sigmoid gate (cmix phase)

  // ---- dtype detect + pointer table + (conditional) conversion of tensors 3..23 ----
  detect_kernel<<<1,256,0,stream>>>(d_in[12], flag);   // probe Wr
  CvtTab tab; PtrTab pt;
  int nblocks;
  {
    size_t poff = 0; int acc8 = 0, bacc = 0;
    long long total8 = 0;
    for (int i=3;i<24;i++) total8 += (long long)(in_sizes[i] >> 3);
    pt.raw[0] = d_in[1]; pt.off[0] = 0;   // wte: raw only (never used via ptab)
    pt.raw[1] = d_in[2]; pt.off[1] = 0;   // wpe: raw only (never used via ptab)
    for (int i=3;i<24;i++){
      int j = i-3;
      pt.raw[i-1] = d_in[i];
      pt.off[i-1] = (long long)poff;
      poff += (size_t)in_sizes[i];
      tab.s[j] = d_in[i];
      tab.off8[j] = acc8;
      tab.bstart[j] = bacc;
      int n8 = in_sizes[i] >> 3;
      int nb = (int)(((long long)n8 * 2048 + total8 - 1) / total8);
      if (nb < 1) nb = 1;
      acc8 += n8; bacc += nb;
    }
    tab.off8[21] = acc8; tab.bstart[21] = bacc;
    nblocks = bacc;
  }
  fill_ptab<<<1,64,0,stream>>>(pt, pool, flag, ptab);
  convert_all<<<nblocks,256,0,stream>>>(tab, pool, flag);

  embed_kernel<<<M_,256,0,stream>>>(idx, d_in[1], d_in[2], flag, X);
  dim3 g4 (M_/128, C_/64, 4);      // (64,8,4) fused projections, 128x64
  dim3 gkv(T_/64, B_*H_, 2);       // K/V transpose
  dim3 gck(M_/128, 32);            // 24 ck tiles + 8 cr tiles, 128x64
  dim3 gwo(M_/128, C_/64);         // (64,8) 128x64
  for (int l=0;l<L_;++l){
    // ---- time mix ----
    ln_tmix_kernel<<<M_,256,0,stream>>>(X, ptab, l, MK,MV,MR,MG);
    gemm4_mfma<<<g4,256,0,stream>>>(ptab, l, MK, Rb, Kb, Vb, Gb);
    kvtrans<<<gkv,256,0,stream>>>(Kb, Vb, Kt, Vt, ptab, l);
    wkv_state_mfma<<<dim3(NC_, B_*H_),256,0,stream>>>(Kt, Vt, S);
    wkv_prefix<<<B_*H_,256,0,stream>>>(S, Sb16, ptab, l);
    wkv_fused<<<dim3(NC_*4, B_*H_),256,0,stream>>>(Rb, Kb, Vt, Sb16, ptab, l, Gb, YGN);
    gemm_wo<<<gwo,256,0,stream>>>(ptab, l, YGN, X);
    // ---- channel mix ----
    ln_cmix_kernel<<<M_,256,0,stream>>>(X, ptab, l, MK, MV);
    gemm_ck_cr<<<gck,256,0,stream>>>(ptab, l, MK, H1, MV, RRb);
    gemm_cmix<<<gwo,256,0,stream>>>(ptab, l, H1, X, RRb);
  }
  lnf_last<<<B_,256,0,stream>>>(X, ptab, XF);
  logits_kernel<<<(B_*V_)/4,256,0,stream>>>(XF, d_in[1], d_out, flag);
}

// Round 11
// 1413.157 us; speedup vs baseline: 1.2111x; 1.0206x over previous
//
#include <hip/hip_runtime.h>

#define L_ 6
#define H_ 8
#define C_ 512
#define V_ 32000
#define B_ 2
#define T_ 4096
#define Q_ 256
#define N_ 64
#define NC_ 16
#define M_ 8192   // B*T

typedef unsigned short u16;
typedef __attribute__((ext_vector_type(8))) short bf16x8;
typedef __attribute__((ext_vector_type(4))) float f32x4;

__device__ __forceinline__ float bf2f(u16 u){
  return __uint_as_float(((unsigned int)u) << 16);
}
__device__ __forceinline__ u16 f2bf(float f){
  unsigned int x = __float_as_uint(f);
  return (u16)((x + 0x7fffu + ((x >> 16) & 1u)) >> 16);
}

__device__ __forceinline__ void gl_lds16(const u16* g, u16* l){
  __builtin_amdgcn_global_load_lds((const __attribute__((address_space(1))) void*)g,
                                   (__attribute__((address_space(3))) void*)l, 16, 0, 0);
}

// ---------------- dtype detection: bf16 weights never have |x|>=2 ----------------
__global__ __launch_bounds__(256) void detect_kernel(const void* __restrict__ probe,
                                                     int* __restrict__ flag){
  __shared__ int cnt;
  if (threadIdx.x == 0) cnt = 0;
  __syncthreads();
  const u16* p = (const u16*)probe;
  int c = 0;
  for (int i = threadIdx.x; i < 2048; i += 256){
    int e = (p[i] >> 7) & 0xFF;
    if (e >= 128) c++;
  }
  atomicAdd(&cnt, c);
  __syncthreads();
  if (threadIdx.x == 0) *flag = (cnt > 32) ? 1 : 0;  // 1 = inputs are fp32
}

// ---------------- pointer table: bf16 -> use raw inputs in place; fp32 -> converted pool ----------------
struct PtrTab { const void* raw[23]; long long off[23]; };

__global__ __launch_bounds__(64) void fill_ptab(PtrTab pt, const u16* __restrict__ pool,
    const int* __restrict__ flag, const u16** __restrict__ ptab){
  int i = threadIdx.x;
  if (i < 23)
    ptab[i+1] = (*flag) ? (pool + pt.off[i]) : (const u16*)pt.raw[i];
}

// ---------------- fp32 -> bf16 conversion, tensors 3..23 only (wte/wpe stay raw) ----------------
struct CvtTab { const void* s[21]; int off8[22]; int bstart[22]; };

__global__ __launch_bounds__(256) void convert_all(CvtTab t, u16* __restrict__ pool,
                                                   const int* __restrict__ flag){
  if (!*flag) return;    // bf16 inputs are consumed in place via ptab
  int i = 0;
  #pragma unroll
  for (int k = 1; k < 21; k++) if ((int)blockIdx.x >= t.bstart[k]) i = k;
  const void* sp = t.s[0];
  #pragma unroll
  for (int k = 1; k < 21; k++) if (i == k) sp = t.s[k];
  const int n8 = t.off8[i+1] - t.off8[i];
  const int nb = t.bstart[i+1] - t.bstart[i];
  const int lb = (int)blockIdx.x - t.bstart[i];
  uint4* dp = (uint4*)pool + t.off8[i];
  const int stride = nb * 256;
  const float4* sf = (const float4*)sp;
  for (int j = lb*256 + (int)threadIdx.x; j < n8; j += stride){
    float4 a0 = sf[2*j], a1 = sf[2*j+1];
    uint4 r0;
    r0.x = (unsigned)f2bf(a0.x) | ((unsigned)f2bf(a0.y) << 16);
    r0.y = (unsigned)f2bf(a0.z) | ((unsigned)f2bf(a0.w) << 16);
    r0.z = (unsigned)f2bf(a1.x) | ((unsigned)f2bf(a1.y) << 16);
    r0.w = (unsigned)f2bf(a1.z) | ((unsigned)f2bf(a1.w) << 16);
    dp[j] = r0;
  }
}

// ---------------- embedding: x = wte[idx] + wpe (reads raw dtype directly) ----------------
__global__ __launch_bounds__(256) void embed_kernel(const int* __restrict__ idx,
    const void* __restrict__ wteR, const void* __restrict__ wpeR,
    const int* __restrict__ flag, float* __restrict__ x){
  int row = blockIdx.x;                 // b*T + t
  int t = row & (T_-1);
  int tok = idx[row];
  float* xo = x + (size_t)row * C_;
  int c = threadIdx.x;
  float a0,a1,b0,b1;
  if (*flag){
    const float* we = (const float*)wteR + (size_t)tok * C_;
    const float* wp = (const float*)wpeR + (size_t)t * C_;
    a0 = we[c]; a1 = we[c+256]; b0 = wp[c]; b1 = wp[c+256];
  } else {
    const u16* we = (const u16*)wteR + (size_t)tok * C_;
    const u16* wp = (const u16*)wpeR + (size_t)t * C_;
    a0 = bf2f(we[c]); a1 = bf2f(we[c+256]); b0 = bf2f(wp[c]); b1 = bf2f(wp[c+256]);
  }
  xo[c]     = a0 + b0;
  xo[c+256] = a1 + b1;
}

// ---------------- fused LN + time-mix token shift (recomputes LN of row t-1) ----------------
__global__ __launch_bounds__(256) void ln_tmix_kernel(const float* __restrict__ x,
    const u16* const* __restrict__ ptab, int l,
    u16* __restrict__ xk, u16* __restrict__ xv, u16* __restrict__ xr, u16* __restrict__ xg){
  const u16* w  = ptab[3] + l*C_;
  const u16* mk = ptab[6] + l*C_;
  const u16* mv = ptab[7] + l*C_;
  const u16* mr = ptab[8] + l*C_;
  const u16* mg = ptab[9] + l*C_;
  int row = blockIdx.x; int t = row & (T_-1);
  size_t off = (size_t)row*C_;
  const float* cur = x + off;
  int c = threadIdx.x;
  float v0 = cur[c], v1 = cur[c+256];
  float p0 = 0.f, p1 = 0.f;
  if (t){ p0 = cur[c - C_]; p1 = cur[c+256 - C_]; }
  float s = v0+v1, ss = v0*v0+v1*v1;
  float sp = p0+p1, ssp = p0*p0+p1*p1;
  int lane = c & 63, wid = c >> 6;
  #pragma unroll
  for (int o=32;o>0;o>>=1){
    s  += __shfl_down(s,o,64);  ss  += __shfl_down(ss,o,64);
    sp += __shfl_down(sp,o,64); ssp += __shfl_down(ssp,o,64);
  }
  __shared__ float r1[4], r2[4], r3[4], r4[4];
  if (lane==0){ r1[wid]=s; r2[wid]=ss; r3[wid]=sp; r4[wid]=ssp; }
  __syncthreads();
  if (c==0){
    float a =r1[0]+r1[1]+r1[2]+r1[3], bq=r2[0]+r2[1]+r2[2]+r2[3];
    float ap=r3[0]+r3[1]+r3[2]+r3[3], bp=r4[0]+r4[1]+r4[2]+r4[3];
    float mu  = a *(1.f/C_); float var  = bq*(1.f/C_) - mu*mu;
    float mup = ap*(1.f/C_); float varp = bp*(1.f/C_) - mup*mup;
    r1[0]=mu;  r2[0]=rsqrtf(fmaxf(var ,0.f)+1e-5f);
    r3[0]=mup; r4[0]=rsqrtf(fmaxf(varp,0.f)+1e-5f);
  }
  __syncthreads();
  float mu=r1[0], inv=r2[0], mup=r3[0], invp=r4[0];
  #pragma unroll
  for (int p=0;p<2;p++){
    int cc = c + p*256;
    float wc = bf2f(w[cc]);
    float xc = ((p?v1:v0)-mu)*inv*wc;
    float xp = t ? ((p?p1:p0)-mup)*invp*wc : 0.f;
    float xx = xp - xc;
    xk[off+cc] = f2bf(xc + xx*bf2f(mk[cc]));
    xv[off+cc] = f2bf(xc + xx*bf2f(mv[cc]));
    xr[off+cc] = f2bf(xc + xx*bf2f(mr[cc]));
    xg[off+cc] = f2bf(xc + xx*bf2f(mg[cc]));
  }
}

// ---------------- fused LN + channel-mix token shift ----------------
__global__ __launch_bounds__(256) void ln_cmix_kernel(const float* __restrict__ x,
    const u16* const* __restrict__ ptab, int l,
    u16* __restrict__ xk, u16* __restrict__ xr){
  const u16* w  = ptab[4]  + l*C_;
  const u16* mk = ptab[19] + l*C_;
  const u16* mr = ptab[20] + l*C_;
  int row = blockIdx.x; int t = row & (T_-1);
  size_t off = (size_t)row*C_;
  const float* cur = x + off;
  int c = threadIdx.x;
  float v0 = cur[c], v1 = cur[c+256];
  float p0 = 0.f, p1 = 0.f;
  if (t){ p0 = cur[c - C_]; p1 = cur[c+256 - C_]; }
  float s = v0+v1, ss = v0*v0+v1*v1;
  float sp = p0+p1, ssp = p0*p0+p1*p1;
  int lane = c & 63, wid = c >> 6;
  #pragma unroll
  for (int o=32;o>0;o>>=1){
    s  += __shfl_down(s,o,64);  ss  += __shfl_down(ss,o,64);
    sp += __shfl_down(sp,o,64); ssp += __shfl_down(ssp,o,64);
  }
  __shared__ float r1[4], r2[4], r3[4], r4[4];
  if (lane==0){ r1[wid]=s; r2[wid]=ss; r3[wid]=sp; r4[wid]=ssp; }
  __syncthreads();
  if (c==0){
    float a =r1[0]+r1[1]+r1[2]+r1[3], bq=r2[0]+r2[1]+r2[2]+r2[3];
    float ap=r3[0]+r3[1]+r3[2]+r3[3], bp=r4[0]+r4[1]+r4[2]+r4[3];
    float mu  = a *(1.f/C_); float var  = bq*(1.f/C_) - mu*mu;
    float mup = ap*(1.f/C_); float varp = bp*(1.f/C_) - mup*mup;
    r1[0]=mu;  r2[0]=rsqrtf(fmaxf(var ,0.f)+1e-5f);
    r3[0]=mup; r4[0]=rsqrtf(fmaxf(varp,0.f)+1e-5f);
  }
  __syncthreads();
  float mu=r1[0], inv=r2[0], mup=r3[0], invp=r4[0];
  #pragma unroll
  for (int p=0;p<2;p++){
    int cc = c + p*256;
    float wc = bf2f(w[cc]);
    float xc = ((p?v1:v0)-mu)*inv*wc;
    float xp = t ? ((p?p1:p0)-mup)*invp*wc : 0.f;
    float xx = xp - xc;
    xk[off+cc] = f2bf(xc + xx*bf2f(mk[cc]));
    xr[off+cc] = f2bf(xc + xx*bf2f(mr[cc]));
  }
}

// ---------------- final LN for last position only ----------------
__global__ __launch_bounds__(256) void lnf_last(const float* __restrict__ x,
    const u16* const* __restrict__ ptab, float* __restrict__ xf){
  const u16* w = ptab[5];
  int b = blockIdx.x;
  const float* xr = x + ((size_t)b*T_ + (T_-1))*C_;
  int c = threadIdx.x;
  float v0 = xr[c], v1 = xr[c+256];
  float s = v0+v1, ss = v0*v0+v1*v1;
  int lane = c & 63, wid = c >> 6;
  #pragma unroll
  for (int o=32;o>0;o>>=1){ s += __shfl_down(s,o,64); ss += __shfl_down(ss,o,64); }
  __shared__ float r1[4], r2[4];
  if (lane==0){ r1[wid]=s; r2[wid]=ss; }
  __syncthreads();
  if (c==0){
    float a=r1[0]+r1[1]+r1[2]+r1[3], bq=r2[0]+r2[1]+r2[2]+r2[3];
    float mu = a*(1.f/C_);
    float var = bq*(1.f/C_) - mu*mu;
    r1[0]=mu; r2[0]=rsqrtf(fmaxf(var,0.f)+1e-5f);
  }
  __syncthreads();
  float mu=r1[0], inv=r2[0];
  xf[b*C_+c]     = (v0-mu)*inv*bf2f(w[c]);
  xf[b*C_+c+256] = (v1-mu)*inv*bf2f(w[c+256]);
}

// ================= MFMA GEMM: 128(M) x 64(N), BK=64, 24KB LDS =================
#define ACT_RELU2_BF16 1
#define ACT_ADD_F32 2
#define ACT_BF16 3
#define ACT_CMIX 4      // Yf += v * bf2f(AuxB) (AuxB holds sigmoid gate)
#define ACT_SIG_BF16 7  // Yb = bf16(sigmoid(v))

template<int ACT>
__device__ __forceinline__ void gemm_mfma_body(u16* __restrict__ Al, u16* __restrict__ Bl,
    const u16* __restrict__ X, const u16* __restrict__ W,
    float* __restrict__ Yf, u16* __restrict__ Yb, const u16* __restrict__ AuxB,
    int Ndim, int Kdim, int bm, int bn){
  const int tid = threadIdx.x;
  const int wv = tid >> 6, ln = tid & 63;
  const int m16 = ln & 15, q = ln >> 4;

  f32x4 acc[2][4];
  #pragma unroll
  for (int i=0;i<2;i++)
    #pragma unroll
    for (int j=0;j<4;j++) acc[i][j] = f32x4{0.f,0.f,0.f,0.f};

  const int r0 = wv*8 + (ln >> 3);
  const int c0 = (ln & 7)*8;
  const u16* ga = X + (size_t)(bm + r0)*Kdim + c0;
  const u16* gb = W + (size_t)(bn + r0)*Kdim + c0;
  u16* la = Al + r0*64 + c0;
  u16* lb = Bl + r0*64 + c0;

  for (int k0=0; k0<Kdim; k0+=64){
    #pragma unroll
    for (int s=0;s<4;s++)
      gl_lds16(ga + (size_t)(s*32)*Kdim + k0, la + s*2048);
    #pragma unroll
    for (int s=0;s<2;s++)
      gl_lds16(gb + (size_t)(s*32)*Kdim + k0, lb + s*2048);
    __syncthreads();
    #pragma unroll
    for (int kh=0; kh<2; kh++){
      bf16x8 af[2], bfr[4];
      #pragma unroll
      for (int i=0;i<2;i++) af[i]  = *(const bf16x8*)(Al + (wv*32 + i*16 + m16)*64 + kh*32 + q*8);
      #pragma unroll
      for (int j=0;j<4;j++) bfr[j] = *(const bf16x8*)(Bl + (j*16 + m16)*64 + kh*32 + q*8);
      #pragma unroll
      for (int i=0;i<2;i++)
        #pragma unroll
        for (int j=0;j<4;j++)
          acc[i][j] = __builtin_amdgcn_mfma_f32_16x16x32_bf16(af[i], bfr[j], acc[i][j], 0, 0, 0);
    }
    __syncthreads();
  }

  // epilogue: C/D layout col=lane&15, row=quad*4+reg
  #pragma unroll
  for (int i=0;i<2;i++){
    int row = bm + wv*32 + i*16 + q*4;
    #pragma unroll
    for (int j=0;j<4;j++){
      int col = bn + j*16 + m16;
      #pragma unroll
      for (int r=0;r<4;r++){
        size_t off = (size_t)(row + r)*Ndim + col;
        float v = acc[i][j][r];
        if (ACT==ACT_ADD_F32) Yf[off] += v;
        else if (ACT==ACT_CMIX){ Yf[off] += v * bf2f(AuxB[off]); }
        else if (ACT==ACT_BF16) Yb[off] = f2bf(v);
        else if (ACT==ACT_RELU2_BF16){ float rr = v>0.f ? v : 0.f; Yb[off] = f2bf(rr*rr); }
        else if (ACT==ACT_SIG_BF16) Yb[off] = f2bf(1.f/(1.f+expf(-v)));
      }
    }
  }
}

#define GEMM_SH __shared__ __align__(16) u16 SH[128*64 + 64*64]

// fused r/k/v/g projections, 128x64 tiles, grid (64,8,4)
__global__ __launch_bounds__(256,4) void gemm4_mfma(const u16* const* __restrict__ ptab, int l,
    const u16* __restrict__ Abase,
    u16* __restrict__ Rb, u16* __restrict__ Kb, u16* __restrict__ Vb, u16* __restrict__ Gb){
  GEMM_SH;
  const size_t MC = (size_t)M_*C_;
  const size_t ws = (size_t)l*C_*C_;
  const int bm = blockIdx.x*128, bn = blockIdx.y*64;
  switch (blockIdx.z){
    case 0:  gemm_mfma_body<ACT_BF16>(SH, SH+128*64, Abase + 2*MC, ptab[12]+ws, nullptr, Rb, nullptr, C_, C_, bm, bn); break;
    case 1:  gemm_mfma_body<ACT_BF16>(SH, SH+128*64, Abase,        ptab[13]+ws, nullptr, Kb, nullptr, C_, C_, bm, bn); break;
    case 2:  gemm_mfma_body<ACT_BF16>(SH, SH+128*64, Abase + 1*MC, ptab[14]+ws, nullptr, Vb, nullptr, C_, C_, bm, bn); break;
    default: gemm_mfma_body<ACT_BF16>(SH, SH+128*64, Abase + 3*MC, ptab[15]+ws, nullptr, Gb, nullptr, C_, C_, bm, bn); break;
  }
}

// fused cmix key (relu^2 -> H1) + receptance gate (sigmoid -> RRb), 128x64, grid (64,32)
__global__ __launch_bounds__(256,4) void gemm_ck_cr(const u16* const* __restrict__ ptab, int l,
    const u16* __restrict__ MK, u16* __restrict__ H1,
    const u16* __restrict__ MV, u16* __restrict__ RRb){
  GEMM_SH;
  if (blockIdx.y < 24)
    gemm_mfma_body<ACT_RELU2_BF16>(SH, SH+128*64, MK, ptab[21]+(size_t)l*3*C_*C_, nullptr, H1, nullptr,
                                   3*C_, C_, blockIdx.x*128, blockIdx.y*64);
  else
    gemm_mfma_body<ACT_SIG_BF16>(SH, SH+128*64, MV, ptab[23]+(size_t)l*C_*C_, nullptr, RRb, nullptr,
                                 C_, C_, blockIdx.x*128, (blockIdx.y-24)*64);
}

// output projection with residual add: X += YGN @ Wo^T   (grid 64x8)
__global__ __launch_bounds__(256,4) void gemm_wo(const u16* const* __restrict__ ptab, int l,
    const u16* __restrict__ YGN, float* __restrict__ X){
  GEMM_SH;
  gemm_mfma_body<ACT_ADD_F32>(SH, SH+128*64, YGN, ptab[16]+(size_t)l*C_*C_, X, nullptr, nullptr,
                              C_, C_, blockIdx.x*128, blockIdx.y*64);
}

// cmix value GEMM with fused tail: X += gate * (H1 @ Wcv^T)   (grid 64x8)
__global__ __launch_bounds__(256,4) void gemm_cmix(const u16* const* __restrict__ ptab, int l,
    const u16* __restrict__ H1, float* __restrict__ X, const u16* __restrict__ RRb){
  GEMM_SH;
  gemm_mfma_body<ACT_CMIX>(SH, SH+128*64, H1, ptab[22]+(size_t)l*3*C_*C_, X, nullptr, RRb,
                           C_, 3*C_, blockIdx.x*128, blockIdx.y*64);
}

// ---------------- K/V per-(b,h) transpose; K gets wdec^(Q-1-tloc) scale ----------------
// grid (T/64, B*H, 2): z=0 V->Vt plain, z=1 K->Kt scaled
__global__ __launch_bounds__(256) void kvtrans(const u16* __restrict__ Kb, const u16* __restrict__ Vb,
    u16* __restrict__ Kt, u16* __restrict__ Vt, const u16* const* __restrict__ ptab, int l){
  __shared__ __align__(16) u16 tile[64*64];
  const int t0 = blockIdx.x*64, bh = blockIdx.y, b = bh>>3, h = bh&7;
  const bool isK = (blockIdx.z == 1);
  const u16* src = isK ? Kb : Vb;
  u16* dst = isK ? Kt : Vt;
  float l2w = 0.f;
  if (isK){
    const u16* td = ptab[10] + l*H_;
    l2w = -expf(bf2f(td[h])) * 1.44269504f;
  }
  const int tid = threadIdx.x;
  #pragma unroll
  for (int it=0; it<2; ++it){
    int tl = it*32 + (tid>>3);
    int n0 = (tid&7)*8;
    union {uint4 q; u16 e[8];} v;
    v.q = *(const uint4*)(src + ((size_t)(b*T_ + t0 + tl))*C_ + h*N_ + n0);
    if (isK){
      int tloc = (t0 + tl) & (Q_-1);
      float sc = exp2f(l2w * (float)(Q_-1 - tloc));
      #pragma unroll
      for (int e=0;e<8;++e) v.e[e] = f2bf(bf2f(v.e[e])*sc);
    }
    int col = n0 ^ (((tl>>3)&7)<<3);
    *(uint4*)&tile[tl*64 + col] = v.q;
  }
  __syncthreads();
  #pragma unroll
  for (int it=0; it<2; ++it){
    int nl = it*32 + (tid>>3);
    int t0l = (tid&7)*8;
    int swz = (tid&7)<<3;
    union {uint4 q; u16 h2[8];} pk;
    #pragma unroll
    for (int e=0;e<8;++e)
      pk.h2[e] = tile[(t0l+e)*64 + (nl ^ swz)];
    *(uint4*)(dst + ((size_t)(bh*N_ + nl))*T_ + t0 + t0l) = pk.q;
  }
}

// ---------------- per-chunk state, stored TRANSPOSED: St[v_feat][k_feat] ----------------
__global__ __launch_bounds__(256) void wkv_state_mfma(const u16* __restrict__ Kt,
    const u16* __restrict__ Vt, float* __restrict__ S){
  const int c = blockIdx.x, bh = blockIdx.y;
  const int tid = threadIdx.x, wv = tid >> 6, ln = tid & 63;
  const int m16 = ln & 15, q = ln >> 4;
  const u16* ka = Kt + (size_t)(bh*N_ + wv*16 + m16)*T_ + c*Q_;
  const u16* vb = Vt + (size_t)(bh*N_ + m16)*T_ + c*Q_;
  f32x4 acc[4];
  #pragma unroll
  for (int nt=0;nt<4;++nt) acc[nt] = f32x4{0.f,0.f,0.f,0.f};
  #pragma unroll
  for (int ks=0; ks<8; ++ks){
    bf16x8 af = *(const bf16x8*)(ka + ks*32 + q*8);
    #pragma unroll
    for (int nt=0;nt<4;++nt){
      bf16x8 bv = *(const bf16x8*)(vb + (size_t)(nt*16)*T_ + ks*32 + q*8);
      acc[nt] = __builtin_amdgcn_mfma_f32_16x16x32_bf16(af, bv, acc[nt], 0,0,0);
    }
  }
  float* Sp = S + ((size_t)bh*NC_ + c)*(N_*N_);
  // MFMA out: k_feat row = wv*16+q*4+r, v_feat col = nt*16+m16. Store transposed.
  #pragma unroll
  for (int nt=0;nt<4;++nt)
    #pragma unroll
    for (int r=0;r<4;++r)
      Sp[(nt*16 + m16)*N_ + (wv*16 + q*4 + r)] = acc[nt][r];
}

// ---------------- sequential prefix over chunks -> bf16 St output ----------------
// Sb16[cc] = bf16( sum_{j<cc} wsd^(cc-1-j) * S_j )  (exclusive prefix, f32 Horner)
__global__ __launch_bounds__(256) void wkv_prefix(const float* __restrict__ S,
    u16* __restrict__ Sb16, const u16* const* __restrict__ ptab, int l){
  const int bh = blockIdx.x, h = bh&7;
  const u16* td = ptab[10] + l*H_;
  const float l2w = -expf(bf2f(td[h])) * 1.44269504f;
  const float wsd = exp2f(l2w * (float)Q_);
  const float* Sp = S + (size_t)bh*NC_*N_*N_;
  u16* Sb = Sb16 + (size_t)bh*NC_*N_*N_;
  for (int e=threadIdx.x; e<N_*N_; e+=256){
    float cur = 0.f;
    for (int cc=0;cc<NC_;++cc){
      Sb[(size_t)cc*N_*N_ + e] = f2bf(cur);
      cur = wsd*cur + Sp[(size_t)cc*N_*N_ + e];
    }
  }
}

// ---------------- FUSED WKV: paired strips {z, 3-z} for uniform per-block work ----------------
// grid (NC_*2, B_*H_): block (c,z) computes strips ip=z and ip=3-z of chunk c.
// Every block does (z+1)+(4-z)=5 jt-units -> no CU load imbalance.
__global__ __launch_bounds__(256) void wkv_fused(const u16* __restrict__ Rb,
    const u16* __restrict__ Kb, const u16* __restrict__ Vt, const u16* __restrict__ Sb16,
    const u16* const* __restrict__ ptab, int l,
    const u16* __restrict__ g, u16* __restrict__ out){
  __shared__ float wpow[Q_];
  __shared__ __align__(16) u16 P[4][16][72];     // wave-private quarters
  __shared__ __align__(16) u16 stl[64][72];      // St bf16: [v_feat n][k_feat k]
  __shared__ __align__(16) u16 gl[2][64][72];    // g tiles for both strips
  const u16* td  = ptab[10] + l*H_;
  const u16* tf  = ptab[11] + l*H_;
  const u16* gnw = ptab[17] + l*C_;
  const u16* gnb = ptab[18] + l*C_;
  const int c = blockIdx.x>>1, z = blockIdx.x&1;
  const int bh = blockIdx.y, b = bh>>3, h = bh&7;
  const int tid = threadIdx.x, wv = tid >> 6, ln = tid & 63;
  const int m16 = ln & 15, q = ln >> 4;
  const float l2w = -expf(bf2f(td[h])) * 1.44269504f;
  const float uu = bf2f(tf[h]);
  wpow[tid] = exp2f(l2w * (float)tid);
  const size_t base = ((size_t)b*T_ + (size_t)c*Q_)*C_ + h*N_;
  const int ips[2] = { z, 3 - z };
  // stage bf16 St (coalesced uint4) and g tiles for both strips
  {
    const u16* Sp = Sb16 + ((size_t)bh*NC_ + c)*(N_*N_);
    #pragma unroll
    for (int k2=0;k2<2;++k2){
      int e = (tid + k2*256)*8;       // e = n*64 + k
      *(uint4*)&stl[e>>6][e&63] = *(const uint4*)(Sp + e);
    }
    #pragma unroll
    for (int half=0; half<2; ++half){
      int i0h = ips[half]*64;
      #pragma unroll
      for (int it=0; it<2; ++it){
        int rr2 = it*32 + (tid>>3);
        int n0 = (tid&7)*8;
        *(uint4*)&gl[half][rr2][n0] = *(const uint4*)(g + base + (size_t)(i0h+rr2)*C_ + n0);
      }
    }
  }
  __syncthreads();
  const u16* vtb = Vt + (size_t)(bh*N_)*T_ + (size_t)c*Q_;
  #pragma unroll
  for (int half=0; half<2; ++half){
    const int ip = ips[half];
    const int i0 = ip*64;
    const int iw0 = i0 + wv*16;
    // ---- intra-chunk (MFMA) ----
    const u16* rrow = Rb + base + (size_t)(iw0 + m16)*C_;
    bf16x8 af0 = *(const bf16x8*)(rrow + q*8);
    bf16x8 af1 = *(const bf16x8*)(rrow + 32 + q*8);
    f32x4 acc[4];
    #pragma unroll
    for (int nt=0;nt<4;++nt) acc[nt] = f32x4{0.f,0.f,0.f,0.f};
    const int irow = iw0 + q*4;
    for (int jt=0; jt<=ip; ++jt){
      // prefetch V fragments for this jt (independent of the K->P chain)
      bf16x8 vfr[2][4];
      #pragma unroll
      for (int kp=0;kp<2;++kp)
        #pragma unroll
        for (int nt=0;nt<4;++nt)
          vfr[kp][nt] = *(const bf16x8*)(vtb + (size_t)(nt*16 + m16)*T_ + jt*64 + kp*32 + q*8);
      f32x4 s[4];
      #pragma unroll
      for (int j2=0;j2<4;++j2) s[j2] = f32x4{0.f,0.f,0.f,0.f};
      #pragma unroll
      for (int j2=0;j2<4;++j2){
        const u16* kr = Kb + base + (size_t)(jt*64 + j2*16 + m16)*C_;
        bf16x8 b0 = *(const bf16x8*)(kr + q*8);
        bf16x8 b1 = *(const bf16x8*)(kr + 32 + q*8);
        s[j2] = __builtin_amdgcn_mfma_f32_16x16x32_bf16(af0, b0, s[j2], 0,0,0);
        s[j2] = __builtin_amdgcn_mfma_f32_16x16x32_bf16(af1, b1, s[j2], 0,0,0);
      }
      #pragma unroll
      for (int j2=0;j2<4;++j2){
        int jc = jt*64 + j2*16 + m16;
        #pragma unroll
        for (int r=0;r<4;++r){
          int ic = irow + r;
          float w = (jc < ic) ? wpow[ic-jc-1] : ((jc==ic) ? uu : 0.f);
          P[wv][q*4+r][j2*16+m16] = f2bf(s[j2][r]*w);
        }
      }
      __asm__ volatile("s_waitcnt lgkmcnt(0)" ::: "memory");
      #pragma unroll
      for (int kp=0;kp<2;++kp){
        bf16x8 ap = *(const bf16x8*)&P[wv][m16][kp*32 + q*8];
        #pragma unroll
        for (int nt=0;nt<4;++nt)
          acc[nt] = __builtin_amdgcn_mfma_f32_16x16x32_bf16(ap, vfr[kp][nt], acc[nt], 0,0,0);
      }
    }
    // ---- inter-chunk via MFMA: y2 = r @ St^T ----
    f32x4 acc2[4];
    #pragma unroll
    for (int nt=0;nt<4;++nt) acc2[nt] = f32x4{0.f,0.f,0.f,0.f};
    #pragma unroll
    for (int nt=0;nt<4;++nt){
      bf16x8 sb0 = *(const bf16x8*)&stl[nt*16 + m16][q*8];
      bf16x8 sb1 = *(const bf16x8*)&stl[nt*16 + m16][32 + q*8];
      acc2[nt] = __builtin_amdgcn_mfma_f32_16x16x32_bf16(af0, sb0, acc2[nt], 0,0,0);
      acc2[nt] = __builtin_amdgcn_mfma_f32_16x16x32_bf16(af1, sb1, acc2[nt], 0,0,0);
    }
    // ---- GroupNorm + silu(g) directly in MFMA C/D layout ----
    #pragma unroll
    for (int r=0;r<4;++r){
      int il = irow + r;                    // row within chunk [0,256)
      int rs = il - i0;                     // row within 64-row strip
      size_t roff = base + (size_t)il*C_;
      float w = wpow[il];
      float val[4];
      float s=0.f, ss=0.f;
      #pragma unroll
      for (int nt=0;nt<4;++nt){
        float v = acc[nt][r] + w*acc2[nt][r];
        val[nt]=v; s+=v; ss+=v*v;
      }
      #pragma unroll
      for (int o=8;o>0;o>>=1){ s+=__shfl_xor(s,o,64); ss+=__shfl_xor(ss,o,64); }
      float mu = s*(1.f/N_);
      float var = ss*(1.f/N_) - mu*mu;
      float inv = rsqrtf(fmaxf(var,0.f) + 6.4e-4f);   // GN_EPS = 1e-5*64
      #pragma unroll
      for (int nt=0;nt<4;++nt){
        int n = nt*16 + m16, ci = h*N_ + n;
        float gg = bf2f(gl[half][rs][n]);
        float sil = gg/(1.f+expf(-gg));
        out[roff + n] = f2bf(((val[nt]-mu)*inv*bf2f(gnw[ci]) + bf2f(gnb[ci]))*sil);
      }
    }
  }
}

// ---------------- logits for last position: [B,V] = xf @ wte^T (raw dtype) ----------------
__global__ __launch_bounds__(256) void logits_kernel(const float* __restrict__ xf,
    const void* __restrict__ wteR, void* __restrict__ out, const int* __restrict__ flag){
  const int wid = threadIdx.x>>6, lane = threadIdx.x&63;
  const int gw = blockIdx.x*4 + wid;     // 0 .. B*V-1
  const int b = gw / V_, v = gw - b*V_;
  const float* xr = xf + b*C_;
  float s = 0.f;
  if (*flag){
    const float* wrow = (const float*)wteR + (size_t)v*C_;
    float4 w0 = ((const float4*)wrow)[lane*2];
    float4 w1 = ((const float4*)wrow)[lane*2+1];
    const float* xp = xr + lane*8;
    s = w0.x*xp[0] + w0.y*xp[1] + w0.z*xp[2] + w0.w*xp[3]
      + w1.x*xp[4] + w1.y*xp[5] + w1.z*xp[6] + w1.w*xp[7];
  } else {
    const u16* wrow = (const u16*)wteR + (size_t)v*C_;
    union {uint4 q; u16 h[8];} uu;
    uu.q = *(const uint4*)(wrow + lane*8);
    #pragma unroll
    for (int j=0;j<8;j++) s += bf2f(uu.h[j])*xr[lane*8+j];
  }
  #pragma unroll
  for (int o=32;o>0;o>>=1) s += __shfl_down(s,o,64);
  if (lane==0){
    size_t o = (size_t)b*V_ + v;
    if (*flag) ((float*)out)[o] = s;          // fp32 harness
    else       ((u16*)out)[o]   = f2bf(s);    // bf16 harness
  }
}

extern "C" void kernel_launch(void* const* d_in, const int* in_sizes, int n_in,
                              void* d_out, int out_size, void* d_ws, size_t ws_size,
                              hipStream_t stream){
  (void)out_size; (void)ws_size; (void)n_in;
  const int* idx  = (const int*)d_in[0];

  char* ws = (char*)d_ws;
  const size_t MC  = (size_t)M_*C_;
  // ---- workspace layout (bytes) ----
  size_t o = 0;
  int* flag = (int*)(ws + o);            o += 1024;
  const u16** ptab = (const u16**)(ws + o); o += 1024;
  float* X   = (float*)(ws + o);         o += MC*4;            // fp32 residual
  u16* MK = (u16*)(ws + o);              o += MC*2;            // also YGN
  u16* MV = (u16*)(ws + o);              o += MC*2;
  u16* MR = (u16*)(ws + o);              o += MC*2;            // also S (tmix) / RRb (cmix)
  u16* MG = (u16*)(ws + o);              o += MC*2;            // also Sb16 (after gemm4)
  u16* Rb = (u16*)(ws + o);              o += MC*2;            // H1 spans Rb..Vb
  u16* Kb = (u16*)(ws + o);              o += MC*2;
  u16* Vb = (u16*)(ws + o);              o += MC*2;
  u16* Gb = (u16*)(ws + o);              o += MC*2;
  u16* Kt = (u16*)(ws + o);              o += MC*2;            // scaled k^T per (b,h): [BH*64, T]
  u16* Vt = (u16*)(ws + o);              o += MC*2;            // v^T per (b,h): [BH*64, T]
  float* XF = (float*)(ws + o);          o += 65536;
  u16* pool = (u16*)(ws + o);            // fp32->bf16 converted inputs 3..23
  u16* YGN = MK;
  float* S  = (float*)MR;    // f32 per-chunk states (live only during tmix phase)
  u16* Sb16 = MG;            // bf16 exclusive-prefix states (2 MB; MG free after gemm4)
  u16* H1 = Rb;              // [M,3C] bf16, spans Rb..Vb
  u16* RRb = MR;             // [M,C] bf16 sigmoid gate (cmix phase)

  // ---- dtype detect + pointer table + (conditional) conversion of tensors 3..23 ----
  detect_kernel<<<1,256,0,stream>>>(d_in[12], flag);   // probe Wr
  CvtTab tab; PtrTab pt;
  int nblocks;
  {
    size_t poff = 0; int acc8 = 0, bacc = 0;
    long long total8 = 0;
    for (int i=3;i<24;i++) total8 += (long long)(in_sizes[i] >> 3);
    pt.raw[0] = d_in[1]; pt.off[0] = 0;   // wte: raw only (never used via ptab)
    pt.raw[1] = d_in[2]; pt.off[1] = 0;   // wpe: raw only (never used via ptab)
    for (int i=3;i<24;i++){
      int j = i-3;
      pt.raw[i-1] = d_in[i];
      pt.off[i-1] = (long long)poff;
      poff += (size_t)in_sizes[i];
      tab.s[j] = d_in[i];
      tab.off8[j] = acc8;
      tab.bstart[j] = bacc;
      int n8 = in_sizes[i] >> 3;
      int nb = (int)(((long long)n8 * 2048 + total8 - 1) / total8);
      if (nb < 1) nb = 1;
      acc8 += n8; bacc += nb;
    }
    tab.off8[21] = acc8; tab.bstart[21] = bacc;
    nblocks = bacc;
  }
  fill_ptab<<<1,64,0,stream>>>(pt, pool, flag, ptab);
  convert_all<<<nblocks,256,0,stream>>>(tab, pool, flag);

  embed_kernel<<<M_,256,0,stream>>>(idx, d_in[1], d_in[2], flag, X);
  dim3 g4 (M_/128, C_/64, 4);      // (64,8,4) fused projections, 128x64
  dim3 gkv(T_/64, B_*H_, 2);       // K/V transpose
  dim3 gck(M_/128, 32);            // 24 ck tiles + 8 cr tiles, 128x64
  dim3 gwo(M_/128, C_/64);         // (64,8) 128x64
  for (int l=0;l<L_;++l){
    // ---- time mix ----
    ln_tmix_kernel<<<M_,256,0,stream>>>(X, ptab, l, MK,MV,MR,MG);
    gemm4_mfma<<<g4,256,0,stream>>>(ptab, l, MK, Rb, Kb, Vb, Gb);
    kvtrans<<<gkv,256,0,stream>>>(Kb, Vb, Kt, Vt, ptab, l);
    wkv_state_mfma<<<dim3(NC_, B_*H_),256,0,stream>>>(Kt, Vt, S);
    wkv_prefix<<<B_*H_,256,0,stream>>>(S, Sb16, ptab, l);
    wkv_fused<<<dim3(NC_*2, B_*H_),256,0,stream>>>(Rb, Kb, Vt, Sb16, ptab, l, Gb, YGN);
    gemm_wo<<<gwo,256,0,stream>>>(ptab, l, YGN, X);
    // ---- channel mix ----
    ln_cmix_kernel<<<M_,256,0,stream>>>(X, ptab, l, MK, MV);
    gemm_ck_cr<<<gck,256,0,stream>>>(ptab, l, MK, H1, MV, RRb);
    gemm_cmix<<<gwo,256,0,stream>>>(ptab, l, H1, X, RRb);
  }
  lnf_last<<<B_,256,0,stream>>>(X, ptab, XF);
  logits_kernel<<<(B_*V_)/4,256,0,stream>>>(XF, d_in[1], d_out, flag);
}

// Round 12
// 1391.128 us; speedup vs baseline: 1.2303x; 1.0158x over previous
//
#include <hip/hip_runtime.h>

#define L_ 6
#define H_ 8
#define C_ 512
#define V_ 32000
#define B_ 2
#define T_ 4096
#define Q_ 256
#define N_ 64
#define NC_ 16
#define M_ 8192   // B*T

typedef unsigned short u16;
typedef __attribute__((ext_vector_type(8))) short bf16x8;
typedef __attribute__((ext_vector_type(4))) float f32x4;

__device__ __forceinline__ float bf2f(u16 u){
  return __uint_as_float(((unsigned int)u) << 16);
}
__device__ __forceinline__ u16 f2bf(float f){
  unsigned int x = __float_as_uint(f);
  return (u16)((x + 0x7fffu + ((x >> 16) & 1u)) >> 16);
}

__device__ __forceinline__ void gl_lds16(const u16* g, u16* l){
  __builtin_amdgcn_global_load_lds((const __attribute__((address_space(1))) void*)g,
                                   (__attribute__((address_space(3))) void*)l, 16, 0, 0);
}

// ---------------- dtype detection: bf16 weights never have |x|>=2 ----------------
__global__ __launch_bounds__(256) void detect_kernel(const void* __restrict__ probe,
                                                     int* __restrict__ flag){
  __shared__ int cnt;
  if (threadIdx.x == 0) cnt = 0;
  __syncthreads();
  const u16* p = (const u16*)probe;
  int c = 0;
  for (int i = threadIdx.x; i < 2048; i += 256){
    int e = (p[i] >> 7) & 0xFF;
    if (e >= 128) c++;
  }
  atomicAdd(&cnt, c);
  __syncthreads();
  if (threadIdx.x == 0) *flag = (cnt > 32) ? 1 : 0;  // 1 = inputs are fp32
}

// ---------------- pointer table: bf16 -> use raw inputs in place; fp32 -> converted pool ----------------
struct PtrTab { const void* raw[23]; long long off[23]; };

__global__ __launch_bounds__(64) void fill_ptab(PtrTab pt, const u16* __restrict__ pool,
    const int* __restrict__ flag, const u16** __restrict__ ptab){
  int i = threadIdx.x;
  if (i < 23)
    ptab[i+1] = (*flag) ? (pool + pt.off[i]) : (const u16*)pt.raw[i];
}

// ---------------- fp32 -> bf16 conversion, tensors 3..23 only (wte/wpe stay raw) ----------------
struct CvtTab { const void* s[21]; int off8[22]; int bstart[22]; };

__global__ __launch_bounds__(256) void convert_all(CvtTab t, u16* __restrict__ pool,
                                                   const int* __restrict__ flag){
  if (!*flag) return;    // bf16 inputs are consumed in place via ptab
  int i = 0;
  #pragma unroll
  for (int k = 1; k < 21; k++) if ((int)blockIdx.x >= t.bstart[k]) i = k;
  const void* sp = t.s[0];
  #pragma unroll
  for (int k = 1; k < 21; k++) if (i == k) sp = t.s[k];
  const int n8 = t.off8[i+1] - t.off8[i];
  const int nb = t.bstart[i+1] - t.bstart[i];
  const int lb = (int)blockIdx.x - t.bstart[i];
  uint4* dp = (uint4*)pool + t.off8[i];
  const int stride = nb * 256;
  const float4* sf = (const float4*)sp;
  for (int j = lb*256 + (int)threadIdx.x; j < n8; j += stride){
    float4 a0 = sf[2*j], a1 = sf[2*j+1];
    uint4 r0;
    r0.x = (unsigned)f2bf(a0.x) | ((unsigned)f2bf(a0.y) << 16);
    r0.y = (unsigned)f2bf(a0.z) | ((unsigned)f2bf(a0.w) << 16);
    r0.z = (unsigned)f2bf(a1.x) | ((unsigned)f2bf(a1.y) << 16);
    r0.w = (unsigned)f2bf(a1.z) | ((unsigned)f2bf(a1.w) << 16);
    dp[j] = r0;
  }
}

// ---------------- embedding: x = wte[idx] + wpe (reads raw dtype directly) ----------------
__global__ __launch_bounds__(256) void embed_kernel(const int* __restrict__ idx,
    const void* __restrict__ wteR, const void* __restrict__ wpeR,
    const int* __restrict__ flag, float* __restrict__ x){
  int row = blockIdx.x;                 // b*T + t
  int t = row & (T_-1);
  int tok = idx[row];
  float* xo = x + (size_t)row * C_;
  int c = threadIdx.x;
  float a0,a1,b0,b1;
  if (*flag){
    const float* we = (const float*)wteR + (size_t)tok * C_;
    const float* wp = (const float*)wpeR + (size_t)t * C_;
    a0 = we[c]; a1 = we[c+256]; b0 = wp[c]; b1 = wp[c+256];
  } else {
    const u16* we = (const u16*)wteR + (size_t)tok * C_;
    const u16* wp = (const u16*)wpeR + (size_t)t * C_;
    a0 = bf2f(we[c]); a1 = bf2f(we[c+256]); b0 = bf2f(wp[c]); b1 = bf2f(wp[c+256]);
  }
  xo[c]     = a0 + b0;
  xo[c+256] = a1 + b1;
}

// ---------------- fused LN + time-mix token shift (recomputes LN of row t-1) ----------------
__global__ __launch_bounds__(256) void ln_tmix_kernel(const float* __restrict__ x,
    const u16* const* __restrict__ ptab, int l,
    u16* __restrict__ xk, u16* __restrict__ xv, u16* __restrict__ xr, u16* __restrict__ xg){
  const u16* w  = ptab[3] + l*C_;
  const u16* mk = ptab[6] + l*C_;
  const u16* mv = ptab[7] + l*C_;
  const u16* mr = ptab[8] + l*C_;
  const u16* mg = ptab[9] + l*C_;
  int row = blockIdx.x; int t = row & (T_-1);
  size_t off = (size_t)row*C_;
  const float* cur = x + off;
  int c = threadIdx.x;
  float v0 = cur[c], v1 = cur[c+256];
  float p0 = 0.f, p1 = 0.f;
  if (t){ p0 = cur[c - C_]; p1 = cur[c+256 - C_]; }
  float s = v0+v1, ss = v0*v0+v1*v1;
  float sp = p0+p1, ssp = p0*p0+p1*p1;
  int lane = c & 63, wid = c >> 6;
  #pragma unroll
  for (int o=32;o>0;o>>=1){
    s  += __shfl_down(s,o,64);  ss  += __shfl_down(ss,o,64);
    sp += __shfl_down(sp,o,64); ssp += __shfl_down(ssp,o,64);
  }
  __shared__ float r1[4], r2[4], r3[4], r4[4];
  if (lane==0){ r1[wid]=s; r2[wid]=ss; r3[wid]=sp; r4[wid]=ssp; }
  __syncthreads();
  if (c==0){
    float a =r1[0]+r1[1]+r1[2]+r1[3], bq=r2[0]+r2[1]+r2[2]+r2[3];
    float ap=r3[0]+r3[1]+r3[2]+r3[3], bp=r4[0]+r4[1]+r4[2]+r4[3];
    float mu  = a *(1.f/C_); float var  = bq*(1.f/C_) - mu*mu;
    float mup = ap*(1.f/C_); float varp = bp*(1.f/C_) - mup*mup;
    r1[0]=mu;  r2[0]=rsqrtf(fmaxf(var ,0.f)+1e-5f);
    r3[0]=mup; r4[0]=rsqrtf(fmaxf(varp,0.f)+1e-5f);
  }
  __syncthreads();
  float mu=r1[0], inv=r2[0], mup=r3[0], invp=r4[0];
  #pragma unroll
  for (int p=0;p<2;p++){
    int cc = c + p*256;
    float wc = bf2f(w[cc]);
    float xc = ((p?v1:v0)-mu)*inv*wc;
    float xp = t ? ((p?p1:p0)-mup)*invp*wc : 0.f;
    float xx = xp - xc;
    xk[off+cc] = f2bf(xc + xx*bf2f(mk[cc]));
    xv[off+cc] = f2bf(xc + xx*bf2f(mv[cc]));
    xr[off+cc] = f2bf(xc + xx*bf2f(mr[cc]));
    xg[off+cc] = f2bf(xc + xx*bf2f(mg[cc]));
  }
}

// ---------------- fused LN + channel-mix token shift ----------------
__global__ __launch_bounds__(256) void ln_cmix_kernel(const float* __restrict__ x,
    const u16* const* __restrict__ ptab, int l,
    u16* __restrict__ xk, u16* __restrict__ xr){
  const u16* w  = ptab[4]  + l*C_;
  const u16* mk = ptab[19] + l*C_;
  const u16* mr = ptab[20] + l*C_;
  int row = blockIdx.x; int t = row & (T_-1);
  size_t off = (size_t)row*C_;
  const float* cur = x + off;
  int c = threadIdx.x;
  float v0 = cur[c], v1 = cur[c+256];
  float p0 = 0.f, p1 = 0.f;
  if (t){ p0 = cur[c - C_]; p1 = cur[c+256 - C_]; }
  float s = v0+v1, ss = v0*v0+v1*v1;
  float sp = p0+p1, ssp = p0*p0+p1*p1;
  int lane = c & 63, wid = c >> 6;
  #pragma unroll
  for (int o=32;o>0;o>>=1){
    s  += __shfl_down(s,o,64);  ss  += __shfl_down(ss,o,64);
    sp += __shfl_down(sp,o,64); ssp += __shfl_down(ssp,o,64);
  }
  __shared__ float r1[4], r2[4], r3[4], r4[4];
  if (lane==0){ r1[wid]=s; r2[wid]=ss; r3[wid]=sp; r4[wid]=ssp; }
  __syncthreads();
  if (c==0){
    float a =r1[0]+r1[1]+r1[2]+r1[3], bq=r2[0]+r2[1]+r2[2]+r2[3];
    float ap=r3[0]+r3[1]+r3[2]+r3[3], bp=r4[0]+r4[1]+r4[2]+r4[3];
    float mu  = a *(1.f/C_); float var  = bq*(1.f/C_) - mu*mu;
    float mup = ap*(1.f/C_); float varp = bp*(1.f/C_) - mup*mup;
    r1[0]=mu;  r2[0]=rsqrtf(fmaxf(var ,0.f)+1e-5f);
    r3[0]=mup; r4[0]=rsqrtf(fmaxf(varp,0.f)+1e-5f);
  }
  __syncthreads();
  float mu=r1[0], inv=r2[0], mup=r3[0], invp=r4[0];
  #pragma unroll
  for (int p=0;p<2;p++){
    int cc = c + p*256;
    float wc = bf2f(w[cc]);
    float xc = ((p?v1:v0)-mu)*inv*wc;
    float xp = t ? ((p?p1:p0)-mup)*invp*wc : 0.f;
    float xx = xp - xc;
    xk[off+cc] = f2bf(xc + xx*bf2f(mk[cc]));
    xr[off+cc] = f2bf(xc + xx*bf2f(mr[cc]));
  }
}

// ---------------- final LN for last position only ----------------
__global__ __launch_bounds__(256) void lnf_last(const float* __restrict__ x,
    const u16* const* __restrict__ ptab, float* __restrict__ xf){
  const u16* w = ptab[5];
  int b = blockIdx.x;
  const float* xr = x + ((size_t)b*T_ + (T_-1))*C_;
  int c = threadIdx.x;
  float v0 = xr[c], v1 = xr[c+256];
  float s = v0+v1, ss = v0*v0+v1*v1;
  int lane = c & 63, wid = c >> 6;
  #pragma unroll
  for (int o=32;o>0;o>>=1){ s += __shfl_down(s,o,64); ss += __shfl_down(ss,o,64); }
  __shared__ float r1[4], r2[4];
  if (lane==0){ r1[wid]=s; r2[wid]=ss; }
  __syncthreads();
  if (c==0){
    float a=r1[0]+r1[1]+r1[2]+r1[3], bq=r2[0]+r2[1]+r2[2]+r2[3];
    float mu = a*(1.f/C_);
    float var = bq*(1.f/C_) - mu*mu;
    r1[0]=mu; r2[0]=rsqrtf(fmaxf(var,0.f)+1e-5f);
  }
  __syncthreads();
  float mu=r1[0], inv=r2[0];
  xf[b*C_+c]     = (v0-mu)*inv*bf2f(w[c]);
  xf[b*C_+c+256] = (v1-mu)*inv*bf2f(w[c+256]);
}

// ================= MFMA GEMM: 128(M) x 64(N), BK=64, 24KB LDS =================
#define ACT_RELU2_BF16 1
#define ACT_ADD_F32 2
#define ACT_BF16 3
#define ACT_CMIX 4      // Yf += v * bf2f(AuxB) (AuxB holds sigmoid gate)
#define ACT_SIG_BF16 7  // Yb = bf16(sigmoid(v))

template<int ACT>
__device__ __forceinline__ void gemm_mfma_body(u16* __restrict__ Al, u16* __restrict__ Bl,
    const u16* __restrict__ X, const u16* __restrict__ W,
    float* __restrict__ Yf, u16* __restrict__ Yb, const u16* __restrict__ AuxB,
    int Ndim, int Kdim, int bm, int bn){
  const int tid = threadIdx.x;
  const int wv = tid >> 6, ln = tid & 63;
  const int m16 = ln & 15, q = ln >> 4;

  f32x4 acc[2][4];
  #pragma unroll
  for (int i=0;i<2;i++)
    #pragma unroll
    for (int j=0;j<4;j++) acc[i][j] = f32x4{0.f,0.f,0.f,0.f};

  const int r0 = wv*8 + (ln >> 3);
  const int c0 = (ln & 7)*8;
  const u16* ga = X + (size_t)(bm + r0)*Kdim + c0;
  const u16* gb = W + (size_t)(bn + r0)*Kdim + c0;
  u16* la = Al + r0*64 + c0;
  u16* lb = Bl + r0*64 + c0;

  for (int k0=0; k0<Kdim; k0+=64){
    #pragma unroll
    for (int s=0;s<4;s++)
      gl_lds16(ga + (size_t)(s*32)*Kdim + k0, la + s*2048);
    #pragma unroll
    for (int s=0;s<2;s++)
      gl_lds16(gb + (size_t)(s*32)*Kdim + k0, lb + s*2048);
    __syncthreads();
    #pragma unroll
    for (int kh=0; kh<2; kh++){
      bf16x8 af[2], bfr[4];
      #pragma unroll
      for (int i=0;i<2;i++) af[i]  = *(const bf16x8*)(Al + (wv*32 + i*16 + m16)*64 + kh*32 + q*8);
      #pragma unroll
      for (int j=0;j<4;j++) bfr[j] = *(const bf16x8*)(Bl + (j*16 + m16)*64 + kh*32 + q*8);
      #pragma unroll
      for (int i=0;i<2;i++)
        #pragma unroll
        for (int j=0;j<4;j++)
          acc[i][j] = __builtin_amdgcn_mfma_f32_16x16x32_bf16(af[i], bfr[j], acc[i][j], 0, 0, 0);
    }
    __syncthreads();
  }

  // epilogue: C/D layout col=lane&15, row=quad*4+reg
  #pragma unroll
  for (int i=0;i<2;i++){
    int row = bm + wv*32 + i*16 + q*4;
    #pragma unroll
    for (int j=0;j<4;j++){
      int col = bn + j*16 + m16;
      #pragma unroll
      for (int r=0;r<4;r++){
        size_t off = (size_t)(row + r)*Ndim + col;
        float v = acc[i][j][r];
        if (ACT==ACT_ADD_F32) Yf[off] += v;
        else if (ACT==ACT_CMIX){ Yf[off] += v * bf2f(AuxB[off]); }
        else if (ACT==ACT_BF16) Yb[off] = f2bf(v);
        else if (ACT==ACT_RELU2_BF16){ float rr = v>0.f ? v : 0.f; Yb[off] = f2bf(rr*rr); }
        else if (ACT==ACT_SIG_BF16) Yb[off] = f2bf(1.f/(1.f+expf(-v)));
      }
    }
  }
}

#define GEMM_SH __shared__ __align__(16) u16 SH[128*64 + 64*64]

// fused r/k/v/g projections, 128x64 tiles, grid (64,8,4)
__global__ __launch_bounds__(256,4) void gemm4_mfma(const u16* const* __restrict__ ptab, int l,
    const u16* __restrict__ Abase,
    u16* __restrict__ Rb, u16* __restrict__ Kb, u16* __restrict__ Vb, u16* __restrict__ Gb){
  GEMM_SH;
  const size_t MC = (size_t)M_*C_;
  const size_t ws = (size_t)l*C_*C_;
  const int bm = blockIdx.x*128, bn = blockIdx.y*64;
  switch (blockIdx.z){
    case 0:  gemm_mfma_body<ACT_BF16>(SH, SH+128*64, Abase + 2*MC, ptab[12]+ws, nullptr, Rb, nullptr, C_, C_, bm, bn); break;
    case 1:  gemm_mfma_body<ACT_BF16>(SH, SH+128*64, Abase,        ptab[13]+ws, nullptr, Kb, nullptr, C_, C_, bm, bn); break;
    case 2:  gemm_mfma_body<ACT_BF16>(SH, SH+128*64, Abase + 1*MC, ptab[14]+ws, nullptr, Vb, nullptr, C_, C_, bm, bn); break;
    default: gemm_mfma_body<ACT_BF16>(SH, SH+128*64, Abase + 3*MC, ptab[15]+ws, nullptr, Gb, nullptr, C_, C_, bm, bn); break;
  }
}

// fused cmix key (relu^2 -> H1) + receptance gate (sigmoid -> RRb), 128x64, grid (64,32)
__global__ __launch_bounds__(256,4) void gemm_ck_cr(const u16* const* __restrict__ ptab, int l,
    const u16* __restrict__ MK, u16* __restrict__ H1,
    const u16* __restrict__ MV, u16* __restrict__ RRb){
  GEMM_SH;
  if (blockIdx.y < 24)
    gemm_mfma_body<ACT_RELU2_BF16>(SH, SH+128*64, MK, ptab[21]+(size_t)l*3*C_*C_, nullptr, H1, nullptr,
                                   3*C_, C_, blockIdx.x*128, blockIdx.y*64);
  else
    gemm_mfma_body<ACT_SIG_BF16>(SH, SH+128*64, MV, ptab[23]+(size_t)l*C_*C_, nullptr, RRb, nullptr,
                                 C_, C_, blockIdx.x*128, (blockIdx.y-24)*64);
}

// output projection with residual add: X += YGN @ Wo^T   (grid 64x8)
__global__ __launch_bounds__(256,4) void gemm_wo(const u16* const* __restrict__ ptab, int l,
    const u16* __restrict__ YGN, float* __restrict__ X){
  GEMM_SH;
  gemm_mfma_body<ACT_ADD_F32>(SH, SH+128*64, YGN, ptab[16]+(size_t)l*C_*C_, X, nullptr, nullptr,
                              C_, C_, blockIdx.x*128, blockIdx.y*64);
}

// cmix value GEMM with fused tail: X += gate * (H1 @ Wcv^T)   (grid 64x8)
__global__ __launch_bounds__(256,4) void gemm_cmix(const u16* const* __restrict__ ptab, int l,
    const u16* __restrict__ H1, float* __restrict__ X, const u16* __restrict__ RRb){
  GEMM_SH;
  gemm_mfma_body<ACT_CMIX>(SH, SH+128*64, H1, ptab[22]+(size_t)l*3*C_*C_, X, nullptr, RRb,
                           C_, 3*C_, blockIdx.x*128, blockIdx.y*64);
}

// ---------------- K/V per-(b,h) transpose; K gets wdec^(Q-1-tloc) scale ----------------
// grid (T/64, B*H, 2): z=0 V->Vt plain, z=1 K->Kt scaled
__global__ __launch_bounds__(256) void kvtrans(const u16* __restrict__ Kb, const u16* __restrict__ Vb,
    u16* __restrict__ Kt, u16* __restrict__ Vt, const u16* const* __restrict__ ptab, int l){
  __shared__ __align__(16) u16 tile[64*64];
  const int t0 = blockIdx.x*64, bh = blockIdx.y, b = bh>>3, h = bh&7;
  const bool isK = (blockIdx.z == 1);
  const u16* src = isK ? Kb : Vb;
  u16* dst = isK ? Kt : Vt;
  float l2w = 0.f;
  if (isK){
    const u16* td = ptab[10] + l*H_;
    l2w = -expf(bf2f(td[h])) * 1.44269504f;
  }
  const int tid = threadIdx.x;
  #pragma unroll
  for (int it=0; it<2; ++it){
    int tl = it*32 + (tid>>3);
    int n0 = (tid&7)*8;
    union {uint4 q; u16 e[8];} v;
    v.q = *(const uint4*)(src + ((size_t)(b*T_ + t0 + tl))*C_ + h*N_ + n0);
    if (isK){
      int tloc = (t0 + tl) & (Q_-1);
      float sc = exp2f(l2w * (float)(Q_-1 - tloc));
      #pragma unroll
      for (int e=0;e<8;++e) v.e[e] = f2bf(bf2f(v.e[e])*sc);
    }
    int col = n0 ^ (((tl>>3)&7)<<3);
    *(uint4*)&tile[tl*64 + col] = v.q;
  }
  __syncthreads();
  #pragma unroll
  for (int it=0; it<2; ++it){
    int nl = it*32 + (tid>>3);
    int t0l = (tid&7)*8;
    int swz = (tid&7)<<3;
    union {uint4 q; u16 h2[8];} pk;
    #pragma unroll
    for (int e=0;e<8;++e)
      pk.h2[e] = tile[(t0l+e)*64 + (nl ^ swz)];
    *(uint4*)(dst + ((size_t)(bh*N_ + nl))*T_ + t0 + t0l) = pk.q;
  }
}

// ---------------- per-chunk state, stored TRANSPOSED: St[v_feat][k_feat] ----------------
__global__ __launch_bounds__(256) void wkv_state_mfma(const u16* __restrict__ Kt,
    const u16* __restrict__ Vt, float* __restrict__ S){
  const int c = blockIdx.x, bh = blockIdx.y;
  const int tid = threadIdx.x, wv = tid >> 6, ln = tid & 63;
  const int m16 = ln & 15, q = ln >> 4;
  const u16* ka = Kt + (size_t)(bh*N_ + wv*16 + m16)*T_ + c*Q_;
  const u16* vb = Vt + (size_t)(bh*N_ + m16)*T_ + c*Q_;
  f32x4 acc[4];
  #pragma unroll
  for (int nt=0;nt<4;++nt) acc[nt] = f32x4{0.f,0.f,0.f,0.f};
  #pragma unroll
  for (int ks=0; ks<8; ++ks){
    bf16x8 af = *(const bf16x8*)(ka + ks*32 + q*8);
    #pragma unroll
    for (int nt=0;nt<4;++nt){
      bf16x8 bv = *(const bf16x8*)(vb + (size_t)(nt*16)*T_ + ks*32 + q*8);
      acc[nt] = __builtin_amdgcn_mfma_f32_16x16x32_bf16(af, bv, acc[nt], 0,0,0);
    }
  }
  float* Sp = S + ((size_t)bh*NC_ + c)*(N_*N_);
  // MFMA out: k_feat row = wv*16+q*4+r, v_feat col = nt*16+m16. Store transposed.
  #pragma unroll
  for (int nt=0;nt<4;++nt)
    #pragma unroll
    for (int r=0;r<4;++r)
      Sp[(nt*16 + m16)*N_ + (wv*16 + q*4 + r)] = acc[nt][r];
}

// ---------------- sequential prefix over chunks -> bf16 St output ----------------
// Sb16[cc] = bf16( sum_{j<cc} wsd^(cc-1-j) * S_j )  (exclusive prefix, f32 Horner)
__global__ __launch_bounds__(256) void wkv_prefix(const float* __restrict__ S,
    u16* __restrict__ Sb16, const u16* const* __restrict__ ptab, int l){
  const int bh = blockIdx.x, h = bh&7;
  const u16* td = ptab[10] + l*H_;
  const float l2w = -expf(bf2f(td[h])) * 1.44269504f;
  const float wsd = exp2f(l2w * (float)Q_);
  const float* Sp = S + (size_t)bh*NC_*N_*N_;
  u16* Sb = Sb16 + (size_t)bh*NC_*N_*N_;
  for (int e=threadIdx.x; e<N_*N_; e+=256){
    float cur = 0.f;
    for (int cc=0;cc<NC_;++cc){
      Sb[(size_t)cc*N_*N_ + e] = f2bf(cur);
      cur = wsd*cur + Sp[(size_t)cc*N_*N_ + e];
    }
  }
}

// ---------------- FUSED WKV: single strip per block, ip swizzled across co-resident blocks ----
// grid (NC_*4, B_*H_). Co-resident blocks differ by 256 in linear id -> same x, y+4.
// ip = ((x&3)+(y>>2))&3 gives each CU's 4 resident blocks DIFFERENT ips -> uniform 10 units/CU.
__global__ __launch_bounds__(256) void wkv_fused(const u16* __restrict__ Rb,
    const u16* __restrict__ Kb, const u16* __restrict__ Vt, const u16* __restrict__ Sb16,
    const u16* const* __restrict__ ptab, int l,
    const u16* __restrict__ g, u16* __restrict__ out){
  __shared__ float wpow[Q_];
  __shared__ __align__(16) u16 P[4][16][72];    // wave-private quarters
  __shared__ __align__(16) u16 stl[64][72];     // St bf16: [v_feat n][k_feat k]
  __shared__ __align__(16) u16 gl[64][72];      // g tile: [row-in-strip][n]
  const u16* td  = ptab[10] + l*H_;
  const u16* tf  = ptab[11] + l*H_;
  const u16* gnw = ptab[17] + l*C_;
  const u16* gnb = ptab[18] + l*C_;
  const int c = blockIdx.x>>2;
  const int ip = ((blockIdx.x & 3) + (blockIdx.y >> 2)) & 3;   // balance swizzle
  const int bh = blockIdx.y, b = bh>>3, h = bh&7;
  const int tid = threadIdx.x, wv = tid >> 6, ln = tid & 63;
  const int m16 = ln & 15, q = ln >> 4;
  const float l2w = -expf(bf2f(td[h])) * 1.44269504f;
  const float uu = bf2f(tf[h]);
  wpow[tid] = exp2f(l2w * (float)tid);
  const size_t base = ((size_t)b*T_ + (size_t)c*Q_)*C_ + h*N_;
  const int i0 = ip*64;
  // stage bf16 St (coalesced uint4) and g tile
  {
    const u16* Sp = Sb16 + ((size_t)bh*NC_ + c)*(N_*N_);
    #pragma unroll
    for (int k2=0;k2<2;++k2){
      int e = (tid + k2*256)*8;       // e = n*64 + k
      *(uint4*)&stl[e>>6][e&63] = *(const uint4*)(Sp + e);
    }
    #pragma unroll
    for (int it=0; it<2; ++it){
      int rr2 = it*32 + (tid>>3);
      int n0 = (tid&7)*8;
      *(uint4*)&gl[rr2][n0] = *(const uint4*)(g + base + (size_t)(i0+rr2)*C_ + n0);
    }
  }
  __syncthreads();
  // ---- intra-chunk (MFMA) ----
  const int iw0 = i0 + wv*16;
  const u16* rrow = Rb + base + (size_t)(iw0 + m16)*C_;
  bf16x8 af0 = *(const bf16x8*)(rrow + q*8);
  bf16x8 af1 = *(const bf16x8*)(rrow + 32 + q*8);
  f32x4 acc[4];
  #pragma unroll
  for (int nt=0;nt<4;++nt) acc[nt] = f32x4{0.f,0.f,0.f,0.f};
  const int irow = iw0 + q*4;
  const u16* vtb = Vt + (size_t)(bh*N_)*T_ + (size_t)c*Q_;
  for (int jt=0; jt<=ip; ++jt){
    // prefetch V fragments for this jt (independent of the K->P chain)
    bf16x8 vfr[2][4];
    #pragma unroll
    for (int kp=0;kp<2;++kp)
      #pragma unroll
      for (int nt=0;nt<4;++nt)
        vfr[kp][nt] = *(const bf16x8*)(vtb + (size_t)(nt*16 + m16)*T_ + jt*64 + kp*32 + q*8);
    f32x4 s[4];
    #pragma unroll
    for (int j2=0;j2<4;++j2) s[j2] = f32x4{0.f,0.f,0.f,0.f};
    #pragma unroll
    for (int j2=0;j2<4;++j2){
      const u16* kr = Kb + base + (size_t)(jt*64 + j2*16 + m16)*C_;
      bf16x8 b0 = *(const bf16x8*)(kr + q*8);
      bf16x8 b1 = *(const bf16x8*)(kr + 32 + q*8);
      s[j2] = __builtin_amdgcn_mfma_f32_16x16x32_bf16(af0, b0, s[j2], 0,0,0);
      s[j2] = __builtin_amdgcn_mfma_f32_16x16x32_bf16(af1, b1, s[j2], 0,0,0);
    }
    #pragma unroll
    for (int j2=0;j2<4;++j2){
      int jc = jt*64 + j2*16 + m16;
      #pragma unroll
      for (int r=0;r<4;++r){
        int ic = irow + r;
        float w = (jc < ic) ? wpow[ic-jc-1] : ((jc==ic) ? uu : 0.f);
        P[wv][q*4+r][j2*16+m16] = f2bf(s[j2][r]*w);
      }
    }
    __asm__ volatile("s_waitcnt lgkmcnt(0)" ::: "memory");
    #pragma unroll
    for (int kp=0;kp<2;++kp){
      bf16x8 ap = *(const bf16x8*)&P[wv][m16][kp*32 + q*8];
      #pragma unroll
      for (int nt=0;nt<4;++nt)
        acc[nt] = __builtin_amdgcn_mfma_f32_16x16x32_bf16(ap, vfr[kp][nt], acc[nt], 0,0,0);
    }
  }
  // ---- inter-chunk via MFMA: y2 = r @ St^T ----
  f32x4 acc2[4];
  #pragma unroll
  for (int nt=0;nt<4;++nt) acc2[nt] = f32x4{0.f,0.f,0.f,0.f};
  #pragma unroll
  for (int nt=0;nt<4;++nt){
    bf16x8 sb0 = *(const bf16x8*)&stl[nt*16 + m16][q*8];
    bf16x8 sb1 = *(const bf16x8*)&stl[nt*16 + m16][32 + q*8];
    acc2[nt] = __builtin_amdgcn_mfma_f32_16x16x32_bf16(af0, sb0, acc2[nt], 0,0,0);
    acc2[nt] = __builtin_amdgcn_mfma_f32_16x16x32_bf16(af1, sb1, acc2[nt], 0,0,0);
  }
  // ---- GroupNorm + silu(g) directly in MFMA C/D layout ----
  #pragma unroll
  for (int r=0;r<4;++r){
    int il = irow + r;                    // row within chunk [0,256)
    int rs = il - i0;                     // row within 64-row strip
    size_t roff = base + (size_t)il*C_;
    float w = wpow[il];
    float val[4];
    float s=0.f, ss=0.f;
    #pragma unroll
    for (int nt=0;nt<4;++nt){
      float v = acc[nt][r] + w*acc2[nt][r];
      val[nt]=v; s+=v; ss+=v*v;
    }
    #pragma unroll
    for (int o=8;o>0;o>>=1){ s+=__shfl_xor(s,o,64); ss+=__shfl_xor(ss,o,64); }
    float mu = s*(1.f/N_);
    float var = ss*(1.f/N_) - mu*mu;
    float inv = rsqrtf(fmaxf(var,0.f) + 6.4e-4f);   // GN_EPS = 1e-5*64
    #pragma unroll
    for (int nt=0;nt<4;++nt){
      int n = nt*16 + m16, ci = h*N_ + n;
      float gg = bf2f(gl[rs][n]);
      float sil = gg/(1.f+expf(-gg));
      out[roff + n] = f2bf(((val[nt]-mu)*inv*bf2f(gnw[ci]) + bf2f(gnb[ci]))*sil);
    }
  }
}

// ---------------- logits for last position: [B,V] = xf @ wte^T (raw dtype) ----------------
__global__ __launch_bounds__(256) void logits_kernel(const float* __restrict__ xf,
    const void* __restrict__ wteR, void* __restrict__ out, const int* __restrict__ flag){
  const int wid = threadIdx.x>>6, lane = threadIdx.x&63;
  const int gw = blockIdx.x*4 + wid;     // 0 .. B*V-1
  const int b = gw / V_, v = gw - b*V_;
  const float* xr = xf + b*C_;
  float s = 0.f;
  if (*flag){
    const float* wrow = (const float*)wteR + (size_t)v*C_;
    float4 w0 = ((const float4*)wrow)[lane*2];
    float4 w1 = ((const float4*)wrow)[lane*2+1];
    const float* xp = xr + lane*8;
    s = w0.x*xp[0] + w0.y*xp[1] + w0.z*xp[2] + w0.w*xp[3]
      + w1.x*xp[4] + w1.y*xp[5] + w1.z*xp[6] + w1.w*xp[7];
  } else {
    const u16* wrow = (const u16*)wteR + (size_t)v*C_;
    union {uint4 q; u16 h[8];} uu;
    uu.q = *(const uint4*)(wrow + lane*8);
    #pragma unroll
    for (int j=0;j<8;j++) s += bf2f(uu.h[j])*xr[lane*8+j];
  }
  #pragma unroll
  for (int o=32;o>0;o>>=1) s += __shfl_down(s,o,64);
  if (lane==0){
    size_t o = (size_t)b*V_ + v;
    if (*flag) ((float*)out)[o] = s;          // fp32 harness
    else       ((u16*)out)[o]   = f2bf(s);    // bf16 harness
  }
}

extern "C" void kernel_launch(void* const* d_in, const int* in_sizes, int n_in,
                              void* d_out, int out_size, void* d_ws, size_t ws_size,
                              hipStream_t stream){
  (void)out_size; (void)ws_size; (void)n_in;
  const int* idx  = (const int*)d_in[0];

  char* ws = (char*)d_ws;
  const size_t MC  = (size_t)M_*C_;
  // ---- workspace layout (bytes) ----
  size_t o = 0;
  int* flag = (int*)(ws + o);            o += 1024;
  const u16** ptab = (const u16**)(ws + o); o += 1024;
  float* X   = (float*)(ws + o);         o += MC*4;            // fp32 residual
  u16* MK = (u16*)(ws + o);              o += MC*2;            // also YGN
  u16* MV = (u16*)(ws + o);              o += MC*2;
  u16* MR = (u16*)(ws + o);              o += MC*2;            // also S (tmix) / RRb (cmix)
  u16* MG = (u16*)(ws + o);              o += MC*2;            // also Sb16 (after gemm4)
  u16* Rb = (u16*)(ws + o);              o += MC*2;            // H1 spans Rb..Vb
  u16* Kb = (u16*)(ws + o);              o += MC*2;
  u16* Vb = (u16*)(ws + o);              o += MC*2;
  u16* Gb = (u16*)(ws + o);              o += MC*2;
  u16* Kt = (u16*)(ws + o);              o += MC*2;            // scaled k^T per (b,h): [BH*64, T]
  u16* Vt = (u16*)(ws + o);              o += MC*2;            // v^T per (b,h): [BH*64, T]
  float* XF = (float*)(ws + o);          o += 65536;
  u16* pool = (u16*)(ws + o);            // fp32->bf16 converted inputs 3..23
  u16* YGN = MK;
  float* S  = (float*)MR;    // f32 per-chunk states (live only during tmix phase)
  u16* Sb16 = MG;            // bf16 exclusive-prefix states (2 MB; MG free after gemm4)
  u16* H1 = Rb;              // [M,3C] bf16, spans Rb..Vb
  u16* RRb = MR;             // [M,C] bf16 sigmoid gate (cmix phase)

  // ---- dtype detect + pointer table + (conditional) conversion of tensors 3..23 ----
  detect_kernel<<<1,256,0,stream>>>(d_in[12], flag);   // probe Wr
  CvtTab tab; PtrTab pt;
  int nblocks;
  {
    size_t poff = 0; int acc8 = 0, bacc = 0;
    long long total8 = 0;
    for (int i=3;i<24;i++) total8 += (long long)(in_sizes[i] >> 3);
    pt.raw[0] = d_in[1]; pt.off[0] = 0;   // wte: raw only (never used via ptab)
    pt.raw[1] = d_in[2]; pt.off[1] = 0;   // wpe: raw only (never used via ptab)
    for (int i=3;i<24;i++){
      int j = i-3;
      pt.raw[i-1] = d_in[i];
      pt.off[i-1] = (long long)poff;
      poff += (size_t)in_sizes[i];
      tab.s[j] = d_in[i];
      tab.off8[j] = acc8;
      tab.bstart[j] = bacc;
      int n8 = in_sizes[i] >> 3;
      int nb = (int)(((long long)n8 * 2048 + total8 - 1) / total8);
      if (nb < 1) nb = 1;
      acc8 += n8; bacc += nb;
    }
    tab.off8[21] = acc8; tab.bstart[21] = bacc;
    nblocks = bacc;
  }
  fill_ptab<<<1,64,0,stream>>>(pt, pool, flag, ptab);
  convert_all<<<nblocks,256,0,stream>>>(tab, pool, flag);

  embed_kernel<<<M_,256,0,stream>>>(idx, d_in[1], d_in[2], flag, X);
  dim3 g4 (M_/128, C_/64, 4);      // (64,8,4) fused projections, 128x64
  dim3 gkv(T_/64, B_*H_, 2);       // K/V transpose
  dim3 gck(M_/128, 32);            // 24 ck tiles + 8 cr tiles, 128x64
  dim3 gwo(M_/128, C_/64);         // (64,8) 128x64
  for (int l=0;l<L_;++l){
    // ---- time mix ----
    ln_tmix_kernel<<<M_,256,0,stream>>>(X, ptab, l, MK,MV,MR,MG);
    gemm4_mfma<<<g4,256,0,stream>>>(ptab, l, MK, Rb, Kb, Vb, Gb);
    kvtrans<<<gkv,256,0,stream>>>(Kb, Vb, Kt, Vt, ptab, l);
    wkv_state_mfma<<<dim3(NC_, B_*H_),256,0,stream>>>(Kt, Vt, S);
    wkv_prefix<<<B_*H_,256,0,stream>>>(S, Sb16, ptab, l);
    wkv_fused<<<dim3(NC_*4, B_*H_),256,0,stream>>>(Rb, Kb, Vt, Sb16, ptab, l, Gb, YGN);
    gemm_wo<<<gwo,256,0,stream>>>(ptab, l, YGN, X);
    // ---- channel mix ----
    ln_cmix_kernel<<<M_,256,0,stream>>>(X, ptab, l, MK, MV);
    gemm_ck_cr<<<gck,256,0,stream>>>(ptab, l, MK, H1, MV, RRb);
    gemm_cmix<<<gwo,256,0,stream>>>(ptab, l, H1, X, RRb);
  }
  lnf_last<<<B_,256,0,stream>>>(X, ptab, XF);
  logits_kernel<<<(B_*V_)/4,256,0,stream>>>(XF, d_in[1], d_out, flag);
}

// Round 13
// 1370.781 us; speedup vs baseline: 1.2486x; 1.0148x over previous
//
#include <hip/hip_runtime.h>

#define L_ 6
#define H_ 8
#define C_ 512
#define V_ 32000
#define B_ 2
#define T_ 4096
#define Q_ 256
#define N_ 64
#define NC_ 16
#define M_ 8192   // B*T

typedef unsigned short u16;
typedef __attribute__((ext_vector_type(8))) short bf16x8;
typedef __attribute__((ext_vector_type(4))) float f32x4;

__device__ __forceinline__ float bf2f(u16 u){
  return __uint_as_float(((unsigned int)u) << 16);
}
__device__ __forceinline__ u16 f2bf(float f){
  unsigned int x = __float_as_uint(f);
  return (u16)((x + 0x7fffu + ((x >> 16) & 1u)) >> 16);
}

__device__ __forceinline__ void gl_lds16(const u16* g, u16* l){
  __builtin_amdgcn_global_load_lds((const __attribute__((address_space(1))) void*)g,
                                   (__attribute__((address_space(3))) void*)l, 16, 0, 0);
}

// ---------------- dtype detection: bf16 weights never have |x|>=2 ----------------
__global__ __launch_bounds__(256) void detect_kernel(const void* __restrict__ probe,
                                                     int* __restrict__ flag){
  __shared__ int cnt;
  if (threadIdx.x == 0) cnt = 0;
  __syncthreads();
  const u16* p = (const u16*)probe;
  int c = 0;
  for (int i = threadIdx.x; i < 2048; i += 256){
    int e = (p[i] >> 7) & 0xFF;
    if (e >= 128) c++;
  }
  atomicAdd(&cnt, c);
  __syncthreads();
  if (threadIdx.x == 0) *flag = (cnt > 32) ? 1 : 0;  // 1 = inputs are fp32
}

// ---------------- pointer table: bf16 -> use raw inputs in place; fp32 -> converted pool ----------------
struct PtrTab { const void* raw[23]; long long off[23]; };

__global__ __launch_bounds__(64) void fill_ptab(PtrTab pt, const u16* __restrict__ pool,
    const int* __restrict__ flag, const u16** __restrict__ ptab){
  int i = threadIdx.x;
  if (i < 23)
    ptab[i+1] = (*flag) ? (pool + pt.off[i]) : (const u16*)pt.raw[i];
}

// ---------------- fp32 -> bf16 conversion, tensors 3..23 only (wte/wpe stay raw) ----------------
struct CvtTab { const void* s[21]; int off8[22]; int bstart[22]; };

__global__ __launch_bounds__(256) void convert_all(CvtTab t, u16* __restrict__ pool,
                                                   const int* __restrict__ flag){
  if (!*flag) return;    // bf16 inputs are consumed in place via ptab
  int i = 0;
  #pragma unroll
  for (int k = 1; k < 21; k++) if ((int)blockIdx.x >= t.bstart[k]) i = k;
  const void* sp = t.s[0];
  #pragma unroll
  for (int k = 1; k < 21; k++) if (i == k) sp = t.s[k];
  const int n8 = t.off8[i+1] - t.off8[i];
  const int nb = t.bstart[i+1] - t.bstart[i];
  const int lb = (int)blockIdx.x - t.bstart[i];
  uint4* dp = (uint4*)pool + t.off8[i];
  const int stride = nb * 256;
  const float4* sf = (const float4*)sp;
  for (int j = lb*256 + (int)threadIdx.x; j < n8; j += stride){
    float4 a0 = sf[2*j], a1 = sf[2*j+1];
    uint4 r0;
    r0.x = (unsigned)f2bf(a0.x) | ((unsigned)f2bf(a0.y) << 16);
    r0.y = (unsigned)f2bf(a0.z) | ((unsigned)f2bf(a0.w) << 16);
    r0.z = (unsigned)f2bf(a1.x) | ((unsigned)f2bf(a1.y) << 16);
    r0.w = (unsigned)f2bf(a1.z) | ((unsigned)f2bf(a1.w) << 16);
    dp[j] = r0;
  }
}

// ---------------- embedding: x = wte[idx] + wpe (reads raw dtype directly) ----------------
__global__ __launch_bounds__(256) void embed_kernel(const int* __restrict__ idx,
    const void* __restrict__ wteR, const void* __restrict__ wpeR,
    const int* __restrict__ flag, float* __restrict__ x){
  int row = blockIdx.x;                 // b*T + t
  int t = row & (T_-1);
  int tok = idx[row];
  float* xo = x + (size_t)row * C_;
  int c = threadIdx.x;
  float a0,a1,b0,b1;
  if (*flag){
    const float* we = (const float*)wteR + (size_t)tok * C_;
    const float* wp = (const float*)wpeR + (size_t)t * C_;
    a0 = we[c]; a1 = we[c+256]; b0 = wp[c]; b1 = wp[c+256];
  } else {
    const u16* we = (const u16*)wteR + (size_t)tok * C_;
    const u16* wp = (const u16*)wpeR + (size_t)t * C_;
    a0 = bf2f(we[c]); a1 = bf2f(we[c+256]); b0 = bf2f(wp[c]); b1 = bf2f(wp[c+256]);
  }
  xo[c]     = a0 + b0;
  xo[c+256] = a1 + b1;
}

// ---------------- fused LN + time-mix token shift (recomputes LN of row t-1) ----------------
__global__ __launch_bounds__(256) void ln_tmix_kernel(const float* __restrict__ x,
    const u16* const* __restrict__ ptab, int l,
    u16* __restrict__ xk, u16* __restrict__ xv, u16* __restrict__ xr, u16* __restrict__ xg){
  const u16* w  = ptab[3] + l*C_;
  const u16* mk = ptab[6] + l*C_;
  const u16* mv = ptab[7] + l*C_;
  const u16* mr = ptab[8] + l*C_;
  const u16* mg = ptab[9] + l*C_;
  int row = blockIdx.x; int t = row & (T_-1);
  size_t off = (size_t)row*C_;
  const float* cur = x + off;
  int c = threadIdx.x;
  float v0 = cur[c], v1 = cur[c+256];
  float p0 = 0.f, p1 = 0.f;
  if (t){ p0 = cur[c - C_]; p1 = cur[c+256 - C_]; }
  float s = v0+v1, ss = v0*v0+v1*v1;
  float sp = p0+p1, ssp = p0*p0+p1*p1;
  int lane = c & 63, wid = c >> 6;
  #pragma unroll
  for (int o=32;o>0;o>>=1){
    s  += __shfl_down(s,o,64);  ss  += __shfl_down(ss,o,64);
    sp += __shfl_down(sp,o,64); ssp += __shfl_down(ssp,o,64);
  }
  __shared__ float r1[4], r2[4], r3[4], r4[4];
  if (lane==0){ r1[wid]=s; r2[wid]=ss; r3[wid]=sp; r4[wid]=ssp; }
  __syncthreads();
  if (c==0){
    float a =r1[0]+r1[1]+r1[2]+r1[3], bq=r2[0]+r2[1]+r2[2]+r2[3];
    float ap=r3[0]+r3[1]+r3[2]+r3[3], bp=r4[0]+r4[1]+r4[2]+r4[3];
    float mu  = a *(1.f/C_); float var  = bq*(1.f/C_) - mu*mu;
    float mup = ap*(1.f/C_); float varp = bp*(1.f/C_) - mup*mup;
    r1[0]=mu;  r2[0]=rsqrtf(fmaxf(var ,0.f)+1e-5f);
    r3[0]=mup; r4[0]=rsqrtf(fmaxf(varp,0.f)+1e-5f);
  }
  __syncthreads();
  float mu=r1[0], inv=r2[0], mup=r3[0], invp=r4[0];
  #pragma unroll
  for (int p=0;p<2;p++){
    int cc = c + p*256;
    float wc = bf2f(w[cc]);
    float xc = ((p?v1:v0)-mu)*inv*wc;
    float xp = t ? ((p?p1:p0)-mup)*invp*wc : 0.f;
    float xx = xp - xc;
    xk[off+cc] = f2bf(xc + xx*bf2f(mk[cc]));
    xv[off+cc] = f2bf(xc + xx*bf2f(mv[cc]));
    xr[off+cc] = f2bf(xc + xx*bf2f(mr[cc]));
    xg[off+cc] = f2bf(xc + xx*bf2f(mg[cc]));
  }
}

// ---------------- fused LN + channel-mix token shift ----------------
__global__ __launch_bounds__(256) void ln_cmix_kernel(const float* __restrict__ x,
    const u16* const* __restrict__ ptab, int l,
    u16* __restrict__ xk, u16* __restrict__ xr){
  const u16* w  = ptab[4]  + l*C_;
  const u16* mk = ptab[19] + l*C_;
  const u16* mr = ptab[20] + l*C_;
  int row = blockIdx.x; int t = row & (T_-1);
  size_t off = (size_t)row*C_;
  const float* cur = x + off;
  int c = threadIdx.x;
  float v0 = cur[c], v1 = cur[c+256];
  float p0 = 0.f, p1 = 0.f;
  if (t){ p0 = cur[c - C_]; p1 = cur[c+256 - C_]; }
  float s = v0+v1, ss = v0*v0+v1*v1;
  float sp = p0+p1, ssp = p0*p0+p1*p1;
  int lane = c & 63, wid = c >> 6;
  #pragma unroll
  for (int o=32;o>0;o>>=1){
    s  += __shfl_down(s,o,64);  ss  += __shfl_down(ss,o,64);
    sp += __shfl_down(sp,o,64); ssp += __shfl_down(ssp,o,64);
  }
  __shared__ float r1[4], r2[4], r3[4], r4[4];
  if (lane==0){ r1[wid]=s; r2[wid]=ss; r3[wid]=sp; r4[wid]=ssp; }
  __syncthreads();
  if (c==0){
    float a =r1[0]+r1[1]+r1[2]+r1[3], bq=r2[0]+r2[1]+r2[2]+r2[3];
    float ap=r3[0]+r3[1]+r3[2]+r3[3], bp=r4[0]+r4[1]+r4[2]+r4[3];
    float mu  = a *(1.f/C_); float var  = bq*(1.f/C_) - mu*mu;
    float mup = ap*(1.f/C_); float varp = bp*(1.f/C_) - mup*mup;
    r1[0]=mu;  r2[0]=rsqrtf(fmaxf(var ,0.f)+1e-5f);
    r3[0]=mup; r4[0]=rsqrtf(fmaxf(varp,0.f)+1e-5f);
  }
  __syncthreads();
  float mu=r1[0], inv=r2[0], mup=r3[0], invp=r4[0];
  #pragma unroll
  for (int p=0;p<2;p++){
    int cc = c + p*256;
    float wc = bf2f(w[cc]);
    float xc = ((p?v1:v0)-mu)*inv*wc;
    float xp = t ? ((p?p1:p0)-mup)*invp*wc : 0.f;
    float xx = xp - xc;
    xk[off+cc] = f2bf(xc + xx*bf2f(mk[cc]));
    xr[off+cc] = f2bf(xc + xx*bf2f(mr[cc]));
  }
}

// ---------------- final LN for last position only ----------------
__global__ __launch_bounds__(256) void lnf_last(const float* __restrict__ x,
    const u16* const* __restrict__ ptab, float* __restrict__ xf){
  const u16* w = ptab[5];
  int b = blockIdx.x;
  const float* xr = x + ((size_t)b*T_ + (T_-1))*C_;
  int c = threadIdx.x;
  float v0 = xr[c], v1 = xr[c+256];
  float s = v0+v1, ss = v0*v0+v1*v1;
  int lane = c & 63, wid = c >> 6;
  #pragma unroll
  for (int o=32;o>0;o>>=1){ s += __shfl_down(s,o,64); ss += __shfl_down(ss,o,64); }
  __shared__ float r1[4], r2[4];
  if (lane==0){ r1[wid]=s; r2[wid]=ss; }
  __syncthreads();
  if (c==0){
    float a=r1[0]+r1[1]+r1[2]+r1[3], bq=r2[0]+r2[1]+r2[2]+r2[3];
    float mu = a*(1.f/C_);
    float var = bq*(1.f/C_) - mu*mu;
    r1[0]=mu; r2[0]=rsqrtf(fmaxf(var,0.f)+1e-5f);
  }
  __syncthreads();
  float mu=r1[0], inv=r2[0];
  xf[b*C_+c]     = (v0-mu)*inv*bf2f(w[c]);
  xf[b*C_+c+256] = (v1-mu)*inv*bf2f(w[c+256]);
}

// ================= MFMA GEMM bodies =================
#define ACT_RELU2_BF16 1
#define ACT_ADD_F32 2
#define ACT_BF16 3
#define ACT_CMIX 4      // Yf += v * bf2f(AuxB) (AuxB holds sigmoid gate)
#define ACT_SIG_BF16 7  // Yb = bf16(sigmoid(v))

// ---- 128(M) x 64(N), BK=64, 24KB LDS ----
template<int ACT>
__device__ __forceinline__ void gemm_mfma_body(u16* __restrict__ Al, u16* __restrict__ Bl,
    const u16* __restrict__ X, const u16* __restrict__ W,
    float* __restrict__ Yf, u16* __restrict__ Yb, const u16* __restrict__ AuxB,
    int Ndim, int Kdim, int bm, int bn){
  const int tid = threadIdx.x;
  const int wv = tid >> 6, ln = tid & 63;
  const int m16 = ln & 15, q = ln >> 4;

  f32x4 acc[2][4];
  #pragma unroll
  for (int i=0;i<2;i++)
    #pragma unroll
    for (int j=0;j<4;j++) acc[i][j] = f32x4{0.f,0.f,0.f,0.f};

  const int r0 = wv*8 + (ln >> 3);
  const int c0 = (ln & 7)*8;
  const u16* ga = X + (size_t)(bm + r0)*Kdim + c0;
  const u16* gb = W + (size_t)(bn + r0)*Kdim + c0;
  u16* la = Al + r0*64 + c0;
  u16* lb = Bl + r0*64 + c0;

  for (int k0=0; k0<Kdim; k0+=64){
    #pragma unroll
    for (int s=0;s<4;s++)
      gl_lds16(ga + (size_t)(s*32)*Kdim + k0, la + s*2048);
    #pragma unroll
    for (int s=0;s<2;s++)
      gl_lds16(gb + (size_t)(s*32)*Kdim + k0, lb + s*2048);
    __syncthreads();
    #pragma unroll
    for (int kh=0; kh<2; kh++){
      bf16x8 af[2], bfr[4];
      #pragma unroll
      for (int i=0;i<2;i++) af[i]  = *(const bf16x8*)(Al + (wv*32 + i*16 + m16)*64 + kh*32 + q*8);
      #pragma unroll
      for (int j=0;j<4;j++) bfr[j] = *(const bf16x8*)(Bl + (j*16 + m16)*64 + kh*32 + q*8);
      #pragma unroll
      for (int i=0;i<2;i++)
        #pragma unroll
        for (int j=0;j<4;j++)
          acc[i][j] = __builtin_amdgcn_mfma_f32_16x16x32_bf16(af[i], bfr[j], acc[i][j], 0, 0, 0);
    }
    __syncthreads();
  }

  // epilogue: C/D layout col=lane&15, row=quad*4+reg
  #pragma unroll
  for (int i=0;i<2;i++){
    int row = bm + wv*32 + i*16 + q*4;
    #pragma unroll
    for (int j=0;j<4;j++){
      int col = bn + j*16 + m16;
      #pragma unroll
      for (int r=0;r<4;r++){
        size_t off = (size_t)(row + r)*Ndim + col;
        float v = acc[i][j][r];
        if (ACT==ACT_ADD_F32) Yf[off] += v;
        else if (ACT==ACT_CMIX){ Yf[off] += v * bf2f(AuxB[off]); }
        else if (ACT==ACT_BF16) Yb[off] = f2bf(v);
        else if (ACT==ACT_RELU2_BF16){ float rr = v>0.f ? v : 0.f; Yb[off] = f2bf(rr*rr); }
        else if (ACT==ACT_SIG_BF16) Yb[off] = f2bf(1.f/(1.f+expf(-v)));
      }
    }
  }
}

// ---- 128(M) x 128(N), BK=64, 32KB LDS: 32 MFMA per K-step per wave ----
template<int ACT>
__device__ __forceinline__ void gemm128_body(u16* __restrict__ Al, u16* __restrict__ Bl,
    const u16* __restrict__ X, const u16* __restrict__ W,
    u16* __restrict__ Yb, int Ndim, int Kdim, int bm, int bn){
  const int tid = threadIdx.x;
  const int wv = tid >> 6, ln = tid & 63;
  const int m16 = ln & 15, q = ln >> 4;

  f32x4 acc[2][8];
  #pragma unroll
  for (int i=0;i<2;i++)
    #pragma unroll
    for (int j=0;j<8;j++) acc[i][j] = f32x4{0.f,0.f,0.f,0.f};

  const int r0 = wv*8 + (ln >> 3);
  const int c0 = (ln & 7)*8;
  const u16* ga = X + (size_t)(bm + r0)*Kdim + c0;
  const u16* gb = W + (size_t)(bn + r0)*Kdim + c0;
  u16* la = Al + r0*64 + c0;
  u16* lb = Bl + r0*64 + c0;

  for (int k0=0; k0<Kdim; k0+=64){
    #pragma unroll
    for (int s=0;s<4;s++)
      gl_lds16(ga + (size_t)(s*32)*Kdim + k0, la + s*2048);
    #pragma unroll
    for (int s=0;s<4;s++)
      gl_lds16(gb + (size_t)(s*32)*Kdim + k0, lb + s*2048);
    __syncthreads();
    #pragma unroll
    for (int kh=0; kh<2; kh++){
      bf16x8 af0 = *(const bf16x8*)(Al + (wv*32 + m16)*64      + kh*32 + q*8);
      bf16x8 af1 = *(const bf16x8*)(Al + (wv*32 + 16 + m16)*64 + kh*32 + q*8);
      #pragma unroll
      for (int j=0;j<8;j++){
        bf16x8 bfr = *(const bf16x8*)(Bl + (j*16 + m16)*64 + kh*32 + q*8);
        acc[0][j] = __builtin_amdgcn_mfma_f32_16x16x32_bf16(af0, bfr, acc[0][j], 0, 0, 0);
        acc[1][j] = __builtin_amdgcn_mfma_f32_16x16x32_bf16(af1, bfr, acc[1][j], 0, 0, 0);
      }
    }
    __syncthreads();
  }

  #pragma unroll
  for (int i=0;i<2;i++){
    int row = bm + wv*32 + i*16 + q*4;
    #pragma unroll
    for (int j=0;j<8;j++){
      int col = bn + j*16 + m16;
      #pragma unroll
      for (int r=0;r<4;r++){
        size_t off = (size_t)(row + r)*Ndim + col;
        float v = acc[i][j][r];
        if (ACT==ACT_BF16) Yb[off] = f2bf(v);
        else if (ACT==ACT_RELU2_BF16){ float rr = v>0.f ? v : 0.f; Yb[off] = f2bf(rr*rr); }
        else if (ACT==ACT_SIG_BF16) Yb[off] = f2bf(1.f/(1.f+expf(-v)));
      }
    }
  }
}

#define GEMM_SH    __shared__ __align__(16) u16 SH[128*64 + 64*64]
#define GEMM_SH128 __shared__ __align__(16) u16 SH[128*64 + 128*64]

// fused r/k/v/g projections, 128x128 tiles, grid (64,4,4) — ONE 32KB LDS buffer
__global__ __launch_bounds__(256,3) void gemm4_mfma(const u16* const* __restrict__ ptab, int l,
    const u16* __restrict__ Abase,
    u16* __restrict__ Rb, u16* __restrict__ Kb, u16* __restrict__ Vb, u16* __restrict__ Gb){
  GEMM_SH128;
  const size_t MC = (size_t)M_*C_;
  const size_t ws = (size_t)l*C_*C_;
  const int bm = blockIdx.x*128, bn = blockIdx.y*128;
  switch (blockIdx.z){
    case 0:  gemm128_body<ACT_BF16>(SH, SH+128*64, Abase + 2*MC, ptab[12]+ws, Rb, C_, C_, bm, bn); break;
    case 1:  gemm128_body<ACT_BF16>(SH, SH+128*64, Abase,        ptab[13]+ws, Kb, C_, C_, bm, bn); break;
    case 2:  gemm128_body<ACT_BF16>(SH, SH+128*64, Abase + 1*MC, ptab[14]+ws, Vb, C_, C_, bm, bn); break;
    default: gemm128_body<ACT_BF16>(SH, SH+128*64, Abase + 3*MC, ptab[15]+ws, Gb, C_, C_, bm, bn); break;
  }
}

// fused cmix key (relu^2 -> H1) + receptance gate (sigmoid -> RRb), 128x128, grid (64,16)
__global__ __launch_bounds__(256,3) void gemm_ck_cr(const u16* const* __restrict__ ptab, int l,
    const u16* __restrict__ MK, u16* __restrict__ H1,
    const u16* __restrict__ MV, u16* __restrict__ RRb){
  GEMM_SH128;
  if (blockIdx.y < 12)
    gemm128_body<ACT_RELU2_BF16>(SH, SH+128*64, MK, ptab[21]+(size_t)l*3*C_*C_, H1,
                                 3*C_, C_, blockIdx.x*128, blockIdx.y*128);
  else
    gemm128_body<ACT_SIG_BF16>(SH, SH+128*64, MV, ptab[23]+(size_t)l*C_*C_, RRb,
                               C_, C_, blockIdx.x*128, (blockIdx.y-12)*128);
}

// output projection with residual add: X += YGN @ Wo^T   (grid 64x8, 128x64)
__global__ __launch_bounds__(256,4) void gemm_wo(const u16* const* __restrict__ ptab, int l,
    const u16* __restrict__ YGN, float* __restrict__ X){
  GEMM_SH;
  gemm_mfma_body<ACT_ADD_F32>(SH, SH+128*64, YGN, ptab[16]+(size_t)l*C_*C_, X, nullptr, nullptr,
                              C_, C_, blockIdx.x*128, blockIdx.y*64);
}

// cmix value GEMM with fused tail: X += gate * (H1 @ Wcv^T)   (grid 64x8, 128x64)
__global__ __launch_bounds__(256,4) void gemm_cmix(const u16* const* __restrict__ ptab, int l,
    const u16* __restrict__ H1, float* __restrict__ X, const u16* __restrict__ RRb){
  GEMM_SH;
  gemm_mfma_body<ACT_CMIX>(SH, SH+128*64, H1, ptab[22]+(size_t)l*3*C_*C_, X, nullptr, RRb,
                           C_, 3*C_, blockIdx.x*128, blockIdx.y*64);
}

// ---------------- K/V per-(b,h) transpose; K gets wdec^(Q-1-tloc) scale ----------------
// grid (T/64, B*H, 2): z=0 V->Vt plain, z=1 K->Kt scaled
__global__ __launch_bounds__(256) void kvtrans(const u16* __restrict__ Kb, const u16* __restrict__ Vb,
    u16* __restrict__ Kt, u16* __restrict__ Vt, const u16* const* __restrict__ ptab, int l){
  __shared__ __align__(16) u16 tile[64*64];
  const int t0 = blockIdx.x*64, bh = blockIdx.y, b = bh>>3, h = bh&7;
  const bool isK = (blockIdx.z == 1);
  const u16* src = isK ? Kb : Vb;
  u16* dst = isK ? Kt : Vt;
  float l2w = 0.f;
  if (isK){
    const u16* td = ptab[10] + l*H_;
    l2w = -expf(bf2f(td[h])) * 1.44269504f;
  }
  const int tid = threadIdx.x;
  #pragma unroll
  for (int it=0; it<2; ++it){
    int tl = it*32 + (tid>>3);
    int n0 = (tid&7)*8;
    union {uint4 q; u16 e[8];} v;
    v.q = *(const uint4*)(src + ((size_t)(b*T_ + t0 + tl))*C_ + h*N_ + n0);
    if (isK){
      int tloc = (t0 + tl) & (Q_-1);
      float sc = exp2f(l2w * (float)(Q_-1 - tloc));
      #pragma unroll
      for (int e=0;e<8;++e) v.e[e] = f2bf(bf2f(v.e[e])*sc);
    }
    int col = n0 ^ (((tl>>3)&7)<<3);
    *(uint4*)&tile[tl*64 + col] = v.q;
  }
  __syncthreads();
  #pragma unroll
  for (int it=0; it<2; ++it){
    int nl = it*32 + (tid>>3);
    int t0l = (tid&7)*8;
    int swz = (tid&7)<<3;
    union {uint4 q; u16 h2[8];} pk;
    #pragma unroll
    for (int e=0;e<8;++e)
      pk.h2[e] = tile[(t0l+e)*64 + (nl ^ swz)];
    *(uint4*)(dst + ((size_t)(bh*N_ + nl))*T_ + t0 + t0l) = pk.q;
  }
}

// ---------------- per-chunk state, stored TRANSPOSED: St[v_feat][k_feat] ----------------
__global__ __launch_bounds__(256) void wkv_state_mfma(const u16* __restrict__ Kt,
    const u16* __restrict__ Vt, float* __restrict__ S){
  const int c = blockIdx.x, bh = blockIdx.y;
  const int tid = threadIdx.x, wv = tid >> 6, ln = tid & 63;
  const int m16 = ln & 15, q = ln >> 4;
  const u16* ka = Kt + (size_t)(bh*N_ + wv*16 + m16)*T_ + c*Q_;
  const u16* vb = Vt + (size_t)(bh*N_ + m16)*T_ + c*Q_;
  f32x4 acc[4];
  #pragma unroll
  for (int nt=0;nt<4;++nt) acc[nt] = f32x4{0.f,0.f,0.f,0.f};
  #pragma unroll
  for (int ks=0; ks<8; ++ks){
    bf16x8 af = *(const bf16x8*)(ka + ks*32 + q*8);
    #pragma unroll
    for (int nt=0;nt<4;++nt){
      bf16x8 bv = *(const bf16x8*)(vb + (size_t)(nt*16)*T_ + ks*32 + q*8);
      acc[nt] = __builtin_amdgcn_mfma_f32_16x16x32_bf16(af, bv, acc[nt], 0,0,0);
    }
  }
  float* Sp = S + ((size_t)bh*NC_ + c)*(N_*N_);
  // MFMA out: k_feat row = wv*16+q*4+r, v_feat col = nt*16+m16. Store transposed.
  #pragma unroll
  for (int nt=0;nt<4;++nt)
    #pragma unroll
    for (int r=0;r<4;++r)
      Sp[(nt*16 + m16)*N_ + (wv*16 + q*4 + r)] = acc[nt][r];
}

// ---------------- sequential prefix over chunks -> bf16 St output ----------------
// Sb16[cc] = bf16( sum_{j<cc} wsd^(cc-1-j) * S_j )  (exclusive prefix, f32 Horner)
__global__ __launch_bounds__(256) void wkv_prefix(const float* __restrict__ S,
    u16* __restrict__ Sb16, const u16* const* __restrict__ ptab, int l){
  const int bh = blockIdx.x, h = bh&7;
  const u16* td = ptab[10] + l*H_;
  const float l2w = -expf(bf2f(td[h])) * 1.44269504f;
  const float wsd = exp2f(l2w * (float)Q_);
  const float* Sp = S + (size_t)bh*NC_*N_*N_;
  u16* Sb = Sb16 + (size_t)bh*NC_*N_*N_;
  for (int e=threadIdx.x; e<N_*N_; e+=256){
    float cur = 0.f;
    for (int cc=0;cc<NC_;++cc){
      Sb[(size_t)cc*N_*N_ + e] = f2bf(cur);
      cur = wsd*cur + Sp[(size_t)cc*N_*N_ + e];
    }
  }
}

// ---------------- FUSED WKV: single strip per block, ip swizzled across co-resident blocks ----
// grid (NC_*4, B_*H_). Co-resident blocks differ by 256 in linear id -> same x, y+4.
// ip = ((x&3)+(y>>2))&3 gives each CU's 4 resident blocks DIFFERENT ips -> uniform 10 units/CU.
__global__ __launch_bounds__(256) void wkv_fused(const u16* __restrict__ Rb,
    const u16* __restrict__ Kb, const u16* __restrict__ Vt, const u16* __restrict__ Sb16,
    const u16* const* __restrict__ ptab, int l,
    const u16* __restrict__ g, u16* __restrict__ out){
  __shared__ float wpow[Q_];
  __shared__ __align__(16) u16 P[4][16][72];    // wave-private quarters
  __shared__ __align__(16) u16 stl[64][72];     // St bf16: [v_feat n][k_feat k]
  __shared__ __align__(16) u16 gl[64][72];      // g tile: [row-in-strip][n]
  const u16* td  = ptab[10] + l*H_;
  const u16* tf  = ptab[11] + l*H_;
  const u16* gnw = ptab[17] + l*C_;
  const u16* gnb = ptab[18] + l*C_;
  const int c = blockIdx.x>>2;
  const int ip = ((blockIdx.x & 3) + (blockIdx.y >> 2)) & 3;   // balance swizzle
  const int bh = blockIdx.y, b = bh>>3, h = bh&7;
  const int tid = threadIdx.x, wv = tid >> 6, ln = tid & 63;
  const int m16 = ln & 15, q = ln >> 4;
  const float l2w = -expf(bf2f(td[h])) * 1.44269504f;
  const float uu = bf2f(tf[h]);
  wpow[tid] = exp2f(l2w * (float)tid);
  const size_t base = ((size_t)b*T_ + (size_t)c*Q_)*C_ + h*N_;
  const int i0 = ip*64;
  // stage bf16 St (coalesced uint4) and g tile
  {
    const u16* Sp = Sb16 + ((size_t)bh*NC_ + c)*(N_*N_);
    #pragma unroll
    for (int k2=0;k2<2;++k2){
      int e = (tid + k2*256)*8;       // e = n*64 + k
      *(uint4*)&stl[e>>6][e&63] = *(const uint4*)(Sp + e);
    }
    #pragma unroll
    for (int it=0; it<2; ++it){
      int rr2 = it*32 + (tid>>3);
      int n0 = (tid&7)*8;
      *(uint4*)&gl[rr2][n0] = *(const uint4*)(g + base + (size_t)(i0+rr2)*C_ + n0);
    }
  }
  __syncthreads();
  // ---- intra-chunk (MFMA) ----
  const int iw0 = i0 + wv*16;
  const u16* rrow = Rb + base + (size_t)(iw0 + m16)*C_;
  bf16x8 af0 = *(const bf16x8*)(rrow + q*8);
  bf16x8 af1 = *(const bf16x8*)(rrow + 32 + q*8);
  f32x4 acc[4];
  #pragma unroll
  for (int nt=0;nt<4;++nt) acc[nt] = f32x4{0.f,0.f,0.f,0.f};
  const int irow = iw0 + q*4;
  const u16* vtb = Vt + (size_t)(bh*N_)*T_ + (size_t)c*Q_;
  for (int jt=0; jt<=ip; ++jt){
    // prefetch V fragments for this jt (independent of the K->P chain)
    bf16x8 vfr[2][4];
    #pragma unroll
    for (int kp=0;kp<2;++kp)
      #pragma unroll
      for (int nt=0;nt<4;++nt)
        vfr[kp][nt] = *(const bf16x8*)(vtb + (size_t)(nt*16 + m16)*T_ + jt*64 + kp*32 + q*8);
    f32x4 s[4];
    #pragma unroll
    for (int j2=0;j2<4;++j2) s[j2] = f32x4{0.f,0.f,0.f,0.f};
    #pragma unroll
    for (int j2=0;j2<4;++j2){
      const u16* kr = Kb + base + (size_t)(jt*64 + j2*16 + m16)*C_;
      bf16x8 b0 = *(const bf16x8*)(kr + q*8);
      bf16x8 b1 = *(const bf16x8*)(kr + 32 + q*8);
      s[j2] = __builtin_amdgcn_mfma_f32_16x16x32_bf16(af0, b0, s[j2], 0,0,0);
      s[j2] = __builtin_amdgcn_mfma_f32_16x16x32_bf16(af1, b1, s[j2], 0,0,0);
    }
    #pragma unroll
    for (int j2=0;j2<4;++j2){
      int jc = jt*64 + j2*16 + m16;
      #pragma unroll
      for (int r=0;r<4;++r){
        int ic = irow + r;
        float w = (jc < ic) ? wpow[ic-jc-1] : ((jc==ic) ? uu : 0.f);
        P[wv][q*4+r][j2*16+m16] = f2bf(s[j2][r]*w);
      }
    }
    __asm__ volatile("s_waitcnt lgkmcnt(0)" ::: "memory");
    #pragma unroll
    for (int kp=0;kp<2;++kp){
      bf16x8 ap = *(const bf16x8*)&P[wv][m16][kp*32 + q*8];
      #pragma unroll
      for (int nt=0;nt<4;++nt)
        acc[nt] = __builtin_amdgcn_mfma_f32_16x16x32_bf16(ap, vfr[kp][nt], acc[nt], 0,0,0);
    }
  }
  // ---- inter-chunk via MFMA: y2 = r @ St^T ----
  f32x4 acc2[4];
  #pragma unroll
  for (int nt=0;nt<4;++nt) acc2[nt] = f32x4{0.f,0.f,0.f,0.f};
  #pragma unroll
  for (int nt=0;nt<4;++nt){
    bf16x8 sb0 = *(const bf16x8*)&stl[nt*16 + m16][q*8];
    bf16x8 sb1 = *(const bf16x8*)&stl[nt*16 + m16][32 + q*8];
    acc2[nt] = __builtin_amdgcn_mfma_f32_16x16x32_bf16(af0, sb0, acc2[nt], 0,0,0);
    acc2[nt] = __builtin_amdgcn_mfma_f32_16x16x32_bf16(af1, sb1, acc2[nt], 0,0,0);
  }
  // ---- GroupNorm + silu(g) directly in MFMA C/D layout ----
  #pragma unroll
  for (int r=0;r<4;++r){
    int il = irow + r;                    // row within chunk [0,256)
    int rs = il - i0;                     // row within 64-row strip
    size_t roff = base + (size_t)il*C_;
    float w = wpow[il];
    float val[4];
    float s=0.f, ss=0.f;
    #pragma unroll
    for (int nt=0;nt<4;++nt){
      float v = acc[nt][r] + w*acc2[nt][r];
      val[nt]=v; s+=v; ss+=v*v;
    }
    #pragma unroll
    for (int o=8;o>0;o>>=1){ s+=__shfl_xor(s,o,64); ss+=__shfl_xor(ss,o,64); }
    float mu = s*(1.f/N_);
    float var = ss*(1.f/N_) - mu*mu;
    float inv = rsqrtf(fmaxf(var,0.f) + 6.4e-4f);   // GN_EPS = 1e-5*64
    #pragma unroll
    for (int nt=0;nt<4;++nt){
      int n = nt*16 + m16, ci = h*N_ + n;
      float gg = bf2f(gl[rs][n]);
      float sil = gg/(1.f+expf(-gg));
      out[roff + n] = f2bf(((val[nt]-mu)*inv*bf2f(gnw[ci]) + bf2f(gnb[ci]))*sil);
    }
  }
}

// ---------------- logits for last position: [B,V] = xf @ wte^T (raw dtype) ----------------
__global__ __launch_bounds__(256) void logits_kernel(const float* __restrict__ xf,
    const void* __restrict__ wteR, void* __restrict__ out, const int* __restrict__ flag){
  const int wid = threadIdx.x>>6, lane = threadIdx.x&63;
  const int gw = blockIdx.x*4 + wid;     // 0 .. B*V-1
  const int b = gw / V_, v = gw - b*V_;
  const float* xr = xf + b*C_;
  float s = 0.f;
  if (*flag){
    const float* wrow = (const float*)wteR + (size_t)v*C_;
    float4 w0 = ((const float4*)wrow)[lane*2];
    float4 w1 = ((const float4*)wrow)[lane*2+1];
    const float* xp = xr + lane*8;
    s = w0.x*xp[0] + w0.y*xp[1] + w0.z*xp[2] + w0.w*xp[3]
      + w1.x*xp[4] + w1.y*xp[5] + w1.z*xp[6] + w1.w*xp[7];
  } else {
    const u16* wrow = (const u16*)wteR + (size_t)v*C_;
    union {uint4 q; u16 h[8];} uu;
    uu.q = *(const uint4*)(wrow + lane*8);
    #pragma unroll
    for (int j=0;j<8;j++) s += bf2f(uu.h[j])*xr[lane*8+j];
  }
  #pragma unroll
  for (int o=32;o>0;o>>=1) s += __shfl_down(s,o,64);
  if (lane==0){
    size_t o = (size_t)b*V_ + v;
    if (*flag) ((float*)out)[o] = s;          // fp32 harness
    else       ((u16*)out)[o]   = f2bf(s);    // bf16 harness
  }
}

extern "C" void kernel_launch(void* const* d_in, const int* in_sizes, int n_in,
                              void* d_out, int out_size, void* d_ws, size_t ws_size,
                              hipStream_t stream){
  (void)out_size; (void)ws_size; (void)n_in;
  const int* idx  = (const int*)d_in[0];

  char* ws = (char*)d_ws;
  const size_t MC  = (size_t)M_*C_;
  // ---- workspace layout (bytes) ----
  size_t o = 0;
  int* flag = (int*)(ws + o);            o += 1024;
  const u16** ptab = (const u16**)(ws + o); o += 1024;
  float* X   = (float*)(ws + o);         o += MC*4;            // fp32 residual
  u16* MK = (u16*)(ws + o);              o += MC*2;            // also YGN
  u16* MV = (u16*)(ws + o);              o += MC*2;
  u16* MR = (u16*)(ws + o);              o += MC*2;            // also S (tmix) / RRb (cmix)
  u16* MG = (u16*)(ws + o);              o += MC*2;            // also Sb16 (after gemm4)
  u16* Rb = (u16*)(ws + o);              o += MC*2;            // H1 spans Rb..Vb
  u16* Kb = (u16*)(ws + o);              o += MC*2;
  u16* Vb = (u16*)(ws + o);              o += MC*2;
  u16* Gb = (u16*)(ws + o);              o += MC*2;
  u16* Kt = (u16*)(ws + o);              o += MC*2;            // scaled k^T per (b,h): [BH*64, T]
  u16* Vt = (u16*)(ws + o);              o += MC*2;            // v^T per (b,h): [BH*64, T]
  float* XF = (float*)(ws + o);          o += 65536;
  u16* pool = (u16*)(ws + o);            // fp32->bf16 converted inputs 3..23
  u16* YGN = MK;
  float* S  = (float*)MR;    // f32 per-chunk states (live only during tmix phase)
  u16* Sb16 = MG;            // bf16 exclusive-prefix states (2 MB; MG free after gemm4)
  u16* H1 = Rb;              // [M,3C] bf16, spans Rb..Vb
  u16* RRb = MR;             // [M,C] bf16 sigmoid gate (cmix phase)

  // ---- dtype detect + pointer table + (conditional) conversion of tensors 3..23 ----
  detect_kernel<<<1,256,0,stream>>>(d_in[12], flag);   // probe Wr
  CvtTab tab; PtrTab pt;
  int nblocks;
  {
    size_t poff = 0; int acc8 = 0, bacc = 0;
    long long total8 = 0;
    for (int i=3;i<24;i++) total8 += (long long)(in_sizes[i] >> 3);
    pt.raw[0] = d_in[1]; pt.off[0] = 0;   // wte: raw only (never used via ptab)
    pt.raw[1] = d_in[2]; pt.off[1] = 0;   // wpe: raw only (never used via ptab)
    for (int i=3;i<24;i++){
      int j = i-3;
      pt.raw[i-1] = d_in[i];
      pt.off[i-1] = (long long)poff;
      poff += (size_t)in_sizes[i];
      tab.s[j] = d_in[i];
      tab.off8[j] = acc8;
      tab.bstart[j] = bacc;
      int n8 = in_sizes[i] >> 3;
      int nb = (int)(((long long)n8 * 2048 + total8 - 1) / total8);
      if (nb < 1) nb = 1;
      acc8 += n8; bacc += nb;
    }
    tab.off8[21] = acc8; tab.bstart[21] = bacc;
    nblocks = bacc;
  }
  fill_ptab<<<1,64,0,stream>>>(pt, pool, flag, ptab);
  convert_all<<<nblocks,256,0,stream>>>(tab, pool, flag);

  embed_kernel<<<M_,256,0,stream>>>(idx, d_in[1], d_in[2], flag, X);
  dim3 g4 (M_/128, C_/128, 4);     // (64,4,4) fused projections, 128x128
  dim3 gkv(T_/64, B_*H_, 2);       // K/V transpose
  dim3 gck(M_/128, 16);            // 12 ck + 4 cr tiles, 128x128
  dim3 gwo(M_/128, C_/64);         // (64,8) 128x64
  for (int l=0;l<L_;++l){
    // ---- time mix ----
    ln_tmix_kernel<<<M_,256,0,stream>>>(X, ptab, l, MK,MV,MR,MG);
    gemm4_mfma<<<g4,256,0,stream>>>(ptab, l, MK, Rb, Kb, Vb, Gb);
    kvtrans<<<gkv,256,0,stream>>>(Kb, Vb, Kt, Vt, ptab, l);
    wkv_state_mfma<<<dim3(NC_, B_*H_),256,0,stream>>>(Kt, Vt, S);
    wkv_prefix<<<B_*H_,256,0,stream>>>(S, Sb16, ptab, l);
    wkv_fused<<<dim3(NC_*4, B_*H_),256,0,stream>>>(Rb, Kb, Vt, Sb16, ptab, l, Gb, YGN);
    gemm_wo<<<gwo,256,0,stream>>>(ptab, l, YGN, X);
    // ---- channel mix ----
    ln_cmix_kernel<<<M_,256,0,stream>>>(X, ptab, l, MK, MV);
    gemm_ck_cr<<<gck,256,0,stream>>>(ptab, l, MK, H1, MV, RRb);
    gemm_cmix<<<gwo,256,0,stream>>>(ptab, l, H1, X, RRb);
  }
  lnf_last<<<B_,256,0,stream>>>(X, ptab, XF);
  logits_kernel<<<(B_*V_)/4,256,0,stream>>>(XF, d_in[1], d_out, flag);
}